// Round 2
// baseline (764.935 us; speedup 1.0000x reference)
//
#include <hip/hip_runtime.h>
#include <cstdint>

#define DEVI __device__ __forceinline__

typedef unsigned short u16;
typedef unsigned int u32;
typedef __attribute__((ext_vector_type(4))) float f32x4;
typedef __attribute__((ext_vector_type(8))) u16 u16x8;
typedef __attribute__((ext_vector_type(4))) u16 u16x4;
typedef __attribute__((ext_vector_type(8))) __bf16 bf16x8;

#define SEQL 2048
#define NBATCH 8
#define MROWS (NBATCH*SEQL)
#define DMODEL 1024
#define DINNER 2048
#define NHEADS 32
#define HEADD 64
#define DSTATE 128
#define CONVD 2304
#define NPROJ 4384
#define NPROJP 4480
#define CHUNKL 128
#define NCHUNK 16
#define PADC 136

DEVI float bf2f(u16 v){ u32 u = ((u32)v)<<16; return __builtin_bit_cast(float,u); }
DEVI u16 f2bf(float f){ u32 u = __builtin_bit_cast(u32,f); u32 r = (u + 0x7fffu + ((u>>16)&1u))>>16; return (u16)r; }

DEVI f32x4 MFMA(u16x8 a, u16x8 b, f32x4 c){
  return __builtin_amdgcn_mfma_f32_16x16x32_bf16(
      __builtin_bit_cast(bf16x8,a), __builtin_bit_cast(bf16x8,b), c, 0,0,0);
}

__global__ void k_sentinel(float* o){ o[0] = 12345.0f; }

// ---------------- convert f32 -> bf16 (with zero-pad tail) ----------------
__global__ __launch_bounds__(256) void k_cvt(const float* __restrict__ src, u16* __restrict__ dst, long n, long ntot){
  long idx = ((long)blockIdx.x*256 + threadIdx.x)*4;
  if (idx >= ntot) return;
  u16x4 o;
  if (idx < n){
    f32x4 v = *(const f32x4*)(src+idx);
    o[0]=f2bf(v[0]); o[1]=f2bf(v[1]); o[2]=f2bf(v[2]); o[3]=f2bf(v[3]);
  } else { o[0]=0; o[1]=0; o[2]=0; o[3]=0; }
  *(u16x4*)(dst+idx) = o;
}

// ---------------- GEMM: C = A * B^T, A (M,K) bf16, Bt (N,K) bf16 ----------
// Reg-staged LDS (no global_load_lds this round — de-risk).
// MODE 0: plain f32 out (ld = Ndim). MODE 1: split epilogue for GEMM1.
template<int MODE>
__global__ __launch_bounds__(256) void k_gemm(const u16* __restrict__ A, const u16* __restrict__ Bt,
    int K, int Ndim, float* __restrict__ outF,
    u16* __restrict__ z_out, u16* __restrict__ xbc_out, float* __restrict__ dtraw_out)
{
  __shared__ u16 sA[128*64];
  __shared__ u16 sB[128*64];
  const int tid = threadIdx.x;
  const int m0 = blockIdx.x * 128;
  const int n0 = blockIdx.y * 128;
  const int lane = tid & 63, wid = tid >> 6;
  const int wr = wid & 1, wc = wid >> 1;
  const int lidx = lane & 15, krow = lane >> 4;
  const f32x4 zf = {0.f,0.f,0.f,0.f};
  f32x4 acc[4][4];
  #pragma unroll
  for (int i=0;i<4;i++)
    #pragma unroll
    for (int j=0;j<4;j++) acc[i][j] = zf;
  const int r8 = tid >> 3, c8 = tid & 7;
  const u16* Ag = A + (long)(m0 + r8)*K + c8*8;
  const u16* Bg = Bt + (long)(n0 + r8)*K + c8*8;
  for (int k0=0; k0<K; k0+=64){
    u16x8 va[4], vb[4];
    #pragma unroll
    for (int i=0;i<4;i++){
      va[i] = *(const u16x8*)(Ag + (long)i*32*K + k0);
      vb[i] = *(const u16x8*)(Bg + (long)i*32*K + k0);
    }
    __syncthreads();   // previous iter's LDS reads complete
    #pragma unroll
    for (int i=0;i<4;i++){
      *(u16x8*)(&sA[(r8 + i*32)*64 + c8*8]) = va[i];
      *(u16x8*)(&sB[(r8 + i*32)*64 + c8*8]) = vb[i];
    }
    __syncthreads();
    #pragma unroll
    for (int kk=0; kk<64; kk+=32){
      u16x8 af[4], bfv[4];
      #pragma unroll
      for (int i=0;i<4;i++){
        af[i]  = *(const u16x8*)(&sA[(wr*64 + i*16 + lidx)*64 + kk + krow*8]);
        bfv[i] = *(const u16x8*)(&sB[(wc*64 + i*16 + lidx)*64 + kk + krow*8]);
      }
      #pragma unroll
      for (int i=0;i<4;i++)
        #pragma unroll
        for (int j=0;j<4;j++)
          acc[i][j] = MFMA(af[i], bfv[j], acc[i][j]);
    }
  }
  #pragma unroll
  for (int i=0;i<4;i++)
    #pragma unroll
    for (int j=0;j<4;j++)
      #pragma unroll
      for (int r=0;r<4;r++){
        int gm = m0 + wr*64 + i*16 + krow*4 + r;
        int gn = n0 + wc*64 + j*16 + lidx;
        float v = acc[i][j][r];
        if (MODE==0){
          outF[(long)gm*Ndim + gn] = v;
        } else {
          if (gn < DINNER) z_out[(long)gm*DINNER + gn] = f2bf(v);
          else if (gn < DINNER+CONVD) xbc_out[(long)gm*CONVD + (gn-DINNER)] = f2bf(v);
          else if (gn < NPROJ) dtraw_out[(long)gm*NHEADS + (gn-DINNER-CONVD)] = v;
        }
      }
}

// ---------------- dt prep: softplus + per-chunk inclusive cumsum ----------
__global__ __launch_bounds__(128) void k_dtprep(const float* __restrict__ dtraw, const float* __restrict__ dt_bias,
    const float* __restrict__ A_log, float* __restrict__ dt_t, float* __restrict__ acs_t)
{
  int b = blockIdx.x >> 9;
  int h = (blockIdx.x >> 4) & 31;
  int c = blockIdx.x & 15;
  int l = threadIdx.x;
  int gl = c*128 + l;
  float raw = dtraw[((long)(b*SEQL + gl))*NHEADS + h] + dt_bias[h];
  float dt = (raw > 20.f) ? raw : log1pf(expf(raw));
  float A = -expf(A_log[h]);
  float ac = dt*A;
  __shared__ float ss[128];
  ss[l] = ac; __syncthreads();
  for (int o=1;o<128;o<<=1){
    float v = (l>=o)? ss[l-o] : 0.f;
    __syncthreads();
    ss[l] += v;
    __syncthreads();
  }
  float acs = ss[l];
  dt_t[((long)(b*NHEADS+h))*SEQL + gl] = dt;
  acs_t[((long)(b*NHEADS+h))*SEQL + gl] = acs;
}

// ---------------- causal depthwise conv + silu; split outputs -------------
// writes xdtT (b,h,p,l) = silu(conv)*dt, BT (b,n,l), CT (b,n,l)  [all bf16]
__global__ __launch_bounds__(256) void k_conv(const u16* __restrict__ xbc, const float* __restrict__ conv_w,
    const float* __restrict__ conv_b, const float* __restrict__ dt_t,
    u16* __restrict__ xdtT, u16* __restrict__ BTt, u16* __restrict__ CTt)
{
  __shared__ u16 sm[131*64];
  int idx = blockIdx.x;
  int b = idx / 576; int rem = idx % 576; int cbk = rem >> 4; int lb = rem & 15;
  int ch0 = cbk*64, l0 = lb*128;
  for (int g = threadIdx.x; g < 131*8; g += 256){
    int r = g >> 3, cg = g & 7;
    int gl = l0 - 3 + r;
    u16x8 v;
    if (gl >= 0) v = *(const u16x8*)(xbc + ((long)(b*SEQL+gl))*CONVD + ch0 + cg*8);
    else { v[0]=0;v[1]=0;v[2]=0;v[3]=0;v[4]=0;v[5]=0;v[6]=0;v[7]=0; }
    *(u16x8*)(&sm[r*64 + cg*8]) = v;
  }
  __syncthreads();
  int ci = threadIdx.x & 63, g4 = threadIdx.x >> 6;
  int chg = ch0 + ci;
  f32x4 wv = *(const f32x4*)(conv_w + chg*4);
  float bia = conv_b[chg];
  bool isX = chg < DINNER;
  int h = chg >> 6; if (h > 31) h = 31;
  int p = chg & 63;
  const float* dtrow = dt_t + ((long)(b*NHEADS+h))*SEQL + l0 + g4*32;
  u16x8 ov[4];
  #pragma unroll
  for (int i=0;i<32;i++){
    int lr = g4*32 + i;
    float a = bia + wv[0]*bf2f(sm[(lr+0)*64+ci]) + wv[1]*bf2f(sm[(lr+1)*64+ci])
                  + wv[2]*bf2f(sm[(lr+2)*64+ci]) + wv[3]*bf2f(sm[(lr+3)*64+ci]);
    float s = a / (1.f + __expf(-a));
    if (isX) s *= dtrow[i];
    ov[i>>3][i&7] = f2bf(s);
  }
  u16* dst;
  if (isX)                      dst = xdtT + (((long)(b*NHEADS+h))*HEADD + p)*SEQL + l0 + g4*32;
  else if (chg < DINNER+DSTATE) dst = BTt + ((long)(b*DSTATE + (chg-DINNER)))*SEQL + l0 + g4*32;
  else                          dst = CTt + ((long)(b*DSTATE + (chg-DINNER-DSTATE)))*SEQL + l0 + g4*32;
  #pragma unroll
  for (int q=0;q<4;q++) *(u16x8*)(dst + q*8) = ov[q];
}

// ---------------- per (b,chunk): CB = C*B^T (unmasked), and Cn (l,n) ------
__global__ __launch_bounds__(256) void k_cb(const u16* __restrict__ BTt, const u16* __restrict__ CTt,
      u16* __restrict__ CBm, u16* __restrict__ Cn)
{
  __shared__ u16 Cl[128*136];
  __shared__ u16 Bl[128*136];
  int b = blockIdx.x >> 4, c = blockIdx.x & 15;
  for (int g = threadIdx.x; g < 2048; g += 256){
    int n = g >> 4, lg = g & 15;
    u16x8 vc = *(const u16x8*)(CTt + ((long)(b*DSTATE+n))*SEQL + c*CHUNKL + lg*8);
    u16x8 vb = *(const u16x8*)(BTt + ((long)(b*DSTATE+n))*SEQL + c*CHUNKL + lg*8);
    #pragma unroll
    for (int j=0;j<8;j++){
      Cl[(lg*8+j)*136 + n] = vc[j];
      Bl[(lg*8+j)*136 + n] = vb[j];
    }
  }
  __syncthreads();
  const int tid = threadIdx.x;
  const int lane = tid & 63, wid = tid >> 6;
  const int wr = wid & 1, wc2 = wid >> 1;
  const int lidx = lane & 15, krow = lane >> 4;
  const f32x4 zf = {0.f,0.f,0.f,0.f};
  f32x4 acc[4][4];
  #pragma unroll
  for (int i=0;i<4;i++)
    #pragma unroll
    for (int j=0;j<4;j++) acc[i][j] = zf;
  #pragma unroll
  for (int k0=0;k0<128;k0+=32){
    u16x8 af[4], bfv[4];
    #pragma unroll
    for (int i=0;i<4;i++){
      af[i]  = *(const u16x8*)(&Cl[(wr*64+i*16+lidx)*136 + k0 + krow*8]);
      bfv[i] = *(const u16x8*)(&Bl[(wc2*64+i*16+lidx)*136 + k0 + krow*8]);
    }
    #pragma unroll
    for (int i=0;i<4;i++)
      #pragma unroll
      for (int j=0;j<4;j++)
        acc[i][j] = MFMA(af[i], bfv[j], acc[i][j]);
  }
  long base = ((long)(b*16+c))*128*128;
  #pragma unroll
  for (int i=0;i<4;i++)
    #pragma unroll
    for (int j=0;j<4;j++)
      #pragma unroll
      for (int r=0;r<4;r++){
        int l = wr*64+i*16+krow*4+r;
        int s = wc2*64+j*16+lidx;
        CBm[base + (long)l*128 + s] = f2bf(acc[i][j][r]);
      }
  for (int g = tid; g < 2048; g += 256){
    int l = g >> 4, ng = g & 15;
    u16x8 o;
    #pragma unroll
    for (int j=0;j<8;j++) o[j] = Cl[l*136 + ng*8 + j];
    *(u16x8*)(Cn + ((long)(b*SEQL + c*CHUNKL + l))*DSTATE + ng*8) = o;
  }
}

// ---------------- fused SSD: one wg per (b,h); sequential over chunks -----
__global__ __launch_bounds__(256) void k_ssd(
    const u16* __restrict__ Cng, const u16* __restrict__ BTt, const u16* __restrict__ xdtT,
    const u16* __restrict__ CBm, const float* __restrict__ acs_t, const float* __restrict__ dt_t,
    const float* __restrict__ Dparam, u16* __restrict__ y)
{
  __shared__ u16 Cs[128*PADC];   // C[l][n] * exp(acs[l])
  __shared__ u16 Bs[128*PADC];   // B^T[n][l] * exp(acs[last]-acs[l])
  __shared__ u16 Ps[128*PADC];   // CB[l][s]*exp(acs[l]-acs[s]) masked
  __shared__ u16 Xs[64*PADC];    // xdt^T [p][l]
  __shared__ float carry[64*132];// states_in [p][n] f32
  __shared__ float acs_s[128], eacs_s[128], dec_s[128], dtr_s[128];
  const int bh = blockIdx.x;
  const int b = bh >> 5, h = bh & 31;
  const int tid = threadIdx.x, lane = tid & 63, wid = tid >> 6;
  const int lidx = lane & 15, krow = lane >> 4;
  const int wl = wid & 1, wp = wid >> 1;
  const int wps = wid & 1, wns = wid >> 1;
  for (int i = tid; i < 64*132; i += 256) carry[i] = 0.f;
  const float Dh = Dparam[h];
  const float* acs_g = acs_t + (long)bh*SEQL;
  const float* dt_g = dt_t + (long)bh*SEQL;
  const u16* X_g = xdtT + (long)bh*HEADD*SEQL;
  const u16* B_g = BTt + (long)b*DSTATE*SEQL;
  const u16* C_g = Cng + (long)b*SEQL*DSTATE;
  const u16* CB_g = CBm + (long)b*NCHUNK*CHUNKL*CHUNKL;
  const f32x4 zf = {0.f,0.f,0.f,0.f};
  for (int c=0;c<NCHUNK;c++){
    __syncthreads();
    if (tid < 128){ acs_s[tid] = acs_g[c*128+tid]; dtr_s[tid] = dt_g[c*128+tid]; }
    __syncthreads();
    if (tid < 128){ float a = acs_s[tid]; eacs_s[tid] = __expf(a); dec_s[tid] = __expf(acs_s[127]-a); }
    __syncthreads();
    for (int g = tid; g < 2048; g += 256){
      int l = g >> 4, cb = g & 15;
      u16x8 v = *(const u16x8*)(C_g + ((long)(c*128+l))*DSTATE + cb*8);
      float e = eacs_s[l];
      u16x8 o;
      #pragma unroll
      for (int j=0;j<8;j++) o[j] = f2bf(bf2f(v[j])*e);
      *(u16x8*)(&Cs[l*PADC + cb*8]) = o;
    }
    for (int g = tid; g < 2048; g += 256){
      int n = g >> 4, lg = g & 15;
      u16x8 v = *(const u16x8*)(B_g + (long)n*SEQL + c*128 + lg*8);
      u16x8 o;
      #pragma unroll
      for (int j=0;j<8;j++) o[j] = f2bf(bf2f(v[j])*dec_s[lg*8+j]);
      *(u16x8*)(&Bs[n*PADC + lg*8]) = o;
    }
    for (int g = tid; g < 1024; g += 256){
      int p = g >> 4, lg = g & 15;
      *(u16x8*)(&Xs[p*PADC + lg*8]) = *(const u16x8*)(X_g + (long)p*SEQL + c*128 + lg*8);
    }
    {
      int l = tid >> 1, s0 = (tid & 1)*64;
      float al = acs_s[l];
      #pragma unroll
      for (int q=0;q<8;q++){
        u16x8 v = *(const u16x8*)(CB_g + ((long)(c*128+l))*CHUNKL + s0 + q*8);
        u16x8 o;
        #pragma unroll
        for (int j=0;j<8;j++){
          int s = s0 + q*8 + j;
          float pv = (s <= l) ? bf2f(v[j]) * __expf(al - acs_s[s]) : 0.f;
          o[j] = f2bf(pv);
        }
        *(u16x8*)(&Ps[l*PADC + s0 + q*8]) = o;
      }
    }
    __syncthreads();
    f32x4 accY[4][2];
    f32x4 accS[2][4];
    #pragma unroll
    for (int i=0;i<4;i++){ accY[i][0]=zf; accY[i][1]=zf; }
    #pragma unroll
    for (int i=0;i<2;i++){ accS[i][0]=zf; accS[i][1]=zf; accS[i][2]=zf; accS[i][3]=zf; }
    // Y_off += (C*eacs) @ carry^T
    #pragma unroll
    for (int k0=0;k0<128;k0+=32){
      u16x8 af[4], bfv[2];
      #pragma unroll
      for (int i=0;i<4;i++) af[i] = *(const u16x8*)(&Cs[(wl*64+i*16+lidx)*PADC + k0 + krow*8]);
      #pragma unroll
      for (int j=0;j<2;j++){
        const float* cp = &carry[(wp*32+j*16+lidx)*132 + k0 + krow*8];
        f32x4 c0 = *(const f32x4*)cp;
        f32x4 c1 = *(const f32x4*)(cp+4);
        u16x8 o;
        o[0]=f2bf(c0[0]); o[1]=f2bf(c0[1]); o[2]=f2bf(c0[2]); o[3]=f2bf(c0[3]);
        o[4]=f2bf(c1[0]); o[5]=f2bf(c1[1]); o[6]=f2bf(c1[2]); o[7]=f2bf(c1[3]);
        bfv[j] = o;
      }
      #pragma unroll
      for (int i=0;i<4;i++)
        #pragma unroll
        for (int j=0;j<2;j++)
          accY[i][j] = MFMA(af[i], bfv[j], accY[i][j]);
    }
    // Y_diag += P @ xdt
    #pragma unroll
    for (int k0=0;k0<128;k0+=32){
      u16x8 af[4], bfv[2];
      #pragma unroll
      for (int i=0;i<4;i++) af[i] = *(const u16x8*)(&Ps[(wl*64+i*16+lidx)*PADC + k0 + krow*8]);
      #pragma unroll
      for (int j=0;j<2;j++) bfv[j] = *(const u16x8*)(&Xs[(wp*32+j*16+lidx)*PADC + k0 + krow*8]);
      #pragma unroll
      for (int i=0;i<4;i++)
        #pragma unroll
        for (int j=0;j<2;j++)
          accY[i][j] = MFMA(af[i], bfv[j], accY[i][j]);
    }
    // states = xdt @ (B*decay)
    #pragma unroll
    for (int k0=0;k0<128;k0+=32){
      u16x8 as2[2], bs2[4];
      #pragma unroll
      for (int i=0;i<2;i++) as2[i] = *(const u16x8*)(&Xs[(wps*32+i*16+lidx)*PADC + k0 + krow*8]);
      #pragma unroll
      for (int j=0;j<4;j++) bs2[j] = *(const u16x8*)(&Bs[(wns*64+j*16+lidx)*PADC + k0 + krow*8]);
      #pragma unroll
      for (int i=0;i<2;i++)
        #pragma unroll
        for (int j=0;j<4;j++)
          accS[i][j] = MFMA(as2[i], bs2[j], accS[i][j]);
    }
    __syncthreads();
    float cd = __expf(acs_s[127]);
    #pragma unroll
    for (int i=0;i<2;i++)
      #pragma unroll
      for (int j=0;j<4;j++)
        #pragma unroll
        for (int r=0;r<4;r++){
          int p = wps*32 + i*16 + krow*4 + r;
          int n = wns*64 + j*16 + lidx;
          carry[p*132+n] = carry[p*132+n]*cd + accS[i][j][r];
        }
    #pragma unroll
    for (int i=0;i<4;i++)
      #pragma unroll
      for (int j=0;j<2;j++)
        #pragma unroll
        for (int r=0;r<4;r++){
          int l = wl*64 + i*16 + krow*4 + r;
          int p = wp*32 + j*16 + lidx;
          float xv = bf2f(Xs[p*PADC + l]) / dtr_s[l];
          float val = accY[i][j][r] + Dh*xv;
          y[((long)(b*SEQL + c*128 + l))*DINNER + h*HEADD + p] = f2bf(val);
        }
  }
}

// ---------------- gating (silu(z)) + RMSNorm -> bf16 ----------------------
__global__ __launch_bounds__(256) void k_gate(const u16* __restrict__ y, const u16* __restrict__ z,
    const float* __restrict__ norm_w, u16* __restrict__ out)
{
  long row = blockIdx.x;
  const u16* yr = y + row*DINNER;
  const u16* zr = z + row*DINNER;
  int t = threadIdx.x;
  u16x8 yy = *(const u16x8*)(yr + t*8);
  u16x8 zz = *(const u16x8*)(zr + t*8);
  float g[8]; float ss = 0.f;
  #pragma unroll
  for (int j=0;j<8;j++){
    float zfv = bf2f(zz[j]);
    float sg = zfv / (1.f + __expf(-zfv));
    float gv = bf2f(yy[j]) * sg;
    g[j] = gv; ss += gv*gv;
  }
  #pragma unroll
  for (int o=32;o>0;o>>=1) ss += __shfl_down(ss, o);
  __shared__ float part[4];
  int lane = t & 63, wid = t>>6;
  if (lane==0) part[wid] = ss;
  __syncthreads();
  float tot = part[0]+part[1]+part[2]+part[3];
  float inv = rsqrtf(tot*(1.f/DINNER) + 1e-5f);
  u16x8 o;
  #pragma unroll
  for (int j=0;j<8;j++) o[j] = f2bf(g[j]*inv*norm_w[t*8+j]);
  *(u16x8*)(out + row*DINNER + t*8) = o;
}

// ---------------- pred = hidden @ dec_w^T + dec_b -------------------------
__global__ __launch_bounds__(256) void k_pred(const float* __restrict__ hid, const float* __restrict__ dec_w,
    const float* __restrict__ dec_b, float* __restrict__ pred)
{
  int t = threadIdx.x;
  long row = (long)blockIdx.x*8 + (t>>5);
  int lk = t & 31;
  const float* hr = hid + row*DMODEL;
  float a0=0.f,a1=0.f,a2=0.f;
  #pragma unroll
  for (int i=0;i<8;i++){
    f32x4 hv = *(const f32x4*)(hr + lk*4 + i*128);
    f32x4 w0 = *(const f32x4*)(dec_w + 0*DMODEL + lk*4 + i*128);
    f32x4 w1 = *(const f32x4*)(dec_w + 1*DMODEL + lk*4 + i*128);
    f32x4 w2 = *(const f32x4*)(dec_w + 2*DMODEL + lk*4 + i*128);
    a0 += hv[0]*w0[0]+hv[1]*w0[1]+hv[2]*w0[2]+hv[3]*w0[3];
    a1 += hv[0]*w1[0]+hv[1]*w1[1]+hv[2]*w1[2]+hv[3]*w1[3];
    a2 += hv[0]*w2[0]+hv[1]*w2[1]+hv[2]*w2[2]+hv[3]*w2[3];
  }
  #pragma unroll
  for (int o=16;o>0;o>>=1){
    a0 += __shfl_down(a0,o,32); a1 += __shfl_down(a1,o,32); a2 += __shfl_down(a2,o,32);
  }
  if (lk==0){
    pred[row*3+0] = a0 + dec_b[0];
    pred[row*3+1] = a1 + dec_b[1];
    pred[row*3+2] = a2 + dec_b[2];
  }
}

extern "C" void kernel_launch(void* const* d_in, const int* in_sizes, int n_in,
                              void* d_out, int out_size, void* d_ws, size_t ws_size,
                              hipStream_t stream)
{
  const float* embed      = (const float*)d_in[0];
  const float* in_proj_w  = (const float*)d_in[1];
  const float* conv_w     = (const float*)d_in[2];
  const float* conv_b     = (const float*)d_in[3];
  const float* dt_bias    = (const float*)d_in[4];
  const float* A_log      = (const float*)d_in[5];
  const float* Dp         = (const float*)d_in[6];
  const float* norm_w     = (const float*)d_in[7];
  const float* out_proj_w = (const float*)d_in[8];
  const float* dec_w      = (const float*)d_in[9];
  const float* dec_b      = (const float*)d_in[10];

  char* ws = (char*)d_ws;
  size_t off = 0;
  auto alloc = [&](size_t bytes)->void*{ void* p = ws + off; off += (bytes + 255) & ~(size_t)255; return p; };

  // Region 1 (75.5 MB): xbc (GEMM1 -> conv), then y bf16 (ssd -> gate)
  u16* xbc = (u16*)alloc((size_t)MROWS*CONVD*2);
  u16* yb  = xbc;  // 67.1 MB <= 75.5 MB, xbc dead after conv
  // Region 2 (67.1 MB): Ebf+W1 (phase 1) -> xdtT (conv->ssd) -> ynorm (gate->GEMM2)
  u16* R2  = (u16*)alloc((size_t)MROWS*DINNER*2);
  u16* Ebf = R2;                                   // 33.5 MB
  u16* W1  = R2 + (size_t)MROWS*DMODEL;            // 9.2 MB, total 42.7 <= 67.1
  u16* xdtT  = R2;
  u16* ynorm = R2;
  // Small buffers (~27 MB)
  float* dtraw = (float*)alloc((size_t)MROWS*NHEADS*4);
  float* dt_t  = (float*)alloc((size_t)NBATCH*NHEADS*SEQL*4);
  float* acs   = (float*)alloc((size_t)NBATCH*NHEADS*SEQL*4);
  u16* BTt   = (u16*)alloc((size_t)NBATCH*DSTATE*SEQL*2);
  u16* CTt   = (u16*)alloc((size_t)NBATCH*DSTATE*SEQL*2);
  u16* Cn    = (u16*)alloc((size_t)NBATCH*SEQL*DSTATE*2);
  u16* CBm   = (u16*)alloc((size_t)NBATCH*NCHUNK*CHUNKL*CHUNKL*2);
  u16* W2    = (u16*)alloc((size_t)DMODEL*DINNER*2);

  if (off > ws_size){
    k_sentinel<<<1,1,0,stream>>>((float*)d_out);  // absmax ~12343 => ws_size too small
    return;
  }

  float* pred   = (float*)d_out;
  float* hidden = (float*)d_out + (size_t)MROWS*3;
  // z lives in the d_out hidden region (exact fit); dead before GEMM2 writes hidden
  u16* zb = (u16*)hidden;

  k_cvt<<<16384,256,0,stream>>>(embed, Ebf, (long)MROWS*DMODEL, (long)MROWS*DMODEL);
  k_cvt<<<4480,256,0,stream>>>(in_proj_w, W1, (long)NPROJ*DMODEL, (long)NPROJP*DMODEL);
  k_cvt<<<2048,256,0,stream>>>(out_proj_w, W2, (long)DMODEL*DINNER, (long)DMODEL*DINNER);
  {
    dim3 g1(128,35);
    k_gemm<1><<<g1,256,0,stream>>>(Ebf, W1, DMODEL, 0, nullptr, zb, xbc, dtraw);
  }
  k_dtprep<<<4096,128,0,stream>>>(dtraw, dt_bias, A_log, dt_t, acs);
  k_conv<<<4608,256,0,stream>>>(xbc, conv_w, conv_b, dt_t, xdtT, BTt, CTt);
  k_cb<<<128,256,0,stream>>>(BTt, CTt, CBm, Cn);
  k_ssd<<<256,256,0,stream>>>(Cn, BTt, xdtT, CBm, acs, dt_t, Dp, yb);
  k_gate<<<16384,256,0,stream>>>(yb, zb, norm_w, ynorm);
  {
    dim3 g2(128,8);
    k_gemm<0><<<g2,256,0,stream>>>(ynorm, W2, DINNER, DMODEL, hidden, nullptr, nullptr, nullptr);
  }
  k_pred<<<2048,256,0,stream>>>(hidden, dec_w, dec_b, pred);
}

// Round 3
// 738.279 us; speedup vs baseline: 1.0361x; 1.0361x over previous
//
#include <hip/hip_runtime.h>
#include <cstdint>

#define DEVI __device__ __forceinline__

typedef unsigned short u16;
typedef unsigned int u32;
typedef __attribute__((ext_vector_type(4))) float f32x4;
typedef __attribute__((ext_vector_type(8))) u16 u16x8;
typedef __attribute__((ext_vector_type(4))) u16 u16x4;
typedef __attribute__((ext_vector_type(8))) __bf16 bf16x8;

#define SEQL 2048
#define NBATCH 8
#define MROWS (NBATCH*SEQL)
#define DMODEL 1024
#define DINNER 2048
#define NHEADS 32
#define HEADD 64
#define DSTATE 128
#define CONVD 2304
#define NPROJ 4384
#define NPROJP 4480
#define CHUNKL 128
#define NCHUNK 16
#define PADC 136

DEVI float bf2f(u16 v){ u32 u = ((u32)v)<<16; return __builtin_bit_cast(float,u); }
DEVI u16 f2bf(float f){ u32 u = __builtin_bit_cast(u32,f); u32 r = (u + 0x7fffu + ((u>>16)&1u))>>16; return (u16)r; }

DEVI void gld_lds16(const void* g, void* lds){
  __builtin_amdgcn_global_load_lds(
    (const __attribute__((address_space(1))) void*)(uintptr_t)g,
    (__attribute__((address_space(3))) void*)(u32)(uintptr_t)lds, 16, 0, 0);
}

DEVI f32x4 MFMA(u16x8 a, u16x8 b, f32x4 c){
  return __builtin_amdgcn_mfma_f32_16x16x32_bf16(
      __builtin_bit_cast(bf16x8,a), __builtin_bit_cast(bf16x8,b), c, 0,0,0);
}

__global__ void k_sentinel(float* o){ o[0] = 12345.0f; }

// ---------------- convert f32 -> bf16 (with zero-pad tail) ----------------
__global__ __launch_bounds__(256) void k_cvt(const float* __restrict__ src, u16* __restrict__ dst, long n, long ntot){
  long idx = ((long)blockIdx.x*256 + threadIdx.x)*4;
  if (idx >= ntot) return;
  u16x4 o;
  if (idx < n){
    f32x4 v = *(const f32x4*)(src+idx);
    o[0]=f2bf(v[0]); o[1]=f2bf(v[1]); o[2]=f2bf(v[2]); o[3]=f2bf(v[3]);
  } else { o[0]=0; o[1]=0; o[2]=0; o[3]=0; }
  *(u16x4*)(dst+idx) = o;
}

// ---------------- GEMM: C = A * B^T, A (M,K) bf16, Bt (N,K) bf16 ----------
// m97 structure: 128^2 tile, BK=64, global_load_lds width-16 staging.
// MODE 0: plain f32 out (ld = Ndim). MODE 1: split epilogue for GEMM1.
template<int MODE>
__global__ __launch_bounds__(256) void k_gemm(const u16* __restrict__ A, const u16* __restrict__ Bt,
    int K, int Ndim, float* __restrict__ outF,
    u16* __restrict__ z_out, u16* __restrict__ xbc_out, float* __restrict__ dtraw_out)
{
  __shared__ u16 sA[128*64];
  __shared__ u16 sB[128*64];
  const int tid = threadIdx.x;
  const int m0 = blockIdx.x * 128;
  const int n0 = blockIdx.y * 128;
  const int lane = tid & 63, wid = tid >> 6;
  const int wr = wid & 1, wc = wid >> 1;
  const int lidx = lane & 15, krow = lane >> 4;
  const f32x4 zf = {0.f,0.f,0.f,0.f};
  f32x4 acc[4][4];
  #pragma unroll
  for (int i=0;i<4;i++)
    #pragma unroll
    for (int j=0;j<4;j++) acc[i][j] = zf;
  const int r8 = tid >> 3, c8 = tid & 7;
  const u16* Ag = A + (long)(m0 + r8)*K + c8*8;
  const u16* Bg = Bt + (long)(n0 + r8)*K + c8*8;
  char* sAb = (char*)sA + tid*16;
  char* sBb = (char*)sB + tid*16;
  for (int k0=0; k0<K; k0+=64){
    #pragma unroll
    for (int i=0;i<4;i++){
      gld_lds16(Ag + (long)i*32*K + k0, sAb + i*4096);
      gld_lds16(Bg + (long)i*32*K + k0, sBb + i*4096);
    }
    asm volatile("s_waitcnt vmcnt(0)" ::: "memory");
    __syncthreads();
    #pragma unroll
    for (int kk=0; kk<64; kk+=32){
      u16x8 af[4], bfv[4];
      #pragma unroll
      for (int i=0;i<4;i++){
        af[i]  = *(const u16x8*)(&sA[(wr*64 + i*16 + lidx)*64 + kk + krow*8]);
        bfv[i] = *(const u16x8*)(&sB[(wc*64 + i*16 + lidx)*64 + kk + krow*8]);
      }
      #pragma unroll
      for (int i=0;i<4;i++)
        #pragma unroll
        for (int j=0;j<4;j++)
          acc[i][j] = MFMA(af[i], bfv[j], acc[i][j]);
    }
    __syncthreads();
  }
  #pragma unroll
  for (int i=0;i<4;i++)
    #pragma unroll
    for (int j=0;j<4;j++)
      #pragma unroll
      for (int r=0;r<4;r++){
        int gm = m0 + wr*64 + i*16 + krow*4 + r;
        int gn = n0 + wc*64 + j*16 + lidx;
        float v = acc[i][j][r];
        if (MODE==0){
          outF[(long)gm*Ndim + gn] = v;
        } else {
          if (gn < DINNER) z_out[(long)gm*DINNER + gn] = f2bf(v);
          else if (gn < DINNER+CONVD) xbc_out[(long)gm*CONVD + (gn-DINNER)] = f2bf(v);
          else if (gn < NPROJ) dtraw_out[(long)gm*NHEADS + (gn-DINNER-CONVD)] = v;
        }
      }
}

// ---------------- dt prep: softplus + per-chunk inclusive cumsum ----------
__global__ __launch_bounds__(128) void k_dtprep(const float* __restrict__ dtraw, const float* __restrict__ dt_bias,
    const float* __restrict__ A_log, float* __restrict__ dt_t, float* __restrict__ acs_t)
{
  int b = blockIdx.x >> 9;
  int h = (blockIdx.x >> 4) & 31;
  int c = blockIdx.x & 15;
  int l = threadIdx.x;
  int gl = c*128 + l;
  float raw = dtraw[((long)(b*SEQL + gl))*NHEADS + h] + dt_bias[h];
  float dt = (raw > 20.f) ? raw : log1pf(expf(raw));
  float A = -expf(A_log[h]);
  float ac = dt*A;
  __shared__ float ss[128];
  ss[l] = ac; __syncthreads();
  for (int o=1;o<128;o<<=1){
    float v = (l>=o)? ss[l-o] : 0.f;
    __syncthreads();
    ss[l] += v;
    __syncthreads();
  }
  float acs = ss[l];
  dt_t[((long)(b*NHEADS+h))*SEQL + gl] = dt;
  acs_t[((long)(b*NHEADS+h))*SEQL + gl] = acs;
}

// ---------------- causal depthwise conv + silu; split outputs -------------
// writes xdtT (b,h,p,l) = silu(conv)*dt, BT (b,n,l), CT (b,n,l)  [all bf16]
__global__ __launch_bounds__(256) void k_conv(const u16* __restrict__ xbc, const float* __restrict__ conv_w,
    const float* __restrict__ conv_b, const float* __restrict__ dt_t,
    u16* __restrict__ xdtT, u16* __restrict__ BTt, u16* __restrict__ CTt)
{
  __shared__ u16 sm[131*64];
  int idx = blockIdx.x;
  int b = idx / 576; int rem = idx % 576; int cbk = rem >> 4; int lb = rem & 15;
  int ch0 = cbk*64, l0 = lb*128;
  for (int g = threadIdx.x; g < 131*8; g += 256){
    int r = g >> 3, cg = g & 7;
    int gl = l0 - 3 + r;
    u16x8 v;
    if (gl >= 0) v = *(const u16x8*)(xbc + ((long)(b*SEQL+gl))*CONVD + ch0 + cg*8);
    else { v[0]=0;v[1]=0;v[2]=0;v[3]=0;v[4]=0;v[5]=0;v[6]=0;v[7]=0; }
    *(u16x8*)(&sm[r*64 + cg*8]) = v;
  }
  __syncthreads();
  int ci = threadIdx.x & 63, g4 = threadIdx.x >> 6;
  int chg = ch0 + ci;
  f32x4 wv = *(const f32x4*)(conv_w + chg*4);
  float bia = conv_b[chg];
  bool isX = chg < DINNER;
  int h = chg >> 6; if (h > 31) h = 31;
  int p = chg & 63;
  const float* dtrow = dt_t + ((long)(b*NHEADS+h))*SEQL + l0 + g4*32;
  u16x8 ov[4];
  #pragma unroll
  for (int i=0;i<32;i++){
    int lr = g4*32 + i;
    float a = bia + wv[0]*bf2f(sm[(lr+0)*64+ci]) + wv[1]*bf2f(sm[(lr+1)*64+ci])
                  + wv[2]*bf2f(sm[(lr+2)*64+ci]) + wv[3]*bf2f(sm[(lr+3)*64+ci]);
    float s = a / (1.f + __expf(-a));
    if (isX) s *= dtrow[i];
    ov[i>>3][i&7] = f2bf(s);
  }
  u16* dst;
  if (isX)                      dst = xdtT + (((long)(b*NHEADS+h))*HEADD + p)*SEQL + l0 + g4*32;
  else if (chg < DINNER+DSTATE) dst = BTt + ((long)(b*DSTATE + (chg-DINNER)))*SEQL + l0 + g4*32;
  else                          dst = CTt + ((long)(b*DSTATE + (chg-DINNER-DSTATE)))*SEQL + l0 + g4*32;
  #pragma unroll
  for (int q=0;q<4;q++) *(u16x8*)(dst + q*8) = ov[q];
}

// ---------------- per (b,chunk): CB = C*B^T (unmasked), and Cn (l,n) ------
__global__ __launch_bounds__(256) void k_cb(const u16* __restrict__ BTt, const u16* __restrict__ CTt,
      u16* __restrict__ CBm, u16* __restrict__ Cn)
{
  __shared__ u16 Cl[128*136];
  __shared__ u16 Bl[128*136];
  int b = blockIdx.x >> 4, c = blockIdx.x & 15;
  for (int g = threadIdx.x; g < 2048; g += 256){
    int n = g >> 4, lg = g & 15;
    u16x8 vc = *(const u16x8*)(CTt + ((long)(b*DSTATE+n))*SEQL + c*CHUNKL + lg*8);
    u16x8 vb = *(const u16x8*)(BTt + ((long)(b*DSTATE+n))*SEQL + c*CHUNKL + lg*8);
    #pragma unroll
    for (int j=0;j<8;j++){
      Cl[(lg*8+j)*136 + n] = vc[j];
      Bl[(lg*8+j)*136 + n] = vb[j];
    }
  }
  __syncthreads();
  const int tid = threadIdx.x;
  const int lane = tid & 63, wid = tid >> 6;
  const int wr = wid & 1, wc2 = wid >> 1;
  const int lidx = lane & 15, krow = lane >> 4;
  const f32x4 zf = {0.f,0.f,0.f,0.f};
  f32x4 acc[4][4];
  #pragma unroll
  for (int i=0;i<4;i++)
    #pragma unroll
    for (int j=0;j<4;j++) acc[i][j] = zf;
  #pragma unroll
  for (int k0=0;k0<128;k0+=32){
    u16x8 af[4], bfv[4];
    #pragma unroll
    for (int i=0;i<4;i++){
      af[i]  = *(const u16x8*)(&Cl[(wr*64+i*16+lidx)*136 + k0 + krow*8]);
      bfv[i] = *(const u16x8*)(&Bl[(wc2*64+i*16+lidx)*136 + k0 + krow*8]);
    }
    #pragma unroll
    for (int i=0;i<4;i++)
      #pragma unroll
      for (int j=0;j<4;j++)
        acc[i][j] = MFMA(af[i], bfv[j], acc[i][j]);
  }
  long base = ((long)(b*16+c))*128*128;
  #pragma unroll
  for (int i=0;i<4;i++)
    #pragma unroll
    for (int j=0;j<4;j++)
      #pragma unroll
      for (int r=0;r<4;r++){
        int l = wr*64+i*16+krow*4+r;
        int s = wc2*64+j*16+lidx;
        CBm[base + (long)l*128 + s] = f2bf(acc[i][j][r]);
      }
  for (int g = tid; g < 2048; g += 256){
    int l = g >> 4, ng = g & 15;
    u16x8 o;
    #pragma unroll
    for (int j=0;j<8;j++) o[j] = Cl[l*136 + ng*8 + j];
    *(u16x8*)(Cn + ((long)(b*SEQL + c*CHUNKL + l))*DSTATE + ng*8) = o;
  }
}

// ---------------- fused SSD: one wg per (b,h); sequential over chunks -----
__global__ __launch_bounds__(256) void k_ssd(
    const u16* __restrict__ Cng, const u16* __restrict__ BTt, const u16* __restrict__ xdtT,
    const u16* __restrict__ CBm, const float* __restrict__ acs_t, const float* __restrict__ dt_t,
    const float* __restrict__ Dparam, u16* __restrict__ y)
{
  __shared__ u16 Cs[128*PADC];   // C[l][n] * exp(acs[l])
  __shared__ u16 Bs[128*PADC];   // B^T[n][l] * exp(acs[last]-acs[l])
  __shared__ u16 Ps[128*PADC];   // CB[l][s]*exp(acs[l]-acs[s]) masked
  __shared__ u16 Xs[64*PADC];    // xdt^T [p][l]
  __shared__ float carry[64*132];// states_in [p][n] f32
  __shared__ float acs_s[128], eacs_s[128], dec_s[128], dtr_s[128];
  const int bh = blockIdx.x;
  const int b = bh >> 5, h = bh & 31;
  const int tid = threadIdx.x, lane = tid & 63, wid = tid >> 6;
  const int lidx = lane & 15, krow = lane >> 4;
  const int wl = wid & 1, wp = wid >> 1;
  const int wps = wid & 1, wns = wid >> 1;
  for (int i = tid; i < 64*132; i += 256) carry[i] = 0.f;
  const float Dh = Dparam[h];
  const float* acs_g = acs_t + (long)bh*SEQL;
  const float* dt_g = dt_t + (long)bh*SEQL;
  const u16* X_g = xdtT + (long)bh*HEADD*SEQL;
  const u16* B_g = BTt + (long)b*DSTATE*SEQL;
  const u16* C_g = Cng + (long)b*SEQL*DSTATE;
  const u16* CB_g = CBm + (long)b*NCHUNK*CHUNKL*CHUNKL;
  const f32x4 zf = {0.f,0.f,0.f,0.f};
  for (int c=0;c<NCHUNK;c++){
    __syncthreads();
    if (tid < 128){ acs_s[tid] = acs_g[c*128+tid]; dtr_s[tid] = dt_g[c*128+tid]; }
    __syncthreads();
    if (tid < 128){ float a = acs_s[tid]; eacs_s[tid] = __expf(a); dec_s[tid] = __expf(acs_s[127]-a); }
    __syncthreads();
    for (int g = tid; g < 2048; g += 256){
      int l = g >> 4, cb = g & 15;
      u16x8 v = *(const u16x8*)(C_g + ((long)(c*128+l))*DSTATE + cb*8);
      float e = eacs_s[l];
      u16x8 o;
      #pragma unroll
      for (int j=0;j<8;j++) o[j] = f2bf(bf2f(v[j])*e);
      *(u16x8*)(&Cs[l*PADC + cb*8]) = o;
    }
    for (int g = tid; g < 2048; g += 256){
      int n = g >> 4, lg = g & 15;
      u16x8 v = *(const u16x8*)(B_g + (long)n*SEQL + c*128 + lg*8);
      u16x8 o;
      #pragma unroll
      for (int j=0;j<8;j++) o[j] = f2bf(bf2f(v[j])*dec_s[lg*8+j]);
      *(u16x8*)(&Bs[n*PADC + lg*8]) = o;
    }
    for (int g = tid; g < 1024; g += 256){
      int p = g >> 4, lg = g & 15;
      *(u16x8*)(&Xs[p*PADC + lg*8]) = *(const u16x8*)(X_g + (long)p*SEQL + c*128 + lg*8);
    }
    {
      int l = tid >> 1, s0 = (tid & 1)*64;
      float al = acs_s[l];
      #pragma unroll
      for (int q=0;q<8;q++){
        u16x8 v = *(const u16x8*)(CB_g + ((long)(c*128+l))*CHUNKL + s0 + q*8);
        u16x8 o;
        #pragma unroll
        for (int j=0;j<8;j++){
          int s = s0 + q*8 + j;
          float pv = (s <= l) ? bf2f(v[j]) * __expf(al - acs_s[s]) : 0.f;
          o[j] = f2bf(pv);
        }
        *(u16x8*)(&Ps[l*PADC + s0 + q*8]) = o;
      }
    }
    __syncthreads();
    f32x4 accY[4][2];
    f32x4 accS[2][4];
    #pragma unroll
    for (int i=0;i<4;i++){ accY[i][0]=zf; accY[i][1]=zf; }
    #pragma unroll
    for (int i=0;i<2;i++){ accS[i][0]=zf; accS[i][1]=zf; accS[i][2]=zf; accS[i][3]=zf; }
    // Y_off += (C*eacs) @ carry^T
    #pragma unroll
    for (int k0=0;k0<128;k0+=32){
      u16x8 af[4], bfv[2];
      #pragma unroll
      for (int i=0;i<4;i++) af[i] = *(const u16x8*)(&Cs[(wl*64+i*16+lidx)*PADC + k0 + krow*8]);
      #pragma unroll
      for (int j=0;j<2;j++){
        const float* cp = &carry[(wp*32+j*16+lidx)*132 + k0 + krow*8];
        f32x4 c0 = *(const f32x4*)cp;
        f32x4 c1 = *(const f32x4*)(cp+4);
        u16x8 o;
        o[0]=f2bf(c0[0]); o[1]=f2bf(c0[1]); o[2]=f2bf(c0[2]); o[3]=f2bf(c0[3]);
        o[4]=f2bf(c1[0]); o[5]=f2bf(c1[1]); o[6]=f2bf(c1[2]); o[7]=f2bf(c1[3]);
        bfv[j] = o;
      }
      #pragma unroll
      for (int i=0;i<4;i++)
        #pragma unroll
        for (int j=0;j<2;j++)
          accY[i][j] = MFMA(af[i], bfv[j], accY[i][j]);
    }
    // Y_diag += P @ xdt
    #pragma unroll
    for (int k0=0;k0<128;k0+=32){
      u16x8 af[4], bfv[2];
      #pragma unroll
      for (int i=0;i<4;i++) af[i] = *(const u16x8*)(&Ps[(wl*64+i*16+lidx)*PADC + k0 + krow*8]);
      #pragma unroll
      for (int j=0;j<2;j++) bfv[j] = *(const u16x8*)(&Xs[(wp*32+j*16+lidx)*PADC + k0 + krow*8]);
      #pragma unroll
      for (int i=0;i<4;i++)
        #pragma unroll
        for (int j=0;j<2;j++)
          accY[i][j] = MFMA(af[i], bfv[j], accY[i][j]);
    }
    // states = xdt @ (B*decay)
    #pragma unroll
    for (int k0=0;k0<128;k0+=32){
      u16x8 as2[2], bs2[4];
      #pragma unroll
      for (int i=0;i<2;i++) as2[i] = *(const u16x8*)(&Xs[(wps*32+i*16+lidx)*PADC + k0 + krow*8]);
      #pragma unroll
      for (int j=0;j<4;j++) bs2[j] = *(const u16x8*)(&Bs[(wns*64+j*16+lidx)*PADC + k0 + krow*8]);
      #pragma unroll
      for (int i=0;i<2;i++)
        #pragma unroll
        for (int j=0;j<4;j++)
          accS[i][j] = MFMA(as2[i], bs2[j], accS[i][j]);
    }
    __syncthreads();
    float cd = __expf(acs_s[127]);
    #pragma unroll
    for (int i=0;i<2;i++)
      #pragma unroll
      for (int j=0;j<4;j++)
        #pragma unroll
        for (int r=0;r<4;r++){
          int p = wps*32 + i*16 + krow*4 + r;
          int n = wns*64 + j*16 + lidx;
          carry[p*132+n] = carry[p*132+n]*cd + accS[i][j][r];
        }
    #pragma unroll
    for (int i=0;i<4;i++)
      #pragma unroll
      for (int j=0;j<2;j++)
        #pragma unroll
        for (int r=0;r<4;r++){
          int l = wl*64 + i*16 + krow*4 + r;
          int p = wp*32 + j*16 + lidx;
          float xv = bf2f(Xs[p*PADC + l]) / dtr_s[l];
          float val = accY[i][j][r] + Dh*xv;
          y[((long)(b*SEQL + c*128 + l))*DINNER + h*HEADD + p] = f2bf(val);
        }
  }
}

// ---------------- gating (silu(z)) + RMSNorm -> bf16 ----------------------
__global__ __launch_bounds__(256) void k_gate(const u16* __restrict__ y, const u16* __restrict__ z,
    const float* __restrict__ norm_w, u16* __restrict__ out)
{
  long row = blockIdx.x;
  const u16* yr = y + row*DINNER;
  const u16* zr = z + row*DINNER;
  int t = threadIdx.x;
  u16x8 yy = *(const u16x8*)(yr + t*8);
  u16x8 zz = *(const u16x8*)(zr + t*8);
  float g[8]; float ss = 0.f;
  #pragma unroll
  for (int j=0;j<8;j++){
    float zfv = bf2f(zz[j]);
    float sg = zfv / (1.f + __expf(-zfv));
    float gv = bf2f(yy[j]) * sg;
    g[j] = gv; ss += gv*gv;
  }
  #pragma unroll
  for (int o=32;o>0;o>>=1) ss += __shfl_down(ss, o);
  __shared__ float part[4];
  int lane = t & 63, wid = t>>6;
  if (lane==0) part[wid] = ss;
  __syncthreads();
  float tot = part[0]+part[1]+part[2]+part[3];
  float inv = rsqrtf(tot*(1.f/DINNER) + 1e-5f);
  u16x8 o;
  #pragma unroll
  for (int j=0;j<8;j++) o[j] = f2bf(g[j]*inv*norm_w[t*8+j]);
  *(u16x8*)(out + row*DINNER + t*8) = o;
}

// ---------------- pred = hidden @ dec_w^T + dec_b -------------------------
__global__ __launch_bounds__(256) void k_pred(const float* __restrict__ hid, const float* __restrict__ dec_w,
    const float* __restrict__ dec_b, float* __restrict__ pred)
{
  int t = threadIdx.x;
  long row = (long)blockIdx.x*8 + (t>>5);
  int lk = t & 31;
  const float* hr = hid + row*DMODEL;
  float a0=0.f,a1=0.f,a2=0.f;
  #pragma unroll
  for (int i=0;i<8;i++){
    f32x4 hv = *(const f32x4*)(hr + lk*4 + i*128);
    f32x4 w0 = *(const f32x4*)(dec_w + 0*DMODEL + lk*4 + i*128);
    f32x4 w1 = *(const f32x4*)(dec_w + 1*DMODEL + lk*4 + i*128);
    f32x4 w2 = *(const f32x4*)(dec_w + 2*DMODEL + lk*4 + i*128);
    a0 += hv[0]*w0[0]+hv[1]*w0[1]+hv[2]*w0[2]+hv[3]*w0[3];
    a1 += hv[0]*w1[0]+hv[1]*w1[1]+hv[2]*w1[2]+hv[3]*w1[3];
    a2 += hv[0]*w2[0]+hv[1]*w2[1]+hv[2]*w2[2]+hv[3]*w2[3];
  }
  #pragma unroll
  for (int o=16;o>0;o>>=1){
    a0 += __shfl_down(a0,o,32); a1 += __shfl_down(a1,o,32); a2 += __shfl_down(a2,o,32);
  }
  if (lk==0){
    pred[row*3+0] = a0 + dec_b[0];
    pred[row*3+1] = a1 + dec_b[1];
    pred[row*3+2] = a2 + dec_b[2];
  }
}

extern "C" void kernel_launch(void* const* d_in, const int* in_sizes, int n_in,
                              void* d_out, int out_size, void* d_ws, size_t ws_size,
                              hipStream_t stream)
{
  const float* embed      = (const float*)d_in[0];
  const float* in_proj_w  = (const float*)d_in[1];
  const float* conv_w     = (const float*)d_in[2];
  const float* conv_b     = (const float*)d_in[3];
  const float* dt_bias    = (const float*)d_in[4];
  const float* A_log      = (const float*)d_in[5];
  const float* Dp         = (const float*)d_in[6];
  const float* norm_w     = (const float*)d_in[7];
  const float* out_proj_w = (const float*)d_in[8];
  const float* dec_w      = (const float*)d_in[9];
  const float* dec_b      = (const float*)d_in[10];

  char* ws = (char*)d_ws;
  size_t off = 0;
  auto alloc = [&](size_t bytes)->void*{ void* p = ws + off; off += (bytes + 255) & ~(size_t)255; return p; };

  // Region 1 (75.5 MB): xbc (GEMM1 -> conv), then y bf16 (ssd -> gate)
  u16* xbc = (u16*)alloc((size_t)MROWS*CONVD*2);
  u16* yb  = xbc;  // 67.1 MB <= 75.5 MB, xbc dead after conv
  // Region 2 (67.1 MB): Ebf+W1 (phase 1) -> xdtT (conv->ssd) -> ynorm (gate->GEMM2)
  u16* R2  = (u16*)alloc((size_t)MROWS*DINNER*2);
  u16* Ebf = R2;                                   // 33.5 MB
  u16* W1  = R2 + (size_t)MROWS*DMODEL;            // 9.2 MB, total 42.7 <= 67.1
  u16* xdtT  = R2;
  u16* ynorm = R2;
  // Small buffers (~27 MB)
  float* dtraw = (float*)alloc((size_t)MROWS*NHEADS*4);
  float* dt_t  = (float*)alloc((size_t)NBATCH*NHEADS*SEQL*4);
  float* acs   = (float*)alloc((size_t)NBATCH*NHEADS*SEQL*4);
  u16* BTt   = (u16*)alloc((size_t)NBATCH*DSTATE*SEQL*2);
  u16* CTt   = (u16*)alloc((size_t)NBATCH*DSTATE*SEQL*2);
  u16* Cn    = (u16*)alloc((size_t)NBATCH*SEQL*DSTATE*2);
  u16* CBm   = (u16*)alloc((size_t)NBATCH*NCHUNK*CHUNKL*CHUNKL*2);
  u16* W2    = (u16*)alloc((size_t)DMODEL*DINNER*2);

  if (off > ws_size){
    k_sentinel<<<1,1,0,stream>>>((float*)d_out);  // absmax ~12343 => ws_size too small
    return;
  }

  float* pred   = (float*)d_out;
  float* hidden = (float*)d_out + (size_t)MROWS*3;
  // z lives in the d_out hidden region (exact fit); dead before GEMM2 writes hidden
  u16* zb = (u16*)hidden;

  k_cvt<<<16384,256,0,stream>>>(embed, Ebf, (long)MROWS*DMODEL, (long)MROWS*DMODEL);
  k_cvt<<<4480,256,0,stream>>>(in_proj_w, W1, (long)NPROJ*DMODEL, (long)NPROJP*DMODEL);
  k_cvt<<<2048,256,0,stream>>>(out_proj_w, W2, (long)DMODEL*DINNER, (long)DMODEL*DINNER);
  {
    dim3 g1(128,35);
    k_gemm<1><<<g1,256,0,stream>>>(Ebf, W1, DMODEL, 0, nullptr, zb, xbc, dtraw);
  }
  k_dtprep<<<4096,128,0,stream>>>(dtraw, dt_bias, A_log, dt_t, acs);
  k_conv<<<4608,256,0,stream>>>(xbc, conv_w, conv_b, dt_t, xdtT, BTt, CTt);
  k_cb<<<128,256,0,stream>>>(BTt, CTt, CBm, Cn);
  k_ssd<<<256,256,0,stream>>>(Cn, BTt, xdtT, CBm, acs, dt_t, Dp, yb);
  k_gate<<<16384,256,0,stream>>>(yb, zb, norm_w, ynorm);
  {
    dim3 g2(128,8);
    k_gemm<0><<<g2,256,0,stream>>>(ynorm, W2, DINNER, DMODEL, hidden, nullptr, nullptr, nullptr);
  }
  k_pred<<<2048,256,0,stream>>>(hidden, dec_w, dec_b, pred);
}

// Round 4
// 647.955 us; speedup vs baseline: 1.1805x; 1.1394x over previous
//
#include <hip/hip_runtime.h>
#include <cstdint>

#define DEVI __device__ __forceinline__

typedef unsigned short u16;
typedef unsigned int u32;
typedef __attribute__((ext_vector_type(4))) float f32x4;
typedef __attribute__((ext_vector_type(8))) u16 u16x8;
typedef __attribute__((ext_vector_type(4))) u16 u16x4;
typedef __attribute__((ext_vector_type(8))) __bf16 bf16x8;

#define SEQL 2048
#define NBATCH 8
#define MROWS (NBATCH*SEQL)
#define DMODEL 1024
#define DINNER 2048
#define NHEADS 32
#define HEADD 64
#define DSTATE 128
#define CONVD 2304
#define NPROJ 4384
#define NPROJP 4608
#define CHUNKL 128
#define NCHUNK 16
#define PADC 136

DEVI float bf2f(u16 v){ u32 u = ((u32)v)<<16; return __builtin_bit_cast(float,u); }
DEVI u16 f2bf(float f){ u32 u = __builtin_bit_cast(u32,f); u32 r = (u + 0x7fffu + ((u>>16)&1u))>>16; return (u16)r; }

DEVI void gld_lds16(const void* g, void* lds){
  __builtin_amdgcn_global_load_lds(
    (const __attribute__((address_space(1))) void*)(uintptr_t)g,
    (__attribute__((address_space(3))) void*)(u32)(uintptr_t)lds, 16, 0, 0);
}

DEVI f32x4 MFMA(u16x8 a, u16x8 b, f32x4 c){
  return __builtin_amdgcn_mfma_f32_16x16x32_bf16(
      __builtin_bit_cast(bf16x8,a), __builtin_bit_cast(bf16x8,b), c, 0,0,0);
}

__global__ void k_sentinel(float* o){ o[0] = 12345.0f; }

// ---------------- convert f32 -> bf16 (with zero-pad tail) ----------------
__global__ __launch_bounds__(256) void k_cvt(const float* __restrict__ src, u16* __restrict__ dst, long n, long ntot){
  long idx = ((long)blockIdx.x*256 + threadIdx.x)*4;
  if (idx >= ntot) return;
  u16x4 o;
  if (idx < n){
    f32x4 v = *(const f32x4*)(src+idx);
    o[0]=f2bf(v[0]); o[1]=f2bf(v[1]); o[2]=f2bf(v[2]); o[3]=f2bf(v[3]);
  } else { o[0]=0; o[1]=0; o[2]=0; o[3]=0; }
  *(u16x4*)(dst+idx) = o;
}

// ================= 256^2 8-phase GEMM (T1+T2+T3+T4+T5) ====================
// C = A * Bt^T. A (M,K) bf16, Bt (N,K) bf16. 512 thr, 128KB dynamic LDS.
// LDS map (bytes): A(d,h) at (d*2+h)*16384 ; B(d,h) at 65536 + (d*2+h)*16384.
// Within a 16KB half: linear stage dest tid*16+L*8192; logical row r=L*64+tid/8,
// granule slot s holds global granule s^(r&7) (XOR swizzle, involution).
#define STG(mat, h, ts) do { \
    const int d_ = (ts) & 1; \
    const size_t ko_ = (size_t)(((ts) < NT) ? (ts) : (NT-1)) * 64; \
    gld_lds16(sbase[mat][h][0] + ko_, (char*)lds + (mat)*65536 + (d_*2+(h))*16384 + tid*16); \
    gld_lds16(sbase[mat][h][1] + ko_, (char*)lds + (mat)*65536 + (d_*2+(h))*16384 + 8192 + tid*16); \
  } while(0)

#define LDA8(AF, d_, qm) { \
    _Pragma("unroll") for (int mf=0; mf<4; mf++) \
    _Pragma("unroll") for (int ks=0; ks<2; ks++) \
      AF[mf][ks] = *(const u16x8*)(lds + (size_t)((d_)*2+wm)*8192 + ((qm)*64+mf*16+lidx)*64 + ((ks*4+krow)^(lidx&7))*8); }

#define LDB4(BF, d_, qn) { \
    _Pragma("unroll") for (int nf=0; nf<2; nf++) \
    _Pragma("unroll") for (int ks=0; ks<2; ks++) \
      BF[nf][ks] = *(const u16x8*)(lds + 32768 + (size_t)((d_)*2+(wn>>1))*8192 + ((wn&1)*64+(qn)*32+nf*16+lidx)*64 + ((ks*4+krow)^(lidx&7))*8); }

#define MMAQ(QM, QN, AF, BF) { \
    _Pragma("unroll") for (int mf=0; mf<4; mf++) \
    _Pragma("unroll") for (int nf=0; nf<2; nf++) \
    _Pragma("unroll") for (int ks=0; ks<2; ks++) \
      acc[(QM)*4+mf][(QN)*2+nf] = MFMA(AF[mf][ks], BF[nf][ks], acc[(QM)*4+mf][(QN)*2+nf]); }

#define BAR1 __builtin_amdgcn_sched_barrier(0); __builtin_amdgcn_s_barrier(); \
    asm volatile("s_waitcnt lgkmcnt(0)" ::: "memory"); __builtin_amdgcn_sched_barrier(0); \
    __builtin_amdgcn_s_setprio(1);
#define BAR2 __builtin_amdgcn_s_setprio(0); __builtin_amdgcn_sched_barrier(0); \
    __builtin_amdgcn_s_barrier(); __builtin_amdgcn_sched_barrier(0);

template<int MODE>
__global__ __launch_bounds__(512, 2) void k_gemm8(const u16* __restrict__ A, const u16* __restrict__ Bt,
    const int K, const int Ndim, float* __restrict__ outF,
    u16* __restrict__ z_out, u16* __restrict__ xbc_out, float* __restrict__ dtraw_out)
{
  extern __shared__ u16 lds[];
  const int NT = K >> 6;
  const int tid = threadIdx.x;
  const int lane = tid & 63, wid = tid >> 6;
  const int wm = wid >> 2, wn = wid & 3;
  const int lidx = lane & 15, krow = lane >> 4;
  // XCD-bijective swizzle (nwg % 8 == 0 for both launches)
  const int nwg = gridDim.x * gridDim.y;
  const int orig = blockIdx.y * gridDim.x + blockIdx.x;
  const int swz = (orig & 7) * (nwg >> 3) + (orig >> 3);
  const int m0 = (swz % gridDim.x) * 256;
  const int n0 = (swz / gridDim.x) * 256;

  f32x4 acc[8][4];
  const f32x4 zf = {0.f,0.f,0.f,0.f};
  #pragma unroll
  for (int i=0;i<8;i++)
    #pragma unroll
    for (int j=0;j<4;j++) acc[i][j] = zf;

  // stage source bases [mat][h][L]; global col pre-swizzled: granule (tid&7)^(r&7)
  const int r0 = tid >> 3;
  const int gsw = ((tid & 7) ^ (r0 & 7)) * 8;
  const u16* sbase[2][2][2];
  #pragma unroll
  for (int h=0; h<2; h++)
    #pragma unroll
    for (int L=0; L<2; L++){
      sbase[0][h][L] = A  + (size_t)(m0 + h*128 + L*64 + r0)*K + gsw;
      sbase[1][h][L] = Bt + (size_t)(n0 + h*128 + L*64 + r0)*K + gsw;
    }

  // prologue: tile0 full + 3 half-tiles of tile1 (SB1(1) staged in loop P1)
  STG(0,0,0); STG(0,1,0); STG(1,0,0); STG(1,1,0);
  asm volatile("s_waitcnt vmcnt(4)" ::: "memory");
  STG(0,0,1); STG(0,1,1); STG(1,0,1);
  asm volatile("s_waitcnt vmcnt(6)" ::: "memory");
  __builtin_amdgcn_sched_barrier(0);
  __builtin_amdgcn_s_barrier();
  __builtin_amdgcn_sched_barrier(0);

  u16x8 af[4][2], bf0[2][2], bf1[2][2];
  for (int t = 0; t < NT; t += 2){
    // ---- tile t (buf0) ----
    // P1: q(m0,n0)
    LDA8(af, 0, 0); LDB4(bf0, 0, 0); STG(1,1,t+1);
    BAR1; MMAQ(0,0,af,bf0); BAR2;
    // P2: q(m0,n1)
    LDB4(bf1, 0, 1);
    BAR1; MMAQ(0,1,af,bf1); BAR2;
    // P3: q(m1,n1)   (A-halves of buf0 free after this phase's reads issue set)
    LDA8(af, 0, 1); STG(1,0,t+2);
    BAR1; MMAQ(1,1,af,bf1); BAR2;
    // P4: q(m1,n0)
    STG(0,0,t+2); STG(0,1,t+2);
    asm volatile("s_waitcnt vmcnt(6)" ::: "memory");
    BAR1; MMAQ(1,0,af,bf0); BAR2;
    // ---- tile t+1 (buf1) ----
    // P5
    LDA8(af, 1, 0); LDB4(bf0, 1, 0); STG(1,1,t+2);
    BAR1; MMAQ(0,0,af,bf0); BAR2;
    // P6
    LDB4(bf1, 1, 1);
    BAR1; MMAQ(0,1,af,bf1); BAR2;
    // P7
    LDA8(af, 1, 1); STG(1,0,t+3);
    BAR1; MMAQ(1,1,af,bf1); BAR2;
    // P8
    STG(0,0,t+3); STG(0,1,t+3);
    asm volatile("s_waitcnt vmcnt(6)" ::: "memory");
    BAR1; MMAQ(1,0,af,bf0); BAR2;
  }
  asm volatile("s_waitcnt vmcnt(0)" ::: "memory"); // drain stray prefetch before wg exit

  #pragma unroll
  for (int im=0; im<8; im++)
    #pragma unroll
    for (int in=0; in<4; in++)
      #pragma unroll
      for (int r=0; r<4; r++){
        int gm = m0 + wm*128 + im*16 + krow*4 + r;
        int gn = n0 + wn*64 + in*16 + lidx;
        float v = acc[im][in][r];
        if (MODE==0){
          outF[(long)gm*Ndim + gn] = v;
        } else {
          if (gn < DINNER) z_out[(long)gm*DINNER + gn] = f2bf(v);
          else if (gn < DINNER+CONVD) xbc_out[(long)gm*CONVD + (gn-DINNER)] = f2bf(v);
          else if (gn < NPROJ) dtraw_out[(long)gm*NHEADS + (gn-DINNER-CONVD)] = v;
        }
      }
}

// ---------------- dt prep: softplus + per-chunk inclusive cumsum ----------
__global__ __launch_bounds__(128) void k_dtprep(const float* __restrict__ dtraw, const float* __restrict__ dt_bias,
    const float* __restrict__ A_log, float* __restrict__ dt_t, float* __restrict__ acs_t)
{
  int b = blockIdx.x >> 9;
  int h = (blockIdx.x >> 4) & 31;
  int c = blockIdx.x & 15;
  int l = threadIdx.x;
  int gl = c*128 + l;
  float raw = dtraw[((long)(b*SEQL + gl))*NHEADS + h] + dt_bias[h];
  float dt = (raw > 20.f) ? raw : log1pf(expf(raw));
  float A = -expf(A_log[h]);
  float ac = dt*A;
  __shared__ float ss[128];
  ss[l] = ac; __syncthreads();
  for (int o=1;o<128;o<<=1){
    float v = (l>=o)? ss[l-o] : 0.f;
    __syncthreads();
    ss[l] += v;
    __syncthreads();
  }
  float acs = ss[l];
  dt_t[((long)(b*NHEADS+h))*SEQL + gl] = dt;
  acs_t[((long)(b*NHEADS+h))*SEQL + gl] = acs;
}

// ---------------- causal depthwise conv + silu; split outputs -------------
__global__ __launch_bounds__(256) void k_conv(const u16* __restrict__ xbc, const float* __restrict__ conv_w,
    const float* __restrict__ conv_b, const float* __restrict__ dt_t,
    u16* __restrict__ xdtT, u16* __restrict__ BTt, u16* __restrict__ CTt)
{
  __shared__ u16 sm[131*64];
  int idx = blockIdx.x;
  int b = idx / 576; int rem = idx % 576; int cbk = rem >> 4; int lb = rem & 15;
  int ch0 = cbk*64, l0 = lb*128;
  for (int g = threadIdx.x; g < 131*8; g += 256){
    int r = g >> 3, cg = g & 7;
    int gl = l0 - 3 + r;
    u16x8 v;
    if (gl >= 0) v = *(const u16x8*)(xbc + ((long)(b*SEQL+gl))*CONVD + ch0 + cg*8);
    else { v[0]=0;v[1]=0;v[2]=0;v[3]=0;v[4]=0;v[5]=0;v[6]=0;v[7]=0; }
    *(u16x8*)(&sm[r*64 + cg*8]) = v;
  }
  __syncthreads();
  int ci = threadIdx.x & 63, g4 = threadIdx.x >> 6;
  int chg = ch0 + ci;
  f32x4 wv = *(const f32x4*)(conv_w + chg*4);
  float bia = conv_b[chg];
  bool isX = chg < DINNER;
  int h = chg >> 6; if (h > 31) h = 31;
  int p = chg & 63;
  const float* dtrow = dt_t + ((long)(b*NHEADS+h))*SEQL + l0 + g4*32;
  u16x8 ov[4];
  #pragma unroll
  for (int i=0;i<32;i++){
    int lr = g4*32 + i;
    float a = bia + wv[0]*bf2f(sm[(lr+0)*64+ci]) + wv[1]*bf2f(sm[(lr+1)*64+ci])
                  + wv[2]*bf2f(sm[(lr+2)*64+ci]) + wv[3]*bf2f(sm[(lr+3)*64+ci]);
    float s = a / (1.f + __expf(-a));
    if (isX) s *= dtrow[i];
    ov[i>>3][i&7] = f2bf(s);
  }
  u16* dst;
  if (isX)                      dst = xdtT + (((long)(b*NHEADS+h))*HEADD + p)*SEQL + l0 + g4*32;
  else if (chg < DINNER+DSTATE) dst = BTt + ((long)(b*DSTATE + (chg-DINNER)))*SEQL + l0 + g4*32;
  else                          dst = CTt + ((long)(b*DSTATE + (chg-DINNER-DSTATE)))*SEQL + l0 + g4*32;
  #pragma unroll
  for (int q=0;q<4;q++) *(u16x8*)(dst + q*8) = ov[q];
}

// ---------------- per (b,chunk): CB = C*B^T (unmasked), and Cn (l,n) ------
__global__ __launch_bounds__(256) void k_cb(const u16* __restrict__ BTt, const u16* __restrict__ CTt,
      u16* __restrict__ CBm, u16* __restrict__ Cn)
{
  __shared__ u16 Cl[128*136];
  __shared__ u16 Bl[128*136];
  int b = blockIdx.x >> 4, c = blockIdx.x & 15;
  for (int g = threadIdx.x; g < 2048; g += 256){
    int n = g >> 4, lg = g & 15;
    u16x8 vc = *(const u16x8*)(CTt + ((long)(b*DSTATE+n))*SEQL + c*CHUNKL + lg*8);
    u16x8 vb = *(const u16x8*)(BTt + ((long)(b*DSTATE+n))*SEQL + c*CHUNKL + lg*8);
    #pragma unroll
    for (int j=0;j<8;j++){
      Cl[(lg*8+j)*136 + n] = vc[j];
      Bl[(lg*8+j)*136 + n] = vb[j];
    }
  }
  __syncthreads();
  const int tid = threadIdx.x;
  const int lane = tid & 63, wid = tid >> 6;
  const int wr = wid & 1, wc2 = wid >> 1;
  const int lidx = lane & 15, krow = lane >> 4;
  const f32x4 zf = {0.f,0.f,0.f,0.f};
  f32x4 acc[4][4];
  #pragma unroll
  for (int i=0;i<4;i++)
    #pragma unroll
    for (int j=0;j<4;j++) acc[i][j] = zf;
  #pragma unroll
  for (int k0=0;k0<128;k0+=32){
    u16x8 af[4], bfv[4];
    #pragma unroll
    for (int i=0;i<4;i++){
      af[i]  = *(const u16x8*)(&Cl[(wr*64+i*16+lidx)*136 + k0 + krow*8]);
      bfv[i] = *(const u16x8*)(&Bl[(wc2*64+i*16+lidx)*136 + k0 + krow*8]);
    }
    #pragma unroll
    for (int i=0;i<4;i++)
      #pragma unroll
      for (int j=0;j<4;j++)
        acc[i][j] = MFMA(af[i], bfv[j], acc[i][j]);
  }
  long base = ((long)(b*16+c))*128*128;
  #pragma unroll
  for (int i=0;i<4;i++)
    #pragma unroll
    for (int j=0;j<4;j++)
      #pragma unroll
      for (int r=0;r<4;r++){
        int l = wr*64+i*16+krow*4+r;
        int s = wc2*64+j*16+lidx;
        CBm[base + (long)l*128 + s] = f2bf(acc[i][j][r]);
      }
  for (int g = tid; g < 2048; g += 256){
    int l = g >> 4, ng = g & 15;
    u16x8 o;
    #pragma unroll
    for (int j=0;j<8;j++) o[j] = Cl[l*136 + ng*8 + j];
    *(u16x8*)(Cn + ((long)(b*SEQL + c*CHUNKL + l))*DSTATE + ng*8) = o;
  }
}

// ---------------- fused SSD: one wg per (b,h); sequential over chunks -----
__global__ __launch_bounds__(256) void k_ssd(
    const u16* __restrict__ Cng, const u16* __restrict__ BTt, const u16* __restrict__ xdtT,
    const u16* __restrict__ CBm, const float* __restrict__ acs_t, const float* __restrict__ dt_t,
    const float* __restrict__ Dparam, u16* __restrict__ y)
{
  __shared__ u16 Cs[128*PADC];
  __shared__ u16 Bs[128*PADC];
  __shared__ u16 Ps[128*PADC];
  __shared__ u16 Xs[64*PADC];
  __shared__ float carry[64*132];
  __shared__ float acs_s[128], eacs_s[128], dec_s[128], dtr_s[128];
  const int bh = blockIdx.x;
  const int b = bh >> 5, h = bh & 31;
  const int tid = threadIdx.x, lane = tid & 63, wid = tid >> 6;
  const int lidx = lane & 15, krow = lane >> 4;
  const int wl = wid & 1, wp = wid >> 1;
  const int wps = wid & 1, wns = wid >> 1;
  for (int i = tid; i < 64*132; i += 256) carry[i] = 0.f;
  const float Dh = Dparam[h];
  const float* acs_g = acs_t + (long)bh*SEQL;
  const float* dt_g = dt_t + (long)bh*SEQL;
  const u16* X_g = xdtT + (long)bh*HEADD*SEQL;
  const u16* B_g = BTt + (long)b*DSTATE*SEQL;
  const u16* C_g = Cng + (long)b*SEQL*DSTATE;
  const u16* CB_g = CBm + (long)b*NCHUNK*CHUNKL*CHUNKL;
  const f32x4 zf = {0.f,0.f,0.f,0.f};
  for (int c=0;c<NCHUNK;c++){
    __syncthreads();
    if (tid < 128){ acs_s[tid] = acs_g[c*128+tid]; dtr_s[tid] = dt_g[c*128+tid]; }
    __syncthreads();
    if (tid < 128){ float a = acs_s[tid]; eacs_s[tid] = __expf(a); dec_s[tid] = __expf(acs_s[127]-a); }
    __syncthreads();
    for (int g = tid; g < 2048; g += 256){
      int l = g >> 4, cb = g & 15;
      u16x8 v = *(const u16x8*)(C_g + ((long)(c*128+l))*DSTATE + cb*8);
      float e = eacs_s[l];
      u16x8 o;
      #pragma unroll
      for (int j=0;j<8;j++) o[j] = f2bf(bf2f(v[j])*e);
      *(u16x8*)(&Cs[l*PADC + cb*8]) = o;
    }
    for (int g = tid; g < 2048; g += 256){
      int n = g >> 4, lg = g & 15;
      u16x8 v = *(const u16x8*)(B_g + (long)n*SEQL + c*128 + lg*8);
      u16x8 o;
      #pragma unroll
      for (int j=0;j<8;j++) o[j] = f2bf(bf2f(v[j])*dec_s[lg*8+j]);
      *(u16x8*)(&Bs[n*PADC + lg*8]) = o;
    }
    for (int g = tid; g < 1024; g += 256){
      int p = g >> 4, lg = g & 15;
      *(u16x8*)(&Xs[p*PADC + lg*8]) = *(const u16x8*)(X_g + (long)p*SEQL + c*128 + lg*8);
    }
    {
      int l = tid >> 1, s0 = (tid & 1)*64;
      float al = acs_s[l];
      #pragma unroll
      for (int q=0;q<8;q++){
        u16x8 v = *(const u16x8*)(CB_g + ((long)(c*128+l))*CHUNKL + s0 + q*8);
        u16x8 o;
        #pragma unroll
        for (int j=0;j<8;j++){
          int s = s0 + q*8 + j;
          float pv = (s <= l) ? bf2f(v[j]) * __expf(al - acs_s[s]) : 0.f;
          o[j] = f2bf(pv);
        }
        *(u16x8*)(&Ps[l*PADC + s0 + q*8]) = o;
      }
    }
    __syncthreads();
    f32x4 accY[4][2];
    f32x4 accS[2][4];
    #pragma unroll
    for (int i=0;i<4;i++){ accY[i][0]=zf; accY[i][1]=zf; }
    #pragma unroll
    for (int i=0;i<2;i++){ accS[i][0]=zf; accS[i][1]=zf; accS[i][2]=zf; accS[i][3]=zf; }
    #pragma unroll
    for (int k0=0;k0<128;k0+=32){
      u16x8 af[4], bfv[2];
      #pragma unroll
      for (int i=0;i<4;i++) af[i] = *(const u16x8*)(&Cs[(wl*64+i*16+lidx)*PADC + k0 + krow*8]);
      #pragma unroll
      for (int j=0;j<2;j++){
        const float* cp = &carry[(wp*32+j*16+lidx)*132 + k0 + krow*8];
        f32x4 c0 = *(const f32x4*)cp;
        f32x4 c1 = *(const f32x4*)(cp+4);
        u16x8 o;
        o[0]=f2bf(c0[0]); o[1]=f2bf(c0[1]); o[2]=f2bf(c0[2]); o[3]=f2bf(c0[3]);
        o[4]=f2bf(c1[0]); o[5]=f2bf(c1[1]); o[6]=f2bf(c1[2]); o[7]=f2bf(c1[3]);
        bfv[j] = o;
      }
      #pragma unroll
      for (int i=0;i<4;i++)
        #pragma unroll
        for (int j=0;j<2;j++)
          accY[i][j] = MFMA(af[i], bfv[j], accY[i][j]);
    }
    #pragma unroll
    for (int k0=0;k0<128;k0+=32){
      u16x8 af[4], bfv[2];
      #pragma unroll
      for (int i=0;i<4;i++) af[i] = *(const u16x8*)(&Ps[(wl*64+i*16+lidx)*PADC + k0 + krow*8]);
      #pragma unroll
      for (int j=0;j<2;j++) bfv[j] = *(const u16x8*)(&Xs[(wp*32+j*16+lidx)*PADC + k0 + krow*8]);
      #pragma unroll
      for (int i=0;i<4;i++)
        #pragma unroll
        for (int j=0;j<2;j++)
          accY[i][j] = MFMA(af[i], bfv[j], accY[i][j]);
    }
    #pragma unroll
    for (int k0=0;k0<128;k0+=32){
      u16x8 as2[2], bs2[4];
      #pragma unroll
      for (int i=0;i<2;i++) as2[i] = *(const u16x8*)(&Xs[(wps*32+i*16+lidx)*PADC + k0 + krow*8]);
      #pragma unroll
      for (int j=0;j<4;j++) bs2[j] = *(const u16x8*)(&Bs[(wns*64+j*16+lidx)*PADC + k0 + krow*8]);
      #pragma unroll
      for (int i=0;i<2;i++)
        #pragma unroll
        for (int j=0;j<4;j++)
          accS[i][j] = MFMA(as2[i], bs2[j], accS[i][j]);
    }
    __syncthreads();
    float cd = __expf(acs_s[127]);
    #pragma unroll
    for (int i=0;i<2;i++)
      #pragma unroll
      for (int j=0;j<4;j++)
        #pragma unroll
        for (int r=0;r<4;r++){
          int p = wps*32 + i*16 + krow*4 + r;
          int n = wns*64 + j*16 + lidx;
          carry[p*132+n] = carry[p*132+n]*cd + accS[i][j][r];
        }
    #pragma unroll
    for (int i=0;i<4;i++)
      #pragma unroll
      for (int j=0;j<2;j++)
        #pragma unroll
        for (int r=0;r<4;r++){
          int l = wl*64 + i*16 + krow*4 + r;
          int p = wp*32 + j*16 + lidx;
          float xv = bf2f(Xs[p*PADC + l]) / dtr_s[l];
          float val = accY[i][j][r] + Dh*xv;
          y[((long)(b*SEQL + c*128 + l))*DINNER + h*HEADD + p] = f2bf(val);
        }
  }
}

// ---------------- gating (silu(z)) + RMSNorm -> bf16 ----------------------
__global__ __launch_bounds__(256) void k_gate(const u16* __restrict__ y, const u16* __restrict__ z,
    const float* __restrict__ norm_w, u16* __restrict__ out)
{
  long row = blockIdx.x;
  const u16* yr = y + row*DINNER;
  const u16* zr = z + row*DINNER;
  int t = threadIdx.x;
  u16x8 yy = *(const u16x8*)(yr + t*8);
  u16x8 zz = *(const u16x8*)(zr + t*8);
  float g[8]; float ss = 0.f;
  #pragma unroll
  for (int j=0;j<8;j++){
    float zfv = bf2f(zz[j]);
    float sg = zfv / (1.f + __expf(-zfv));
    float gv = bf2f(yy[j]) * sg;
    g[j] = gv; ss += gv*gv;
  }
  #pragma unroll
  for (int o=32;o>0;o>>=1) ss += __shfl_down(ss, o);
  __shared__ float part[4];
  int lane = t & 63, wid = t>>6;
  if (lane==0) part[wid] = ss;
  __syncthreads();
  float tot = part[0]+part[1]+part[2]+part[3];
  float inv = rsqrtf(tot*(1.f/DINNER) + 1e-5f);
  u16x8 o;
  #pragma unroll
  for (int j=0;j<8;j++) o[j] = f2bf(g[j]*inv*norm_w[t*8+j]);
  *(u16x8*)(out + row*DINNER + t*8) = o;
}

// ---------------- pred = hidden @ dec_w^T + dec_b -------------------------
__global__ __launch_bounds__(256) void k_pred(const float* __restrict__ hid, const float* __restrict__ dec_w,
    const float* __restrict__ dec_b, float* __restrict__ pred)
{
  int t = threadIdx.x;
  long row = (long)blockIdx.x*8 + (t>>5);
  int lk = t & 31;
  const float* hr = hid + row*DMODEL;
  float a0=0.f,a1=0.f,a2=0.f;
  #pragma unroll
  for (int i=0;i<8;i++){
    f32x4 hv = *(const f32x4*)(hr + lk*4 + i*128);
    f32x4 w0 = *(const f32x4*)(dec_w + 0*DMODEL + lk*4 + i*128);
    f32x4 w1 = *(const f32x4*)(dec_w + 1*DMODEL + lk*4 + i*128);
    f32x4 w2 = *(const f32x4*)(dec_w + 2*DMODEL + lk*4 + i*128);
    a0 += hv[0]*w0[0]+hv[1]*w0[1]+hv[2]*w0[2]+hv[3]*w0[3];
    a1 += hv[0]*w1[0]+hv[1]*w1[1]+hv[2]*w1[2]+hv[3]*w1[3];
    a2 += hv[0]*w2[0]+hv[1]*w2[1]+hv[2]*w2[2]+hv[3]*w2[3];
  }
  #pragma unroll
  for (int o=16;o>0;o>>=1){
    a0 += __shfl_down(a0,o,32); a1 += __shfl_down(a1,o,32); a2 += __shfl_down(a2,o,32);
  }
  if (lk==0){
    pred[row*3+0] = a0 + dec_b[0];
    pred[row*3+1] = a1 + dec_b[1];
    pred[row*3+2] = a2 + dec_b[2];
  }
}

extern "C" void kernel_launch(void* const* d_in, const int* in_sizes, int n_in,
                              void* d_out, int out_size, void* d_ws, size_t ws_size,
                              hipStream_t stream)
{
  const float* embed      = (const float*)d_in[0];
  const float* in_proj_w  = (const float*)d_in[1];
  const float* conv_w     = (const float*)d_in[2];
  const float* conv_b     = (const float*)d_in[3];
  const float* dt_bias    = (const float*)d_in[4];
  const float* A_log      = (const float*)d_in[5];
  const float* Dp         = (const float*)d_in[6];
  const float* norm_w     = (const float*)d_in[7];
  const float* out_proj_w = (const float*)d_in[8];
  const float* dec_w      = (const float*)d_in[9];
  const float* dec_b      = (const float*)d_in[10];

  char* ws = (char*)d_ws;
  size_t off = 0;
  auto alloc = [&](size_t bytes)->void*{ void* p = ws + off; off += (bytes + 255) & ~(size_t)255; return p; };

  // Region 1 (75.5 MB): xbc (GEMM1 -> conv), then y bf16 (ssd -> gate)
  u16* xbc = (u16*)alloc((size_t)MROWS*CONVD*2);
  u16* yb  = xbc;
  // Region 2 (67.1 MB): Ebf+W1 (phase 1) -> xdtT (conv->ssd) -> ynorm (gate->GEMM2)
  u16* R2  = (u16*)alloc((size_t)MROWS*DINNER*2);
  u16* Ebf = R2;                                   // 33.5 MB
  u16* W1  = R2 + (size_t)MROWS*DMODEL;            // 9.44 MB (4608 rows), total 43 <= 67.1
  u16* xdtT  = R2;
  u16* ynorm = R2;
  float* dtraw = (float*)alloc((size_t)MROWS*NHEADS*4);
  float* dt_t  = (float*)alloc((size_t)NBATCH*NHEADS*SEQL*4);
  float* acs   = (float*)alloc((size_t)NBATCH*NHEADS*SEQL*4);
  u16* BTt   = (u16*)alloc((size_t)NBATCH*DSTATE*SEQL*2);
  u16* CTt   = (u16*)alloc((size_t)NBATCH*DSTATE*SEQL*2);
  u16* Cn    = (u16*)alloc((size_t)NBATCH*SEQL*DSTATE*2);
  u16* CBm   = (u16*)alloc((size_t)NBATCH*NCHUNK*CHUNKL*CHUNKL*2);
  u16* W2    = (u16*)alloc((size_t)DMODEL*DINNER*2);

  if (off > ws_size){
    k_sentinel<<<1,1,0,stream>>>((float*)d_out);
    return;
  }

  float* pred   = (float*)d_out;
  float* hidden = (float*)d_out + (size_t)MROWS*3;
  u16* zb = (u16*)hidden;  // z in d_out hidden region; dead before GEMM2 writes hidden

  hipFuncSetAttribute((const void*)k_gemm8<1>, hipFuncAttributeMaxDynamicSharedMemorySize, 131072);
  hipFuncSetAttribute((const void*)k_gemm8<0>, hipFuncAttributeMaxDynamicSharedMemorySize, 131072);

  k_cvt<<<16384,256,0,stream>>>(embed, Ebf, (long)MROWS*DMODEL, (long)MROWS*DMODEL);
  k_cvt<<<4608,256,0,stream>>>(in_proj_w, W1, (long)NPROJ*DMODEL, (long)NPROJP*DMODEL);
  k_cvt<<<2048,256,0,stream>>>(out_proj_w, W2, (long)DMODEL*DINNER, (long)DMODEL*DINNER);
  {
    dim3 g1(64, NPROJP/256);   // 64 x 18 = 1152 wgs (%8==0)
    k_gemm8<1><<<g1,512,131072,stream>>>(Ebf, W1, DMODEL, 0, nullptr, zb, xbc, dtraw);
  }
  k_dtprep<<<4096,128,0,stream>>>(dtraw, dt_bias, A_log, dt_t, acs);
  k_conv<<<4608,256,0,stream>>>(xbc, conv_w, conv_b, dt_t, xdtT, BTt, CTt);
  k_cb<<<128,256,0,stream>>>(BTt, CTt, CBm, Cn);
  k_ssd<<<256,256,0,stream>>>(Cn, BTt, xdtT, CBm, acs, dt_t, Dp, yb);
  k_gate<<<16384,256,0,stream>>>(yb, zb, norm_w, ynorm);
  {
    dim3 g2(64, DMODEL/256);   // 64 x 4 = 256 wgs (%8==0)
    k_gemm8<0><<<g2,512,131072,stream>>>(ynorm, W2, DINNER, DMODEL, hidden, nullptr, nullptr, nullptr);
  }
  k_pred<<<2048,256,0,stream>>>(hidden, dec_w, dec_b, pred);
}

// Round 5
// 553.130 us; speedup vs baseline: 1.3829x; 1.1714x over previous
//
#include <hip/hip_runtime.h>
#include <cstdint>

#define DEVI __device__ __forceinline__

typedef unsigned short u16;
typedef unsigned int u32;
typedef __attribute__((ext_vector_type(4))) float f32x4;
typedef __attribute__((ext_vector_type(8))) u16 u16x8;
typedef __attribute__((ext_vector_type(4))) u16 u16x4;
typedef __attribute__((ext_vector_type(8))) __bf16 bf16x8;

#define SEQL 2048
#define NBATCH 8
#define MROWS (NBATCH*SEQL)
#define DMODEL 1024
#define DINNER 2048
#define NHEADS 32
#define HEADD 64
#define DSTATE 128
#define CONVD 2304
#define NPROJ 4384
#define NPROJP 4608
#define CHUNKL 128
#define NCHUNK 16
#define PADC 136

DEVI float bf2f(u16 v){ u32 u = ((u32)v)<<16; return __builtin_bit_cast(float,u); }
DEVI u16 f2bf(float f){ u32 u = __builtin_bit_cast(u32,f); u32 r = (u + 0x7fffu + ((u>>16)&1u))>>16; return (u16)r; }

DEVI void gld_lds16(const void* g, void* lds){
  __builtin_amdgcn_global_load_lds(
    (const __attribute__((address_space(1))) void*)(uintptr_t)g,
    (__attribute__((address_space(3))) void*)(u32)(uintptr_t)lds, 16, 0, 0);
}

DEVI f32x4 MFMA(u16x8 a, u16x8 b, f32x4 c){
  return __builtin_amdgcn_mfma_f32_16x16x32_bf16(
      __builtin_bit_cast(bf16x8,a), __builtin_bit_cast(bf16x8,b), c, 0,0,0);
}

__global__ void k_sentinel(float* o){ o[0] = 12345.0f; }

// ---------------- convert f32 -> bf16 (with zero-pad tail) ----------------
__global__ __launch_bounds__(256) void k_cvt(const float* __restrict__ src, u16* __restrict__ dst, long n, long ntot){
  long idx = ((long)blockIdx.x*256 + threadIdx.x)*4;
  if (idx >= ntot) return;
  u16x4 o;
  if (idx < n){
    f32x4 v = *(const f32x4*)(src+idx);
    o[0]=f2bf(v[0]); o[1]=f2bf(v[1]); o[2]=f2bf(v[2]); o[3]=f2bf(v[3]);
  } else { o[0]=0; o[1]=0; o[2]=0; o[3]=0; }
  *(u16x4*)(dst+idx) = o;
}

// ================= 256^2 8-phase GEMM (T1+T2+T3+T4+T5) ====================
#define STG(mat, h, ts) do { \
    const int d_ = (ts) & 1; \
    const size_t ko_ = (size_t)(((ts) < NT) ? (ts) : (NT-1)) * 64; \
    gld_lds16(sbase[mat][h][0] + ko_, (char*)lds + (mat)*65536 + (d_*2+(h))*16384 + tid*16); \
    gld_lds16(sbase[mat][h][1] + ko_, (char*)lds + (mat)*65536 + (d_*2+(h))*16384 + 8192 + tid*16); \
  } while(0)

#define LDA8(AF, d_, qm) { \
    _Pragma("unroll") for (int mf=0; mf<4; mf++) \
    _Pragma("unroll") for (int ks=0; ks<2; ks++) \
      AF[mf][ks] = *(const u16x8*)(lds + (size_t)((d_)*2+wm)*8192 + ((qm)*64+mf*16+lidx)*64 + ((ks*4+krow)^(lidx&7))*8); }

#define LDB4(BF, d_, qn) { \
    _Pragma("unroll") for (int nf=0; nf<2; nf++) \
    _Pragma("unroll") for (int ks=0; ks<2; ks++) \
      BF[nf][ks] = *(const u16x8*)(lds + 32768 + (size_t)((d_)*2+(wn>>1))*8192 + ((wn&1)*64+(qn)*32+nf*16+lidx)*64 + ((ks*4+krow)^(lidx&7))*8); }

#define MMAQ(QM, QN, AF, BF) { \
    _Pragma("unroll") for (int mf=0; mf<4; mf++) \
    _Pragma("unroll") for (int nf=0; nf<2; nf++) \
    _Pragma("unroll") for (int ks=0; ks<2; ks++) \
      acc[(QM)*4+mf][(QN)*2+nf] = MFMA(AF[mf][ks], BF[nf][ks], acc[(QM)*4+mf][(QN)*2+nf]); }

#define BAR1 __builtin_amdgcn_sched_barrier(0); __builtin_amdgcn_s_barrier(); \
    asm volatile("s_waitcnt lgkmcnt(0)" ::: "memory"); __builtin_amdgcn_sched_barrier(0); \
    __builtin_amdgcn_s_setprio(1);
#define BAR2 __builtin_amdgcn_s_setprio(0); __builtin_amdgcn_sched_barrier(0); \
    __builtin_amdgcn_s_barrier(); __builtin_amdgcn_sched_barrier(0);

template<int MODE>
__global__ __launch_bounds__(512, 2) void k_gemm8(const u16* __restrict__ A, const u16* __restrict__ Bt,
    const int K, const int Ndim, float* __restrict__ outF,
    u16* __restrict__ z_out, u16* __restrict__ xbc_out, float* __restrict__ dtraw_out)
{
  extern __shared__ u16 lds[];
  const int NT = K >> 6;
  const int tid = threadIdx.x;
  const int lane = tid & 63, wid = tid >> 6;
  const int wm = wid >> 2, wn = wid & 3;
  const int lidx = lane & 15, krow = lane >> 4;
  const int nwg = gridDim.x * gridDim.y;
  const int orig = blockIdx.y * gridDim.x + blockIdx.x;
  const int swz = (orig & 7) * (nwg >> 3) + (orig >> 3);
  const int m0 = (swz % gridDim.x) * 256;
  const int n0 = (swz / gridDim.x) * 256;

  f32x4 acc[8][4];
  const f32x4 zf = {0.f,0.f,0.f,0.f};
  #pragma unroll
  for (int i=0;i<8;i++)
    #pragma unroll
    for (int j=0;j<4;j++) acc[i][j] = zf;

  const int r0 = tid >> 3;
  const int gsw = ((tid & 7) ^ (r0 & 7)) * 8;
  const u16* sbase[2][2][2];
  #pragma unroll
  for (int h=0; h<2; h++)
    #pragma unroll
    for (int L=0; L<2; L++){
      sbase[0][h][L] = A  + (size_t)(m0 + h*128 + L*64 + r0)*K + gsw;
      sbase[1][h][L] = Bt + (size_t)(n0 + h*128 + L*64 + r0)*K + gsw;
    }

  STG(0,0,0); STG(0,1,0); STG(1,0,0); STG(1,1,0);
  asm volatile("s_waitcnt vmcnt(4)" ::: "memory");
  STG(0,0,1); STG(0,1,1); STG(1,0,1);
  asm volatile("s_waitcnt vmcnt(6)" ::: "memory");
  __builtin_amdgcn_sched_barrier(0);
  __builtin_amdgcn_s_barrier();
  __builtin_amdgcn_sched_barrier(0);

  u16x8 af[4][2], bf0[2][2], bf1[2][2];
  for (int t = 0; t < NT; t += 2){
    LDA8(af, 0, 0); LDB4(bf0, 0, 0); STG(1,1,t+1);
    BAR1; MMAQ(0,0,af,bf0); BAR2;
    LDB4(bf1, 0, 1);
    BAR1; MMAQ(0,1,af,bf1); BAR2;
    LDA8(af, 0, 1); STG(1,0,t+2);
    BAR1; MMAQ(1,1,af,bf1); BAR2;
    STG(0,0,t+2); STG(0,1,t+2);
    asm volatile("s_waitcnt vmcnt(6)" ::: "memory");
    BAR1; MMAQ(1,0,af,bf0); BAR2;
    LDA8(af, 1, 0); LDB4(bf0, 1, 0); STG(1,1,t+2);
    BAR1; MMAQ(0,0,af,bf0); BAR2;
    LDB4(bf1, 1, 1);
    BAR1; MMAQ(0,1,af,bf1); BAR2;
    LDA8(af, 1, 1); STG(1,0,t+3);
    BAR1; MMAQ(1,1,af,bf1); BAR2;
    STG(0,0,t+3); STG(0,1,t+3);
    asm volatile("s_waitcnt vmcnt(6)" ::: "memory");
    BAR1; MMAQ(1,0,af,bf0); BAR2;
  }
  asm volatile("s_waitcnt vmcnt(0)" ::: "memory");

  #pragma unroll
  for (int im=0; im<8; im++)
    #pragma unroll
    for (int in=0; in<4; in++)
      #pragma unroll
      for (int r=0; r<4; r++){
        int gm = m0 + wm*128 + im*16 + krow*4 + r;
        int gn = n0 + wn*64 + in*16 + lidx;
        float v = acc[im][in][r];
        if (MODE==0){
          outF[(long)gm*Ndim + gn] = v;
        } else {
          if (gn < DINNER) z_out[(long)gm*DINNER + gn] = f2bf(v);
          else if (gn < DINNER+CONVD) xbc_out[(long)gm*CONVD + (gn-DINNER)] = f2bf(v);
          else if (gn < NPROJ) dtraw_out[(long)gm*NHEADS + (gn-DINNER-CONVD)] = v;
        }
      }
}

// ---------------- dt prep: softplus + per-chunk inclusive cumsum ----------
__global__ __launch_bounds__(128) void k_dtprep(const float* __restrict__ dtraw, const float* __restrict__ dt_bias,
    const float* __restrict__ A_log, float* __restrict__ dt_t, float* __restrict__ acs_t)
{
  int b = blockIdx.x >> 9;
  int h = (blockIdx.x >> 4) & 31;
  int c = blockIdx.x & 15;
  int l = threadIdx.x;
  int gl = c*128 + l;
  float raw = dtraw[((long)(b*SEQL + gl))*NHEADS + h] + dt_bias[h];
  float dt = (raw > 20.f) ? raw : log1pf(expf(raw));
  float A = -expf(A_log[h]);
  float ac = dt*A;
  __shared__ float ss[128];
  ss[l] = ac; __syncthreads();
  for (int o=1;o<128;o<<=1){
    float v = (l>=o)? ss[l-o] : 0.f;
    __syncthreads();
    ss[l] += v;
    __syncthreads();
  }
  float acs = ss[l];
  dt_t[((long)(b*NHEADS+h))*SEQL + gl] = dt;
  acs_t[((long)(b*NHEADS+h))*SEQL + gl] = acs;
}

// ---------------- causal depthwise conv + silu; split outputs -------------
__global__ __launch_bounds__(256) void k_conv(const u16* __restrict__ xbc, const float* __restrict__ conv_w,
    const float* __restrict__ conv_b, const float* __restrict__ dt_t,
    u16* __restrict__ xdtT, u16* __restrict__ BTt, u16* __restrict__ CTt)
{
  __shared__ u16 sm[131*64];
  int idx = blockIdx.x;
  int b = idx / 576; int rem = idx % 576; int cbk = rem >> 4; int lb = rem & 15;
  int ch0 = cbk*64, l0 = lb*128;
  for (int g = threadIdx.x; g < 131*8; g += 256){
    int r = g >> 3, cg = g & 7;
    int gl = l0 - 3 + r;
    u16x8 v;
    if (gl >= 0) v = *(const u16x8*)(xbc + ((long)(b*SEQL+gl))*CONVD + ch0 + cg*8);
    else { v[0]=0;v[1]=0;v[2]=0;v[3]=0;v[4]=0;v[5]=0;v[6]=0;v[7]=0; }
    *(u16x8*)(&sm[r*64 + cg*8]) = v;
  }
  __syncthreads();
  int ci = threadIdx.x & 63, g4 = threadIdx.x >> 6;
  int chg = ch0 + ci;
  f32x4 wv = *(const f32x4*)(conv_w + chg*4);
  float bia = conv_b[chg];
  bool isX = chg < DINNER;
  int h = chg >> 6; if (h > 31) h = 31;
  int p = chg & 63;
  const float* dtrow = dt_t + ((long)(b*NHEADS+h))*SEQL + l0 + g4*32;
  u16x8 ov[4];
  #pragma unroll
  for (int i=0;i<32;i++){
    int lr = g4*32 + i;
    float a = bia + wv[0]*bf2f(sm[(lr+0)*64+ci]) + wv[1]*bf2f(sm[(lr+1)*64+ci])
                  + wv[2]*bf2f(sm[(lr+2)*64+ci]) + wv[3]*bf2f(sm[(lr+3)*64+ci]);
    float s = a / (1.f + __expf(-a));
    if (isX) s *= dtrow[i];
    ov[i>>3][i&7] = f2bf(s);
  }
  u16* dst;
  if (isX)                      dst = xdtT + (((long)(b*NHEADS+h))*HEADD + p)*SEQL + l0 + g4*32;
  else if (chg < DINNER+DSTATE) dst = BTt + ((long)(b*DSTATE + (chg-DINNER)))*SEQL + l0 + g4*32;
  else                          dst = CTt + ((long)(b*DSTATE + (chg-DINNER-DSTATE)))*SEQL + l0 + g4*32;
  #pragma unroll
  for (int q=0;q<4;q++) *(u16x8*)(dst + q*8) = ov[q];
}

// ---------------- per (b,chunk): CB = C*B^T (unmasked), and Cn (l,n) ------
__global__ __launch_bounds__(256) void k_cb(const u16* __restrict__ BTt, const u16* __restrict__ CTt,
      u16* __restrict__ CBm, u16* __restrict__ Cn)
{
  __shared__ u16 Cl[128*136];
  __shared__ u16 Bl[128*136];
  int b = blockIdx.x >> 4, c = blockIdx.x & 15;
  for (int g = threadIdx.x; g < 2048; g += 256){
    int n = g >> 4, lg = g & 15;
    u16x8 vc = *(const u16x8*)(CTt + ((long)(b*DSTATE+n))*SEQL + c*CHUNKL + lg*8);
    u16x8 vb = *(const u16x8*)(BTt + ((long)(b*DSTATE+n))*SEQL + c*CHUNKL + lg*8);
    #pragma unroll
    for (int j=0;j<8;j++){
      Cl[(lg*8+j)*136 + n] = vc[j];
      Bl[(lg*8+j)*136 + n] = vb[j];
    }
  }
  __syncthreads();
  const int tid = threadIdx.x;
  const int lane = tid & 63, wid = tid >> 6;
  const int wr = wid & 1, wc2 = wid >> 1;
  const int lidx = lane & 15, krow = lane >> 4;
  const f32x4 zf = {0.f,0.f,0.f,0.f};
  f32x4 acc[4][4];
  #pragma unroll
  for (int i=0;i<4;i++)
    #pragma unroll
    for (int j=0;j<4;j++) acc[i][j] = zf;
  #pragma unroll
  for (int k0=0;k0<128;k0+=32){
    u16x8 af[4], bfv[4];
    #pragma unroll
    for (int i=0;i<4;i++){
      af[i]  = *(const u16x8*)(&Cl[(wr*64+i*16+lidx)*136 + k0 + krow*8]);
      bfv[i] = *(const u16x8*)(&Bl[(wc2*64+i*16+lidx)*136 + k0 + krow*8]);
    }
    #pragma unroll
    for (int i=0;i<4;i++)
      #pragma unroll
      for (int j=0;j<4;j++)
        acc[i][j] = MFMA(af[i], bfv[j], acc[i][j]);
  }
  long base = ((long)(b*16+c))*128*128;
  #pragma unroll
  for (int i=0;i<4;i++)
    #pragma unroll
    for (int j=0;j<4;j++)
      #pragma unroll
      for (int r=0;r<4;r++){
        int l = wr*64+i*16+krow*4+r;
        int s = wc2*64+j*16+lidx;
        CBm[base + (long)l*128 + s] = f2bf(acc[i][j][r]);
      }
  for (int g = tid; g < 2048; g += 256){
    int l = g >> 4, ng = g & 15;
    u16x8 o;
    #pragma unroll
    for (int j=0;j<8;j++) o[j] = Cl[l*136 + ng*8 + j];
    *(u16x8*)(Cn + ((long)(b*SEQL + c*CHUNKL + l))*DSTATE + ng*8) = o;
  }
}

// ============ parallel SSD path ============
// k_par: per (b,c,h) chunk states[p][n] = sum_l xdt[p,l] * B[n,l] * dec[l]
__global__ __launch_bounds__(256) void k_par(
    const u16* __restrict__ BTt, const u16* __restrict__ xdtT,
    const float* __restrict__ acs_t, u16* __restrict__ states)
{
  __shared__ u16 Bs[128*PADC];
  __shared__ u16 Xs[64*PADC];
  __shared__ float acs_s[128], dec_s[128];
  const int idx = blockIdx.x;
  const int c = idx & 15, bh = idx >> 4, b = bh >> 5;
  const int tid = threadIdx.x, lane = tid & 63, wid = tid >> 6;
  const int lidx = lane & 15, krow = lane >> 4;
  const int wps = wid & 1, wns = wid >> 1;
  const float* acs_g = acs_t + (long)bh*SEQL + c*128;
  const u16* X_g = xdtT + (long)bh*HEADD*SEQL + c*128;
  const u16* B_g = BTt + (long)b*DSTATE*SEQL + c*128;
  if (tid < 128) acs_s[tid] = acs_g[tid];
  __syncthreads();
  if (tid < 128) dec_s[tid] = __expf(acs_s[127] - acs_s[tid]);
  __syncthreads();
  for (int g = tid; g < 2048; g += 256){
    int n = g >> 4, lg = g & 15;
    u16x8 v = *(const u16x8*)(B_g + (long)n*SEQL + lg*8);
    u16x8 o;
    #pragma unroll
    for (int j=0;j<8;j++) o[j] = f2bf(bf2f(v[j])*dec_s[lg*8+j]);
    *(u16x8*)(&Bs[n*PADC + lg*8]) = o;
  }
  for (int g = tid; g < 1024; g += 256){
    int p = g >> 4, lg = g & 15;
    *(u16x8*)(&Xs[p*PADC + lg*8]) = *(const u16x8*)(X_g + (long)p*SEQL + lg*8);
  }
  __syncthreads();
  const f32x4 zf = {0.f,0.f,0.f,0.f};
  f32x4 accS[2][4];
  #pragma unroll
  for (int i=0;i<2;i++){ accS[i][0]=zf; accS[i][1]=zf; accS[i][2]=zf; accS[i][3]=zf; }
  #pragma unroll
  for (int k0=0;k0<128;k0+=32){
    u16x8 as2[2], bs2[4];
    #pragma unroll
    for (int i=0;i<2;i++) as2[i] = *(const u16x8*)(&Xs[(wps*32+i*16+lidx)*PADC + k0 + krow*8]);
    #pragma unroll
    for (int j=0;j<4;j++) bs2[j] = *(const u16x8*)(&Bs[(wns*64+j*16+lidx)*PADC + k0 + krow*8]);
    #pragma unroll
    for (int i=0;i<2;i++)
      #pragma unroll
      for (int j=0;j<4;j++)
        accS[i][j] = MFMA(as2[i], bs2[j], accS[i][j]);
  }
  u16* Sg = states + (long)idx*8192;
  #pragma unroll
  for (int i=0;i<2;i++)
    #pragma unroll
    for (int j=0;j<4;j++)
      #pragma unroll
      for (int r=0;r<4;r++){
        int p = wps*32 + i*16 + krow*4 + r;
        int n = wns*64 + j*16 + lidx;
        Sg[p*128 + n] = f2bf(accS[i][j][r]);
      }
}

// k_scan: exclusive scan over chunks, in place. thread owns 4 consecutive n.
__global__ __launch_bounds__(256) void k_scan(u16* __restrict__ states, const float* __restrict__ acs_t)
{
  long gid = (long)blockIdx.x*256 + threadIdx.x;
  int bh = (int)(gid >> 11);          // 2048 quads per (b,h)
  int q = (int)(gid & 2047);
  __shared__ float cds[16];
  if (threadIdx.x < 16) cds[threadIdx.x] = __expf(acs_t[(long)bh*SEQL + threadIdx.x*128 + 127]);
  __syncthreads();
  u16* p = states + (long)bh*NCHUNK*8192 + q*4;
  u16x4 sv[16];
  #pragma unroll
  for (int c=0;c<16;c++) sv[c] = *(const u16x4*)(p + c*8192);
  float c0=0.f,c1=0.f,c2=0.f,c3=0.f;
  #pragma unroll
  for (int c=0;c<16;c++){
    u16x4 o; o[0]=f2bf(c0); o[1]=f2bf(c1); o[2]=f2bf(c2); o[3]=f2bf(c3);
    *(u16x4*)(p + c*8192) = o;
    float cd = cds[c];
    c0 = c0*cd + bf2f(sv[c][0]);
    c1 = c1*cd + bf2f(sv[c][1]);
    c2 = c2*cd + bf2f(sv[c][2]);
    c3 = c3*cd + bf2f(sv[c][3]);
  }
}

// k_yoff: per (b,c,h): y = Y_diag + D*x + Y_off  (two-stage LDS reuse)
__global__ __launch_bounds__(256) void k_yoff(
    const u16* __restrict__ Cng, const u16* __restrict__ xdtT, const u16* __restrict__ CBm,
    const u16* __restrict__ SI, const float* __restrict__ acs_t, const float* __restrict__ dt_t,
    const float* __restrict__ Dparam, u16* __restrict__ y)
{
  __shared__ u16 Ts[128*PADC];   // Ps, then Cs
  __shared__ u16 Us[64*PADC];    // Xs, then SIs
  __shared__ float acs_s[128], dtr_s[128], eacs_s[128];
  const int idx = blockIdx.x;
  const int c = idx & 15, bh = idx >> 4, b = bh >> 5, h = bh & 31;
  const int tid = threadIdx.x, lane = tid & 63, wid = tid >> 6;
  const int lidx = lane & 15, krow = lane >> 4;
  const int wl = wid & 1, wp = wid >> 1;
  const float Dh = Dparam[h];
  const float* acs_g = acs_t + (long)bh*SEQL + c*128;
  const float* dt_g  = dt_t  + (long)bh*SEQL + c*128;
  const u16* X_g = xdtT + (long)bh*HEADD*SEQL + c*128;
  const u16* C_g = Cng + ((long)(b*SEQL + c*128))*DSTATE;
  const u16* CB_g = CBm + ((long)(b*NCHUNK + c))*CHUNKL*CHUNKL;
  const u16* SI_g = SI + (long)idx*8192;
  if (tid < 128){ acs_s[tid] = acs_g[tid]; dtr_s[tid] = dt_g[tid]; }
  __syncthreads();
  if (tid < 128) eacs_s[tid] = __expf(acs_s[tid]);
  __syncthreads();
  // stage Ps (masked CB * exp(acs_l - acs_s)) and Xs
  {
    int l = tid >> 1, s0 = (tid & 1)*64;
    float al = acs_s[l];
    #pragma unroll
    for (int qq=0;qq<8;qq++){
      u16x8 v = *(const u16x8*)(CB_g + (long)l*CHUNKL + s0 + qq*8);
      u16x8 o;
      #pragma unroll
      for (int j=0;j<8;j++){
        int s = s0 + qq*8 + j;
        float pv = (s <= l) ? bf2f(v[j]) * __expf(al - acs_s[s]) : 0.f;
        o[j] = f2bf(pv);
      }
      *(u16x8*)(&Ts[l*PADC + s0 + qq*8]) = o;
    }
  }
  for (int g = tid; g < 1024; g += 256){
    int p = g >> 4, lg = g & 15;
    *(u16x8*)(&Us[p*PADC + lg*8]) = *(const u16x8*)(X_g + (long)p*SEQL + lg*8);
  }
  __syncthreads();
  const f32x4 zf = {0.f,0.f,0.f,0.f};
  f32x4 accY[4][2];
  #pragma unroll
  for (int i=0;i<4;i++){ accY[i][0]=zf; accY[i][1]=zf; }
  // Y_diag = P @ X^T
  #pragma unroll
  for (int k0=0;k0<128;k0+=32){
    u16x8 af[4], bfv[2];
    #pragma unroll
    for (int i=0;i<4;i++) af[i] = *(const u16x8*)(&Ts[(wl*64+i*16+lidx)*PADC + k0 + krow*8]);
    #pragma unroll
    for (int j=0;j<2;j++) bfv[j] = *(const u16x8*)(&Us[(wp*32+j*16+lidx)*PADC + k0 + krow*8]);
    #pragma unroll
    for (int i=0;i<4;i++)
      #pragma unroll
      for (int j=0;j<2;j++)
        accY[i][j] = MFMA(af[i], bfv[j], accY[i][j]);
  }
  // D-term (reads Us=Xs before restage)
  #pragma unroll
  for (int i=0;i<4;i++)
    #pragma unroll
    for (int j=0;j<2;j++)
      #pragma unroll
      for (int r=0;r<4;r++){
        int l = wl*64 + i*16 + krow*4 + r;
        int p = wp*32 + j*16 + lidx;
        accY[i][j][r] += Dh * bf2f(Us[p*PADC + l]) / dtr_s[l];
      }
  __syncthreads();
  // restage: Ts = C*eacs, Us = states_in
  for (int g = tid; g < 2048; g += 256){
    int l = g >> 4, cb = g & 15;
    u16x8 v = *(const u16x8*)(C_g + (long)l*DSTATE + cb*8);
    float e = eacs_s[l];
    u16x8 o;
    #pragma unroll
    for (int j=0;j<8;j++) o[j] = f2bf(bf2f(v[j])*e);
    *(u16x8*)(&Ts[l*PADC + cb*8]) = o;
  }
  for (int g = tid; g < 1024; g += 256){
    int p = g >> 4, lg = g & 15;
    *(u16x8*)(&Us[p*PADC + lg*8]) = *(const u16x8*)(SI_g + p*128 + lg*8);
  }
  __syncthreads();
  // Y_off = (C*eacs) @ SI^T
  #pragma unroll
  for (int k0=0;k0<128;k0+=32){
    u16x8 af[4], bfv[2];
    #pragma unroll
    for (int i=0;i<4;i++) af[i] = *(const u16x8*)(&Ts[(wl*64+i*16+lidx)*PADC + k0 + krow*8]);
    #pragma unroll
    for (int j=0;j<2;j++) bfv[j] = *(const u16x8*)(&Us[(wp*32+j*16+lidx)*PADC + k0 + krow*8]);
    #pragma unroll
    for (int i=0;i<4;i++)
      #pragma unroll
      for (int j=0;j<2;j++)
        accY[i][j] = MFMA(af[i], bfv[j], accY[i][j]);
  }
  #pragma unroll
  for (int i=0;i<4;i++)
    #pragma unroll
    for (int j=0;j<2;j++)
      #pragma unroll
      for (int r=0;r<4;r++){
        int l = wl*64 + i*16 + krow*4 + r;
        int p = wp*32 + j*16 + lidx;
        y[((long)(b*SEQL + c*128 + l))*DINNER + h*HEADD + p] = f2bf(accY[i][j][r]);
      }
}

// ---------------- fused SSD (fallback if workspace too small) -------------
__global__ __launch_bounds__(256) void k_ssd(
    const u16* __restrict__ Cng, const u16* __restrict__ BTt, const u16* __restrict__ xdtT,
    const u16* __restrict__ CBm, const float* __restrict__ acs_t, const float* __restrict__ dt_t,
    const float* __restrict__ Dparam, u16* __restrict__ y)
{
  __shared__ u16 Cs[128*PADC];
  __shared__ u16 Bs[128*PADC];
  __shared__ u16 Ps[128*PADC];
  __shared__ u16 Xs[64*PADC];
  __shared__ float carry[64*132];
  __shared__ float acs_s[128], eacs_s[128], dec_s[128], dtr_s[128];
  const int bh = blockIdx.x;
  const int b = bh >> 5, h = bh & 31;
  const int tid = threadIdx.x, lane = tid & 63, wid = tid >> 6;
  const int lidx = lane & 15, krow = lane >> 4;
  const int wl = wid & 1, wp = wid >> 1;
  const int wps = wid & 1, wns = wid >> 1;
  for (int i = tid; i < 64*132; i += 256) carry[i] = 0.f;
  const float Dh = Dparam[h];
  const float* acs_g = acs_t + (long)bh*SEQL;
  const float* dt_g = dt_t + (long)bh*SEQL;
  const u16* X_g = xdtT + (long)bh*HEADD*SEQL;
  const u16* B_g = BTt + (long)b*DSTATE*SEQL;
  const u16* C_g = Cng + (long)b*SEQL*DSTATE;
  const u16* CB_g = CBm + (long)b*NCHUNK*CHUNKL*CHUNKL;
  const f32x4 zf = {0.f,0.f,0.f,0.f};
  for (int c=0;c<NCHUNK;c++){
    __syncthreads();
    if (tid < 128){ acs_s[tid] = acs_g[c*128+tid]; dtr_s[tid] = dt_g[c*128+tid]; }
    __syncthreads();
    if (tid < 128){ float a = acs_s[tid]; eacs_s[tid] = __expf(a); dec_s[tid] = __expf(acs_s[127]-a); }
    __syncthreads();
    for (int g = tid; g < 2048; g += 256){
      int l = g >> 4, cb = g & 15;
      u16x8 v = *(const u16x8*)(C_g + ((long)(c*128+l))*DSTATE + cb*8);
      float e = eacs_s[l];
      u16x8 o;
      #pragma unroll
      for (int j=0;j<8;j++) o[j] = f2bf(bf2f(v[j])*e);
      *(u16x8*)(&Cs[l*PADC + cb*8]) = o;
    }
    for (int g = tid; g < 2048; g += 256){
      int n = g >> 4, lg = g & 15;
      u16x8 v = *(const u16x8*)(B_g + (long)n*SEQL + c*128 + lg*8);
      u16x8 o;
      #pragma unroll
      for (int j=0;j<8;j++) o[j] = f2bf(bf2f(v[j])*dec_s[lg*8+j]);
      *(u16x8*)(&Bs[n*PADC + lg*8]) = o;
    }
    for (int g = tid; g < 1024; g += 256){
      int p = g >> 4, lg = g & 15;
      *(u16x8*)(&Xs[p*PADC + lg*8]) = *(const u16x8*)(X_g + (long)p*SEQL + c*128 + lg*8);
    }
    {
      int l = tid >> 1, s0 = (tid & 1)*64;
      float al = acs_s[l];
      #pragma unroll
      for (int q=0;q<8;q++){
        u16x8 v = *(const u16x8*)(CB_g + ((long)(c*128+l))*CHUNKL + s0 + q*8);
        u16x8 o;
        #pragma unroll
        for (int j=0;j<8;j++){
          int s = s0 + q*8 + j;
          float pv = (s <= l) ? bf2f(v[j]) * __expf(al - acs_s[s]) : 0.f;
          o[j] = f2bf(pv);
        }
        *(u16x8*)(&Ps[l*PADC + s0 + q*8]) = o;
      }
    }
    __syncthreads();
    f32x4 accY[4][2];
    f32x4 accS[2][4];
    #pragma unroll
    for (int i=0;i<4;i++){ accY[i][0]=zf; accY[i][1]=zf; }
    #pragma unroll
    for (int i=0;i<2;i++){ accS[i][0]=zf; accS[i][1]=zf; accS[i][2]=zf; accS[i][3]=zf; }
    #pragma unroll
    for (int k0=0;k0<128;k0+=32){
      u16x8 af[4], bfv[2];
      #pragma unroll
      for (int i=0;i<4;i++) af[i] = *(const u16x8*)(&Cs[(wl*64+i*16+lidx)*PADC + k0 + krow*8]);
      #pragma unroll
      for (int j=0;j<2;j++){
        const float* cp = &carry[(wp*32+j*16+lidx)*132 + k0 + krow*8];
        f32x4 c0 = *(const f32x4*)cp;
        f32x4 c1 = *(const f32x4*)(cp+4);
        u16x8 o;
        o[0]=f2bf(c0[0]); o[1]=f2bf(c0[1]); o[2]=f2bf(c0[2]); o[3]=f2bf(c0[3]);
        o[4]=f2bf(c1[0]); o[5]=f2bf(c1[1]); o[6]=f2bf(c1[2]); o[7]=f2bf(c1[3]);
        bfv[j] = o;
      }
      #pragma unroll
      for (int i=0;i<4;i++)
        #pragma unroll
        for (int j=0;j<2;j++)
          accY[i][j] = MFMA(af[i], bfv[j], accY[i][j]);
    }
    #pragma unroll
    for (int k0=0;k0<128;k0+=32){
      u16x8 af[4], bfv[2];
      #pragma unroll
      for (int i=0;i<4;i++) af[i] = *(const u16x8*)(&Ps[(wl*64+i*16+lidx)*PADC + k0 + krow*8]);
      #pragma unroll
      for (int j=0;j<2;j++) bfv[j] = *(const u16x8*)(&Xs[(wp*32+j*16+lidx)*PADC + k0 + krow*8]);
      #pragma unroll
      for (int i=0;i<4;i++)
        #pragma unroll
        for (int j=0;j<2;j++)
          accY[i][j] = MFMA(af[i], bfv[j], accY[i][j]);
    }
    #pragma unroll
    for (int k0=0;k0<128;k0+=32){
      u16x8 as2[2], bs2[4];
      #pragma unroll
      for (int i=0;i<2;i++) as2[i] = *(const u16x8*)(&Xs[(wps*32+i*16+lidx)*PADC + k0 + krow*8]);
      #pragma unroll
      for (int j=0;j<4;j++) bs2[j] = *(const u16x8*)(&Bs[(wns*64+j*16+lidx)*PADC + k0 + krow*8]);
      #pragma unroll
      for (int i=0;i<2;i++)
        #pragma unroll
        for (int j=0;j<4;j++)
          accS[i][j] = MFMA(as2[i], bs2[j], accS[i][j]);
    }
    __syncthreads();
    float cd = __expf(acs_s[127]);
    #pragma unroll
    for (int i=0;i<2;i++)
      #pragma unroll
      for (int j=0;j<4;j++)
        #pragma unroll
        for (int r=0;r<4;r++){
          int p = wps*32 + i*16 + krow*4 + r;
          int n = wns*64 + j*16 + lidx;
          carry[p*132+n] = carry[p*132+n]*cd + accS[i][j][r];
        }
    #pragma unroll
    for (int i=0;i<4;i++)
      #pragma unroll
      for (int j=0;j<2;j++)
        #pragma unroll
        for (int r=0;r<4;r++){
          int l = wl*64 + i*16 + krow*4 + r;
          int p = wp*32 + j*16 + lidx;
          float xv = bf2f(Xs[p*PADC + l]) / dtr_s[l];
          float val = accY[i][j][r] + Dh*xv;
          y[((long)(b*SEQL + c*128 + l))*DINNER + h*HEADD + p] = f2bf(val);
        }
  }
}

// ---------------- gating (silu(z)) + RMSNorm -> bf16 ----------------------
__global__ __launch_bounds__(256) void k_gate(const u16* __restrict__ y, const u16* __restrict__ z,
    const float* __restrict__ norm_w, u16* __restrict__ out)
{
  long row = blockIdx.x;
  const u16* yr = y + row*DINNER;
  const u16* zr = z + row*DINNER;
  int t = threadIdx.x;
  u16x8 yy = *(const u16x8*)(yr + t*8);
  u16x8 zz = *(const u16x8*)(zr + t*8);
  float g[8]; float ss = 0.f;
  #pragma unroll
  for (int j=0;j<8;j++){
    float zfv = bf2f(zz[j]);
    float sg = zfv / (1.f + __expf(-zfv));
    float gv = bf2f(yy[j]) * sg;
    g[j] = gv; ss += gv*gv;
  }
  #pragma unroll
  for (int o=32;o>0;o>>=1) ss += __shfl_down(ss, o);
  __shared__ float part[4];
  int lane = t & 63, wid = t>>6;
  if (lane==0) part[wid] = ss;
  __syncthreads();
  float tot = part[0]+part[1]+part[2]+part[3];
  float inv = rsqrtf(tot*(1.f/DINNER) + 1e-5f);
  u16x8 o;
  #pragma unroll
  for (int j=0;j<8;j++) o[j] = f2bf(g[j]*inv*norm_w[t*8+j]);
  *(u16x8*)(out + row*DINNER + t*8) = o;
}

// ---------------- pred = hidden @ dec_w^T + dec_b -------------------------
__global__ __launch_bounds__(256) void k_pred(const float* __restrict__ hid, const float* __restrict__ dec_w,
    const float* __restrict__ dec_b, float* __restrict__ pred)
{
  int t = threadIdx.x;
  long row = (long)blockIdx.x*8 + (t>>5);
  int lk = t & 31;
  const float* hr = hid + row*DMODEL;
  float a0=0.f,a1=0.f,a2=0.f;
  #pragma unroll
  for (int i=0;i<8;i++){
    f32x4 hv = *(const f32x4*)(hr + lk*4 + i*128);
    f32x4 w0 = *(const f32x4*)(dec_w + 0*DMODEL + lk*4 + i*128);
    f32x4 w1 = *(const f32x4*)(dec_w + 1*DMODEL + lk*4 + i*128);
    f32x4 w2 = *(const f32x4*)(dec_w + 2*DMODEL + lk*4 + i*128);
    a0 += hv[0]*w0[0]+hv[1]*w0[1]+hv[2]*w0[2]+hv[3]*w0[3];
    a1 += hv[0]*w1[0]+hv[1]*w1[1]+hv[2]*w1[2]+hv[3]*w1[3];
    a2 += hv[0]*w2[0]+hv[1]*w2[1]+hv[2]*w2[2]+hv[3]*w2[3];
  }
  #pragma unroll
  for (int o=16;o>0;o>>=1){
    a0 += __shfl_down(a0,o,32); a1 += __shfl_down(a1,o,32); a2 += __shfl_down(a2,o,32);
  }
  if (lk==0){
    pred[row*3+0] = a0 + dec_b[0];
    pred[row*3+1] = a1 + dec_b[1];
    pred[row*3+2] = a2 + dec_b[2];
  }
}

extern "C" void kernel_launch(void* const* d_in, const int* in_sizes, int n_in,
                              void* d_out, int out_size, void* d_ws, size_t ws_size,
                              hipStream_t stream)
{
  const float* embed      = (const float*)d_in[0];
  const float* in_proj_w  = (const float*)d_in[1];
  const float* conv_w     = (const float*)d_in[2];
  const float* conv_b     = (const float*)d_in[3];
  const float* dt_bias    = (const float*)d_in[4];
  const float* A_log      = (const float*)d_in[5];
  const float* Dp         = (const float*)d_in[6];
  const float* norm_w     = (const float*)d_in[7];
  const float* out_proj_w = (const float*)d_in[8];
  const float* dec_w      = (const float*)d_in[9];
  const float* dec_b      = (const float*)d_in[10];

  char* ws = (char*)d_ws;
  size_t off = 0;
  auto alloc = [&](size_t bytes)->void*{ void* p = ws + off; off += (bytes + 255) & ~(size_t)255; return p; };

  // Region 1 (75.5 MB): xbc (GEMM1 -> conv), then y bf16 (ssd path -> gate)
  u16* xbc = (u16*)alloc((size_t)MROWS*CONVD*2);
  u16* yb  = xbc;
  // Region 2 (67.1 MB): Ebf+W1 (phase 1) -> xdtT (conv -> ssd)
  u16* R2  = (u16*)alloc((size_t)MROWS*DINNER*2);
  u16* Ebf = R2;
  u16* W1  = R2 + (size_t)MROWS*DMODEL;
  u16* xdtT  = R2;
  u16* ynorm = R2;
  float* dtraw = (float*)alloc((size_t)MROWS*NHEADS*4);
  float* dt_t  = (float*)alloc((size_t)NBATCH*NHEADS*SEQL*4);
  float* acs   = (float*)alloc((size_t)NBATCH*NHEADS*SEQL*4);
  u16* BTt   = (u16*)alloc((size_t)NBATCH*DSTATE*SEQL*2);
  u16* CTt   = (u16*)alloc((size_t)NBATCH*DSTATE*SEQL*2);
  u16* Cn    = (u16*)alloc((size_t)NBATCH*SEQL*DSTATE*2);
  u16* CBm   = (u16*)alloc((size_t)NBATCH*NCHUNK*CHUNKL*CHUNKL*2);
  u16* W2    = (u16*)alloc((size_t)DMODEL*DINNER*2);

  size_t off_base = off;
  u16* S = (u16*)alloc((size_t)NBATCH*NHEADS*NCHUNK*HEADD*DSTATE*2); // 33.5 MB states
  bool use_par = (off <= ws_size);

  if (off_base > ws_size){
    k_sentinel<<<1,1,0,stream>>>((float*)d_out);
    return;
  }

  float* pred   = (float*)d_out;
  float* hidden = (float*)d_out + (size_t)MROWS*3;
  u16* zb = (u16*)hidden;  // z in d_out hidden region; dead before GEMM2 writes hidden

  hipFuncSetAttribute((const void*)k_gemm8<1>, hipFuncAttributeMaxDynamicSharedMemorySize, 131072);
  hipFuncSetAttribute((const void*)k_gemm8<0>, hipFuncAttributeMaxDynamicSharedMemorySize, 131072);

  k_cvt<<<16384,256,0,stream>>>(embed, Ebf, (long)MROWS*DMODEL, (long)MROWS*DMODEL);
  k_cvt<<<4608,256,0,stream>>>(in_proj_w, W1, (long)NPROJ*DMODEL, (long)NPROJP*DMODEL);
  k_cvt<<<2048,256,0,stream>>>(out_proj_w, W2, (long)DMODEL*DINNER, (long)DMODEL*DINNER);
  {
    dim3 g1(64, NPROJP/256);
    k_gemm8<1><<<g1,512,131072,stream>>>(Ebf, W1, DMODEL, 0, nullptr, zb, xbc, dtraw);
  }
  k_dtprep<<<4096,128,0,stream>>>(dtraw, dt_bias, A_log, dt_t, acs);
  k_conv<<<4608,256,0,stream>>>(xbc, conv_w, conv_b, dt_t, xdtT, BTt, CTt);
  k_cb<<<128,256,0,stream>>>(BTt, CTt, CBm, Cn);
  if (use_par){
    k_par<<<4096,256,0,stream>>>(BTt, xdtT, acs, S);
    k_scan<<<2048,256,0,stream>>>(S, acs);
    k_yoff<<<4096,256,0,stream>>>(Cn, xdtT, CBm, S, acs, dt_t, Dp, yb);
  } else {
    k_ssd<<<256,256,0,stream>>>(Cn, BTt, xdtT, CBm, acs, dt_t, Dp, yb);
  }
  k_gate<<<16384,256,0,stream>>>(yb, zb, norm_w, ynorm);
  {
    dim3 g2(64, DMODEL/256);
    k_gemm8<0><<<g2,512,131072,stream>>>(ynorm, W2, DINNER, DMODEL, hidden, nullptr, nullptr, nullptr);
  }
  k_pred<<<2048,256,0,stream>>>(hidden, dec_w, dec_b, pred);
}

// Round 6
// 533.851 us; speedup vs baseline: 1.4329x; 1.0361x over previous
//
#include <hip/hip_runtime.h>
#include <cstdint>

#define DEVI __device__ __forceinline__

typedef unsigned short u16;
typedef unsigned int u32;
typedef __attribute__((ext_vector_type(4))) float f32x4;
typedef __attribute__((ext_vector_type(8))) u16 u16x8;
typedef __attribute__((ext_vector_type(4))) u16 u16x4;
typedef __attribute__((ext_vector_type(8))) __bf16 bf16x8;

#define SEQL 2048
#define NBATCH 8
#define MROWS (NBATCH*SEQL)
#define DMODEL 1024
#define DINNER 2048
#define NHEADS 32
#define HEADD 64
#define DSTATE 128
#define CONVD 2304
#define NPROJ 4384
#define NPROJP 4608
#define CHUNKL 128
#define NCHUNK 16
#define PADC 136

DEVI float bf2f(u16 v){ u32 u = ((u32)v)<<16; return __builtin_bit_cast(float,u); }
DEVI u16 f2bf(float f){ u32 u = __builtin_bit_cast(u32,f); u32 r = (u + 0x7fffu + ((u>>16)&1u))>>16; return (u16)r; }

DEVI void gld_lds16(const void* g, void* lds){
  __builtin_amdgcn_global_load_lds(
    (const __attribute__((address_space(1))) void*)(uintptr_t)g,
    (__attribute__((address_space(3))) void*)(u32)(uintptr_t)lds, 16, 0, 0);
}

DEVI f32x4 MFMA(u16x8 a, u16x8 b, f32x4 c){
  return __builtin_amdgcn_mfma_f32_16x16x32_bf16(
      __builtin_bit_cast(bf16x8,a), __builtin_bit_cast(bf16x8,b), c, 0,0,0);
}

__global__ void k_sentinel(float* o){ o[0] = 12345.0f; }

// ---------------- convert f32 -> bf16 (with zero-pad tail) ----------------
__global__ __launch_bounds__(256) void k_cvt(const float* __restrict__ src, u16* __restrict__ dst, long n, long ntot){
  long idx = ((long)blockIdx.x*256 + threadIdx.x)*4;
  if (idx >= ntot) return;
  u16x4 o;
  if (idx < n){
    f32x4 v = *(const f32x4*)(src+idx);
    o[0]=f2bf(v[0]); o[1]=f2bf(v[1]); o[2]=f2bf(v[2]); o[3]=f2bf(v[3]);
  } else { o[0]=0; o[1]=0; o[2]=0; o[3]=0; }
  *(u16x4*)(dst+idx) = o;
}

// ================= 256^2 8-phase GEMM (T1+T2+T3+T4+T5) ====================
#define STG(mat, h, ts) do { \
    const int d_ = (ts) & 1; \
    const size_t ko_ = (size_t)(((ts) < NT) ? (ts) : (NT-1)) * 64; \
    gld_lds16(sbase[mat][h][0] + ko_, (char*)lds + (mat)*65536 + (d_*2+(h))*16384 + tid*16); \
    gld_lds16(sbase[mat][h][1] + ko_, (char*)lds + (mat)*65536 + (d_*2+(h))*16384 + 8192 + tid*16); \
  } while(0)

#define LDA8(AF, d_, qm) { \
    _Pragma("unroll") for (int mf=0; mf<4; mf++) \
    _Pragma("unroll") for (int ks=0; ks<2; ks++) \
      AF[mf][ks] = *(const u16x8*)(lds + (size_t)((d_)*2+wm)*8192 + ((qm)*64+mf*16+lidx)*64 + ((ks*4+krow)^(lidx&7))*8); }

#define LDB4(BF, d_, qn) { \
    _Pragma("unroll") for (int nf=0; nf<2; nf++) \
    _Pragma("unroll") for (int ks=0; ks<2; ks++) \
      BF[nf][ks] = *(const u16x8*)(lds + 32768 + (size_t)((d_)*2+(wn>>1))*8192 + ((wn&1)*64+(qn)*32+nf*16+lidx)*64 + ((ks*4+krow)^(lidx&7))*8); }

#define MMAQ(QM, QN, AF, BF) { \
    _Pragma("unroll") for (int mf=0; mf<4; mf++) \
    _Pragma("unroll") for (int nf=0; nf<2; nf++) \
    _Pragma("unroll") for (int ks=0; ks<2; ks++) \
      acc[(QM)*4+mf][(QN)*2+nf] = MFMA(AF[mf][ks], BF[nf][ks], acc[(QM)*4+mf][(QN)*2+nf]); }

#define BAR1 __builtin_amdgcn_sched_barrier(0); __builtin_amdgcn_s_barrier(); \
    asm volatile("s_waitcnt lgkmcnt(0)" ::: "memory"); __builtin_amdgcn_sched_barrier(0); \
    __builtin_amdgcn_s_setprio(1);
#define BAR2 __builtin_amdgcn_s_setprio(0); __builtin_amdgcn_sched_barrier(0); \
    __builtin_amdgcn_s_barrier(); __builtin_amdgcn_sched_barrier(0);

template<int MODE>
__global__ __launch_bounds__(512, 2) void k_gemm8(const u16* __restrict__ A, const u16* __restrict__ Bt,
    const int K, const int Ndim, float* __restrict__ outF,
    u16* __restrict__ z_out, u16* __restrict__ xbc_out, float* __restrict__ dtraw_out)
{
  extern __shared__ u16 lds[];
  const int NT = K >> 6;
  const int tid = threadIdx.x;
  const int lane = tid & 63, wid = tid >> 6;
  const int wm = wid >> 2, wn = wid & 3;
  const int lidx = lane & 15, krow = lane >> 4;
  // ---- L2-aware mapping: bijective chunked XCD transform (m204) composed
  // with GROUP_M grouping: each XCD owns a contiguous pid chunk; within it,
  // an 8-m-tile A-band (4MB, L2-resident) is walked n-fastest-in-groups.
  const int nmt = gridDim.x, nnt = gridDim.y;
  const int nwg = nmt * nnt;
  const int orig = blockIdx.y * nmt + blockIdx.x;
  const int qq = nwg >> 3, rr = nwg & 7;
  const int xcd = orig & 7, li = orig >> 3;
  const int pid = (xcd < rr ? xcd*(qq+1) : rr*(qq+1) + (xcd-rr)*qq) + li;
  const int GM = 8;                       // nmt % 8 == 0 for both launches
  const int npg = GM * nnt;
  const int gid = pid / npg;
  const int rem = pid % npg;
  const int m0 = (gid*GM + (rem & (GM-1))) * 256;
  const int n0 = (rem / GM) * 256;

  f32x4 acc[8][4];
  const f32x4 zf = {0.f,0.f,0.f,0.f};
  #pragma unroll
  for (int i=0;i<8;i++)
    #pragma unroll
    for (int j=0;j<4;j++) acc[i][j] = zf;

  const int r0 = tid >> 3;
  const int gsw = ((tid & 7) ^ (r0 & 7)) * 8;
  const u16* sbase[2][2][2];
  #pragma unroll
  for (int h=0; h<2; h++)
    #pragma unroll
    for (int L=0; L<2; L++){
      sbase[0][h][L] = A  + (size_t)(m0 + h*128 + L*64 + r0)*K + gsw;
      sbase[1][h][L] = Bt + (size_t)(n0 + h*128 + L*64 + r0)*K + gsw;
    }

  STG(0,0,0); STG(0,1,0); STG(1,0,0); STG(1,1,0);
  asm volatile("s_waitcnt vmcnt(4)" ::: "memory");
  STG(0,0,1); STG(0,1,1); STG(1,0,1);
  asm volatile("s_waitcnt vmcnt(6)" ::: "memory");
  __builtin_amdgcn_sched_barrier(0);
  __builtin_amdgcn_s_barrier();
  __builtin_amdgcn_sched_barrier(0);

  u16x8 af[4][2], bf0[2][2], bf1[2][2];
  for (int t = 0; t < NT; t += 2){
    LDA8(af, 0, 0); LDB4(bf0, 0, 0); STG(1,1,t+1);
    BAR1; MMAQ(0,0,af,bf0); BAR2;
    LDB4(bf1, 0, 1);
    BAR1; MMAQ(0,1,af,bf1); BAR2;
    LDA8(af, 0, 1); STG(1,0,t+2);
    BAR1; MMAQ(1,1,af,bf1); BAR2;
    STG(0,0,t+2); STG(0,1,t+2);
    asm volatile("s_waitcnt vmcnt(6)" ::: "memory");
    BAR1; MMAQ(1,0,af,bf0); BAR2;
    LDA8(af, 1, 0); LDB4(bf0, 1, 0); STG(1,1,t+2);
    BAR1; MMAQ(0,0,af,bf0); BAR2;
    LDB4(bf1, 1, 1);
    BAR1; MMAQ(0,1,af,bf1); BAR2;
    LDA8(af, 1, 1); STG(1,0,t+3);
    BAR1; MMAQ(1,1,af,bf1); BAR2;
    STG(0,0,t+3); STG(0,1,t+3);
    asm volatile("s_waitcnt vmcnt(6)" ::: "memory");
    BAR1; MMAQ(1,0,af,bf0); BAR2;
  }
  asm volatile("s_waitcnt vmcnt(0)" ::: "memory");

  #pragma unroll
  for (int im=0; im<8; im++)
    #pragma unroll
    for (int in=0; in<4; in++)
      #pragma unroll
      for (int r=0; r<4; r++){
        int gm = m0 + wm*128 + im*16 + krow*4 + r;
        int gn = n0 + wn*64 + in*16 + lidx;
        float v = acc[im][in][r];
        if (MODE==0){
          outF[(long)gm*Ndim + gn] = v;
        } else {
          if (gn < DINNER) z_out[(long)gm*DINNER + gn] = f2bf(v);
          else if (gn < DINNER+CONVD) xbc_out[(long)gm*CONVD + (gn-DINNER)] = f2bf(v);
          else if (gn < NPROJ) dtraw_out[(long)gm*NHEADS + (gn-DINNER-CONVD)] = v;
        }
      }
}

// ---------------- dt prep: softplus + per-chunk inclusive cumsum ----------
__global__ __launch_bounds__(128) void k_dtprep(const float* __restrict__ dtraw, const float* __restrict__ dt_bias,
    const float* __restrict__ A_log, float* __restrict__ dt_t, float* __restrict__ acs_t)
{
  int b = blockIdx.x >> 9;
  int h = (blockIdx.x >> 4) & 31;
  int c = blockIdx.x & 15;
  int l = threadIdx.x;
  int gl = c*128 + l;
  float raw = dtraw[((long)(b*SEQL + gl))*NHEADS + h] + dt_bias[h];
  float dt = (raw > 20.f) ? raw : log1pf(expf(raw));
  float A = -expf(A_log[h]);
  float ac = dt*A;
  __shared__ float ss[128];
  ss[l] = ac; __syncthreads();
  for (int o=1;o<128;o<<=1){
    float v = (l>=o)? ss[l-o] : 0.f;
    __syncthreads();
    ss[l] += v;
    __syncthreads();
  }
  float acs = ss[l];
  dt_t[((long)(b*NHEADS+h))*SEQL + gl] = dt;
  acs_t[((long)(b*NHEADS+h))*SEQL + gl] = acs;
}

// ---------------- causal depthwise conv + silu; split outputs -------------
__global__ __launch_bounds__(256) void k_conv(const u16* __restrict__ xbc, const float* __restrict__ conv_w,
    const float* __restrict__ conv_b, const float* __restrict__ dt_t,
    u16* __restrict__ xdtT, u16* __restrict__ BTt, u16* __restrict__ CTt)
{
  __shared__ u16 sm[131*64];
  int idx = blockIdx.x;
  int b = idx / 576; int rem = idx % 576; int cbk = rem >> 4; int lb = rem & 15;
  int ch0 = cbk*64, l0 = lb*128;
  for (int g = threadIdx.x; g < 131*8; g += 256){
    int r = g >> 3, cg = g & 7;
    int gl = l0 - 3 + r;
    u16x8 v;
    if (gl >= 0) v = *(const u16x8*)(xbc + ((long)(b*SEQL+gl))*CONVD + ch0 + cg*8);
    else { v[0]=0;v[1]=0;v[2]=0;v[3]=0;v[4]=0;v[5]=0;v[6]=0;v[7]=0; }
    *(u16x8*)(&sm[r*64 + cg*8]) = v;
  }
  __syncthreads();
  int ci = threadIdx.x & 63, g4 = threadIdx.x >> 6;
  int chg = ch0 + ci;
  f32x4 wv = *(const f32x4*)(conv_w + chg*4);
  float bia = conv_b[chg];
  bool isX = chg < DINNER;
  int h = chg >> 6; if (h > 31) h = 31;
  int p = chg & 63;
  const float* dtrow = dt_t + ((long)(b*NHEADS+h))*SEQL + l0 + g4*32;
  u16x8 ov[4];
  #pragma unroll
  for (int i=0;i<32;i++){
    int lr = g4*32 + i;
    float a = bia + wv[0]*bf2f(sm[(lr+0)*64+ci]) + wv[1]*bf2f(sm[(lr+1)*64+ci])
                  + wv[2]*bf2f(sm[(lr+2)*64+ci]) + wv[3]*bf2f(sm[(lr+3)*64+ci]);
    float s = a / (1.f + __expf(-a));
    if (isX) s *= dtrow[i];
    ov[i>>3][i&7] = f2bf(s);
  }
  u16* dst;
  if (isX)                      dst = xdtT + (((long)(b*NHEADS+h))*HEADD + p)*SEQL + l0 + g4*32;
  else if (chg < DINNER+DSTATE) dst = BTt + ((long)(b*DSTATE + (chg-DINNER)))*SEQL + l0 + g4*32;
  else                          dst = CTt + ((long)(b*DSTATE + (chg-DINNER-DSTATE)))*SEQL + l0 + g4*32;
  #pragma unroll
  for (int q=0;q<4;q++) *(u16x8*)(dst + q*8) = ov[q];
}

// ---------------- per (b,chunk): CB = C*B^T (unmasked), and Cn (l,n) ------
__global__ __launch_bounds__(256) void k_cb(const u16* __restrict__ BTt, const u16* __restrict__ CTt,
      u16* __restrict__ CBm, u16* __restrict__ Cn)
{
  __shared__ u16 Cl[128*136];
  __shared__ u16 Bl[128*136];
  int b = blockIdx.x >> 4, c = blockIdx.x & 15;
  for (int g = threadIdx.x; g < 2048; g += 256){
    int n = g >> 4, lg = g & 15;
    u16x8 vc = *(const u16x8*)(CTt + ((long)(b*DSTATE+n))*SEQL + c*CHUNKL + lg*8);
    u16x8 vb = *(const u16x8*)(BTt + ((long)(b*DSTATE+n))*SEQL + c*CHUNKL + lg*8);
    #pragma unroll
    for (int j=0;j<8;j++){
      Cl[(lg*8+j)*136 + n] = vc[j];
      Bl[(lg*8+j)*136 + n] = vb[j];
    }
  }
  __syncthreads();
  const int tid = threadIdx.x;
  const int lane = tid & 63, wid = tid >> 6;
  const int wr = wid & 1, wc2 = wid >> 1;
  const int lidx = lane & 15, krow = lane >> 4;
  const f32x4 zf = {0.f,0.f,0.f,0.f};
  f32x4 acc[4][4];
  #pragma unroll
  for (int i=0;i<4;i++)
    #pragma unroll
    for (int j=0;j<4;j++) acc[i][j] = zf;
  #pragma unroll
  for (int k0=0;k0<128;k0+=32){
    u16x8 af[4], bfv[4];
    #pragma unroll
    for (int i=0;i<4;i++){
      af[i]  = *(const u16x8*)(&Cl[(wr*64+i*16+lidx)*136 + k0 + krow*8]);
      bfv[i] = *(const u16x8*)(&Bl[(wc2*64+i*16+lidx)*136 + k0 + krow*8]);
    }
    #pragma unroll
    for (int i=0;i<4;i++)
      #pragma unroll
      for (int j=0;j<4;j++)
        acc[i][j] = MFMA(af[i], bfv[j], acc[i][j]);
  }
  long base = ((long)(b*16+c))*128*128;
  #pragma unroll
  for (int i=0;i<4;i++)
    #pragma unroll
    for (int j=0;j<4;j++)
      #pragma unroll
      for (int r=0;r<4;r++){
        int l = wr*64+i*16+krow*4+r;
        int s = wc2*64+j*16+lidx;
        CBm[base + (long)l*128 + s] = f2bf(acc[i][j][r]);
      }
  for (int g = tid; g < 2048; g += 256){
    int l = g >> 4, ng = g & 15;
    u16x8 o;
    #pragma unroll
    for (int j=0;j<8;j++) o[j] = Cl[l*136 + ng*8 + j];
    *(u16x8*)(Cn + ((long)(b*SEQL + c*CHUNKL + l))*DSTATE + ng*8) = o;
  }
}

// ============ parallel SSD path ============
__global__ __launch_bounds__(256) void k_par(
    const u16* __restrict__ BTt, const u16* __restrict__ xdtT,
    const float* __restrict__ acs_t, u16* __restrict__ states)
{
  __shared__ u16 Bs[128*PADC];
  __shared__ u16 Xs[64*PADC];
  __shared__ float acs_s[128], dec_s[128];
  const int idx = blockIdx.x;
  const int c = idx & 15, bh = idx >> 4, b = bh >> 5;
  const int tid = threadIdx.x, lane = tid & 63, wid = tid >> 6;
  const int lidx = lane & 15, krow = lane >> 4;
  const int wps = wid & 1, wns = wid >> 1;
  const float* acs_g = acs_t + (long)bh*SEQL + c*128;
  const u16* X_g = xdtT + (long)bh*HEADD*SEQL + c*128;
  const u16* B_g = BTt + (long)b*DSTATE*SEQL + c*128;
  if (tid < 128) acs_s[tid] = acs_g[tid];
  __syncthreads();
  if (tid < 128) dec_s[tid] = __expf(acs_s[127] - acs_s[tid]);
  __syncthreads();
  for (int g = tid; g < 2048; g += 256){
    int n = g >> 4, lg = g & 15;
    u16x8 v = *(const u16x8*)(B_g + (long)n*SEQL + lg*8);
    u16x8 o;
    #pragma unroll
    for (int j=0;j<8;j++) o[j] = f2bf(bf2f(v[j])*dec_s[lg*8+j]);
    *(u16x8*)(&Bs[n*PADC + lg*8]) = o;
  }
  for (int g = tid; g < 1024; g += 256){
    int p = g >> 4, lg = g & 15;
    *(u16x8*)(&Xs[p*PADC + lg*8]) = *(const u16x8*)(X_g + (long)p*SEQL + lg*8);
  }
  __syncthreads();
  const f32x4 zf = {0.f,0.f,0.f,0.f};
  f32x4 accS[2][4];
  #pragma unroll
  for (int i=0;i<2;i++){ accS[i][0]=zf; accS[i][1]=zf; accS[i][2]=zf; accS[i][3]=zf; }
  #pragma unroll
  for (int k0=0;k0<128;k0+=32){
    u16x8 as2[2], bs2[4];
    #pragma unroll
    for (int i=0;i<2;i++) as2[i] = *(const u16x8*)(&Xs[(wps*32+i*16+lidx)*PADC + k0 + krow*8]);
    #pragma unroll
    for (int j=0;j<4;j++) bs2[j] = *(const u16x8*)(&Bs[(wns*64+j*16+lidx)*PADC + k0 + krow*8]);
    #pragma unroll
    for (int i=0;i<2;i++)
      #pragma unroll
      for (int j=0;j<4;j++)
        accS[i][j] = MFMA(as2[i], bs2[j], accS[i][j]);
  }
  u16* Sg = states + (long)idx*8192;
  #pragma unroll
  for (int i=0;i<2;i++)
    #pragma unroll
    for (int j=0;j<4;j++)
      #pragma unroll
      for (int r=0;r<4;r++){
        int p = wps*32 + i*16 + krow*4 + r;
        int n = wns*64 + j*16 + lidx;
        Sg[p*128 + n] = f2bf(accS[i][j][r]);
      }
}

__global__ __launch_bounds__(256) void k_scan(u16* __restrict__ states, const float* __restrict__ acs_t)
{
  long gid = (long)blockIdx.x*256 + threadIdx.x;
  int bh = (int)(gid >> 11);
  int q = (int)(gid & 2047);
  __shared__ float cds[16];
  if (threadIdx.x < 16) cds[threadIdx.x] = __expf(acs_t[(long)bh*SEQL + threadIdx.x*128 + 127]);
  __syncthreads();
  u16* p = states + (long)bh*NCHUNK*8192 + q*4;
  u16x4 sv[16];
  #pragma unroll
  for (int c=0;c<16;c++) sv[c] = *(const u16x4*)(p + c*8192);
  float c0=0.f,c1=0.f,c2=0.f,c3=0.f;
  #pragma unroll
  for (int c=0;c<16;c++){
    u16x4 o; o[0]=f2bf(c0); o[1]=f2bf(c1); o[2]=f2bf(c2); o[3]=f2bf(c3);
    *(u16x4*)(p + c*8192) = o;
    float cd = cds[c];
    c0 = c0*cd + bf2f(sv[c][0]);
    c1 = c1*cd + bf2f(sv[c][1]);
    c2 = c2*cd + bf2f(sv[c][2]);
    c3 = c3*cd + bf2f(sv[c][3]);
  }
}

__global__ __launch_bounds__(256) void k_yoff(
    const u16* __restrict__ Cng, const u16* __restrict__ xdtT, const u16* __restrict__ CBm,
    const u16* __restrict__ SI, const float* __restrict__ acs_t, const float* __restrict__ dt_t,
    const float* __restrict__ Dparam, u16* __restrict__ y)
{
  __shared__ u16 Ts[128*PADC];
  __shared__ u16 Us[64*PADC];
  __shared__ float acs_s[128], dtr_s[128], eacs_s[128];
  const int idx = blockIdx.x;
  const int c = idx & 15, bh = idx >> 4, b = bh >> 5, h = bh & 31;
  const int tid = threadIdx.x, lane = tid & 63, wid = tid >> 6;
  const int lidx = lane & 15, krow = lane >> 4;
  const int wl = wid & 1, wp = wid >> 1;
  const float Dh = Dparam[h];
  const float* acs_g = acs_t + (long)bh*SEQL + c*128;
  const float* dt_g  = dt_t  + (long)bh*SEQL + c*128;
  const u16* X_g = xdtT + (long)bh*HEADD*SEQL + c*128;
  const u16* C_g = Cng + ((long)(b*SEQL + c*128))*DSTATE;
  const u16* CB_g = CBm + ((long)(b*NCHUNK + c))*CHUNKL*CHUNKL;
  const u16* SI_g = SI + (long)idx*8192;
  if (tid < 128){ acs_s[tid] = acs_g[tid]; dtr_s[tid] = dt_g[tid]; }
  __syncthreads();
  if (tid < 128) eacs_s[tid] = __expf(acs_s[tid]);
  __syncthreads();
  {
    int l = tid >> 1, s0 = (tid & 1)*64;
    float al = acs_s[l];
    #pragma unroll
    for (int qq=0;qq<8;qq++){
      u16x8 v = *(const u16x8*)(CB_g + (long)l*CHUNKL + s0 + qq*8);
      u16x8 o;
      #pragma unroll
      for (int j=0;j<8;j++){
        int s = s0 + qq*8 + j;
        float pv = (s <= l) ? bf2f(v[j]) * __expf(al - acs_s[s]) : 0.f;
        o[j] = f2bf(pv);
      }
      *(u16x8*)(&Ts[l*PADC + s0 + qq*8]) = o;
    }
  }
  for (int g = tid; g < 1024; g += 256){
    int p = g >> 4, lg = g & 15;
    *(u16x8*)(&Us[p*PADC + lg*8]) = *(const u16x8*)(X_g + (long)p*SEQL + lg*8);
  }
  __syncthreads();
  const f32x4 zf = {0.f,0.f,0.f,0.f};
  f32x4 accY[4][2];
  #pragma unroll
  for (int i=0;i<4;i++){ accY[i][0]=zf; accY[i][1]=zf; }
  #pragma unroll
  for (int k0=0;k0<128;k0+=32){
    u16x8 af[4], bfv[2];
    #pragma unroll
    for (int i=0;i<4;i++) af[i] = *(const u16x8*)(&Ts[(wl*64+i*16+lidx)*PADC + k0 + krow*8]);
    #pragma unroll
    for (int j=0;j<2;j++) bfv[j] = *(const u16x8*)(&Us[(wp*32+j*16+lidx)*PADC + k0 + krow*8]);
    #pragma unroll
    for (int i=0;i<4;i++)
      #pragma unroll
      for (int j=0;j<2;j++)
        accY[i][j] = MFMA(af[i], bfv[j], accY[i][j]);
  }
  #pragma unroll
  for (int i=0;i<4;i++)
    #pragma unroll
    for (int j=0;j<2;j++)
      #pragma unroll
      for (int r=0;r<4;r++){
        int l = wl*64 + i*16 + krow*4 + r;
        int p = wp*32 + j*16 + lidx;
        accY[i][j][r] += Dh * bf2f(Us[p*PADC + l]) / dtr_s[l];
      }
  __syncthreads();
  for (int g = tid; g < 2048; g += 256){
    int l = g >> 4, cb = g & 15;
    u16x8 v = *(const u16x8*)(C_g + (long)l*DSTATE + cb*8);
    float e = eacs_s[l];
    u16x8 o;
    #pragma unroll
    for (int j=0;j<8;j++) o[j] = f2bf(bf2f(v[j])*e);
    *(u16x8*)(&Ts[l*PADC + cb*8]) = o;
  }
  for (int g = tid; g < 1024; g += 256){
    int p = g >> 4, lg = g & 15;
    *(u16x8*)(&Us[p*PADC + lg*8]) = *(const u16x8*)(SI_g + p*128 + lg*8);
  }
  __syncthreads();
  #pragma unroll
  for (int k0=0;k0<128;k0+=32){
    u16x8 af[4], bfv[2];
    #pragma unroll
    for (int i=0;i<4;i++) af[i] = *(const u16x8*)(&Ts[(wl*64+i*16+lidx)*PADC + k0 + krow*8]);
    #pragma unroll
    for (int j=0;j<2;j++) bfv[j] = *(const u16x8*)(&Us[(wp*32+j*16+lidx)*PADC + k0 + krow*8]);
    #pragma unroll
    for (int i=0;i<4;i++)
      #pragma unroll
      for (int j=0;j<2;j++)
        accY[i][j] = MFMA(af[i], bfv[j], accY[i][j]);
  }
  #pragma unroll
  for (int i=0;i<4;i++)
    #pragma unroll
    for (int j=0;j<2;j++)
      #pragma unroll
      for (int r=0;r<4;r++){
        int l = wl*64 + i*16 + krow*4 + r;
        int p = wp*32 + j*16 + lidx;
        y[((long)(b*SEQL + c*128 + l))*DINNER + h*HEADD + p] = f2bf(accY[i][j][r]);
      }
}

// ---------------- fused SSD (fallback if workspace too small) -------------
__global__ __launch_bounds__(256) void k_ssd(
    const u16* __restrict__ Cng, const u16* __restrict__ BTt, const u16* __restrict__ xdtT,
    const u16* __restrict__ CBm, const float* __restrict__ acs_t, const float* __restrict__ dt_t,
    const float* __restrict__ Dparam, u16* __restrict__ y)
{
  __shared__ u16 Cs[128*PADC];
  __shared__ u16 Bs[128*PADC];
  __shared__ u16 Ps[128*PADC];
  __shared__ u16 Xs[64*PADC];
  __shared__ float carry[64*132];
  __shared__ float acs_s[128], eacs_s[128], dec_s[128], dtr_s[128];
  const int bh = blockIdx.x;
  const int b = bh >> 5, h = bh & 31;
  const int tid = threadIdx.x, lane = tid & 63, wid = tid >> 6;
  const int lidx = lane & 15, krow = lane >> 4;
  const int wl = wid & 1, wp = wid >> 1;
  const int wps = wid & 1, wns = wid >> 1;
  for (int i = tid; i < 64*132; i += 256) carry[i] = 0.f;
  const float Dh = Dparam[h];
  const float* acs_g = acs_t + (long)bh*SEQL;
  const float* dt_g = dt_t + (long)bh*SEQL;
  const u16* X_g = xdtT + (long)bh*HEADD*SEQL;
  const u16* B_g = BTt + (long)b*DSTATE*SEQL;
  const u16* C_g = Cng + (long)b*SEQL*DSTATE;
  const u16* CB_g = CBm + (long)b*NCHUNK*CHUNKL*CHUNKL;
  const f32x4 zf = {0.f,0.f,0.f,0.f};
  for (int c=0;c<NCHUNK;c++){
    __syncthreads();
    if (tid < 128){ acs_s[tid] = acs_g[c*128+tid]; dtr_s[tid] = dt_g[c*128+tid]; }
    __syncthreads();
    if (tid < 128){ float a = acs_s[tid]; eacs_s[tid] = __expf(a); dec_s[tid] = __expf(acs_s[127]-a); }
    __syncthreads();
    for (int g = tid; g < 2048; g += 256){
      int l = g >> 4, cb = g & 15;
      u16x8 v = *(const u16x8*)(C_g + ((long)(c*128+l))*DSTATE + cb*8);
      float e = eacs_s[l];
      u16x8 o;
      #pragma unroll
      for (int j=0;j<8;j++) o[j] = f2bf(bf2f(v[j])*e);
      *(u16x8*)(&Cs[l*PADC + cb*8]) = o;
    }
    for (int g = tid; g < 2048; g += 256){
      int n = g >> 4, lg = g & 15;
      u16x8 v = *(const u16x8*)(B_g + (long)n*SEQL + c*128 + lg*8);
      u16x8 o;
      #pragma unroll
      for (int j=0;j<8;j++) o[j] = f2bf(bf2f(v[j])*dec_s[lg*8+j]);
      *(u16x8*)(&Bs[n*PADC + lg*8]) = o;
    }
    for (int g = tid; g < 1024; g += 256){
      int p = g >> 4, lg = g & 15;
      *(u16x8*)(&Xs[p*PADC + lg*8]) = *(const u16x8*)(X_g + (long)p*SEQL + c*128 + lg*8);
    }
    {
      int l = tid >> 1, s0 = (tid & 1)*64;
      float al = acs_s[l];
      #pragma unroll
      for (int q=0;q<8;q++){
        u16x8 v = *(const u16x8*)(CB_g + ((long)(c*128+l))*CHUNKL + s0 + q*8);
        u16x8 o;
        #pragma unroll
        for (int j=0;j<8;j++){
          int s = s0 + q*8 + j;
          float pv = (s <= l) ? bf2f(v[j]) * __expf(al - acs_s[s]) : 0.f;
          o[j] = f2bf(pv);
        }
        *(u16x8*)(&Ps[l*PADC + s0 + q*8]) = o;
      }
    }
    __syncthreads();
    f32x4 accY[4][2];
    f32x4 accS[2][4];
    #pragma unroll
    for (int i=0;i<4;i++){ accY[i][0]=zf; accY[i][1]=zf; }
    #pragma unroll
    for (int i=0;i<2;i++){ accS[i][0]=zf; accS[i][1]=zf; accS[i][2]=zf; accS[i][3]=zf; }
    #pragma unroll
    for (int k0=0;k0<128;k0+=32){
      u16x8 af[4], bfv[2];
      #pragma unroll
      for (int i=0;i<4;i++) af[i] = *(const u16x8*)(&Cs[(wl*64+i*16+lidx)*PADC + k0 + krow*8]);
      #pragma unroll
      for (int j=0;j<2;j++){
        const float* cp = &carry[(wp*32+j*16+lidx)*132 + k0 + krow*8];
        f32x4 c0 = *(const f32x4*)cp;
        f32x4 c1 = *(const f32x4*)(cp+4);
        u16x8 o;
        o[0]=f2bf(c0[0]); o[1]=f2bf(c0[1]); o[2]=f2bf(c0[2]); o[3]=f2bf(c0[3]);
        o[4]=f2bf(c1[0]); o[5]=f2bf(c1[1]); o[6]=f2bf(c1[2]); o[7]=f2bf(c1[3]);
        bfv[j] = o;
      }
      #pragma unroll
      for (int i=0;i<4;i++)
        #pragma unroll
        for (int j=0;j<2;j++)
          accY[i][j] = MFMA(af[i], bfv[j], accY[i][j]);
    }
    #pragma unroll
    for (int k0=0;k0<128;k0+=32){
      u16x8 af[4], bfv[2];
      #pragma unroll
      for (int i=0;i<4;i++) af[i] = *(const u16x8*)(&Ps[(wl*64+i*16+lidx)*PADC + k0 + krow*8]);
      #pragma unroll
      for (int j=0;j<2;j++) bfv[j] = *(const u16x8*)(&Xs[(wp*32+j*16+lidx)*PADC + k0 + krow*8]);
      #pragma unroll
      for (int i=0;i<4;i++)
        #pragma unroll
        for (int j=0;j<2;j++)
          accY[i][j] = MFMA(af[i], bfv[j], accY[i][j]);
    }
    #pragma unroll
    for (int k0=0;k0<128;k0+=32){
      u16x8 as2[2], bs2[4];
      #pragma unroll
      for (int i=0;i<2;i++) as2[i] = *(const u16x8*)(&Xs[(wps*32+i*16+lidx)*PADC + k0 + krow*8]);
      #pragma unroll
      for (int j=0;j<4;j++) bs2[j] = *(const u16x8*)(&Bs[(wns*64+j*16+lidx)*PADC + k0 + krow*8]);
      #pragma unroll
      for (int i=0;i<2;i++)
        #pragma unroll
        for (int j=0;j<4;j++)
          accS[i][j] = MFMA(as2[i], bs2[j], accS[i][j]);
    }
    __syncthreads();
    float cd = __expf(acs_s[127]);
    #pragma unroll
    for (int i=0;i<2;i++)
      #pragma unroll
      for (int j=0;j<4;j++)
        #pragma unroll
        for (int r=0;r<4;r++){
          int p = wps*32 + i*16 + krow*4 + r;
          int n = wns*64 + j*16 + lidx;
          carry[p*132+n] = carry[p*132+n]*cd + accS[i][j][r];
        }
    #pragma unroll
    for (int i=0;i<4;i++)
      #pragma unroll
      for (int j=0;j<2;j++)
        #pragma unroll
        for (int r=0;r<4;r++){
          int l = wl*64 + i*16 + krow*4 + r;
          int p = wp*32 + j*16 + lidx;
          float xv = bf2f(Xs[p*PADC + l]) / dtr_s[l];
          float val = accY[i][j][r] + Dh*xv;
          y[((long)(b*SEQL + c*128 + l))*DINNER + h*HEADD + p] = f2bf(val);
        }
  }
}

// ---------------- gating (silu(z)) + RMSNorm -> bf16 ----------------------
__global__ __launch_bounds__(256) void k_gate(const u16* __restrict__ y, const u16* __restrict__ z,
    const float* __restrict__ norm_w, u16* __restrict__ out)
{
  long row = blockIdx.x;
  const u16* yr = y + row*DINNER;
  const u16* zr = z + row*DINNER;
  int t = threadIdx.x;
  u16x8 yy = *(const u16x8*)(yr + t*8);
  u16x8 zz = *(const u16x8*)(zr + t*8);
  float g[8]; float ss = 0.f;
  #pragma unroll
  for (int j=0;j<8;j++){
    float zfv = bf2f(zz[j]);
    float sg = zfv / (1.f + __expf(-zfv));
    float gv = bf2f(yy[j]) * sg;
    g[j] = gv; ss += gv*gv;
  }
  #pragma unroll
  for (int o=32;o>0;o>>=1) ss += __shfl_down(ss, o);
  __shared__ float part[4];
  int lane = t & 63, wid = t>>6;
  if (lane==0) part[wid] = ss;
  __syncthreads();
  float tot = part[0]+part[1]+part[2]+part[3];
  float inv = rsqrtf(tot*(1.f/DINNER) + 1e-5f);
  u16x8 o;
  #pragma unroll
  for (int j=0;j<8;j++) o[j] = f2bf(g[j]*inv*norm_w[t*8+j]);
  *(u16x8*)(out + row*DINNER + t*8) = o;
}

// ---------------- pred = hidden @ dec_w^T + dec_b -------------------------
__global__ __launch_bounds__(256) void k_pred(const float* __restrict__ hid, const float* __restrict__ dec_w,
    const float* __restrict__ dec_b, float* __restrict__ pred)
{
  int t = threadIdx.x;
  long row = (long)blockIdx.x*8 + (t>>5);
  int lk = t & 31;
  const float* hr = hid + row*DMODEL;
  float a0=0.f,a1=0.f,a2=0.f;
  #pragma unroll
  for (int i=0;i<8;i++){
    f32x4 hv = *(const f32x4*)(hr + lk*4 + i*128);
    f32x4 w0 = *(const f32x4*)(dec_w + 0*DMODEL + lk*4 + i*128);
    f32x4 w1 = *(const f32x4*)(dec_w + 1*DMODEL + lk*4 + i*128);
    f32x4 w2 = *(const f32x4*)(dec_w + 2*DMODEL + lk*4 + i*128);
    a0 += hv[0]*w0[0]+hv[1]*w0[1]+hv[2]*w0[2]+hv[3]*w0[3];
    a1 += hv[0]*w1[0]+hv[1]*w1[1]+hv[2]*w1[2]+hv[3]*w1[3];
    a2 += hv[0]*w2[0]+hv[1]*w2[1]+hv[2]*w2[2]+hv[3]*w2[3];
  }
  #pragma unroll
  for (int o=16;o>0;o>>=1){
    a0 += __shfl_down(a0,o,32); a1 += __shfl_down(a1,o,32); a2 += __shfl_down(a2,o,32);
  }
  if (lk==0){
    pred[row*3+0] = a0 + dec_b[0];
    pred[row*3+1] = a1 + dec_b[1];
    pred[row*3+2] = a2 + dec_b[2];
  }
}

extern "C" void kernel_launch(void* const* d_in, const int* in_sizes, int n_in,
                              void* d_out, int out_size, void* d_ws, size_t ws_size,
                              hipStream_t stream)
{
  const float* embed      = (const float*)d_in[0];
  const float* in_proj_w  = (const float*)d_in[1];
  const float* conv_w     = (const float*)d_in[2];
  const float* conv_b     = (const float*)d_in[3];
  const float* dt_bias    = (const float*)d_in[4];
  const float* A_log      = (const float*)d_in[5];
  const float* Dp         = (const float*)d_in[6];
  const float* norm_w     = (const float*)d_in[7];
  const float* out_proj_w = (const float*)d_in[8];
  const float* dec_w      = (const float*)d_in[9];
  const float* dec_b      = (const float*)d_in[10];

  char* ws = (char*)d_ws;
  size_t off = 0;
  auto alloc = [&](size_t bytes)->void*{ void* p = ws + off; off += (bytes + 255) & ~(size_t)255; return p; };

  u16* xbc = (u16*)alloc((size_t)MROWS*CONVD*2);
  u16* yb  = xbc;
  u16* R2  = (u16*)alloc((size_t)MROWS*DINNER*2);
  u16* Ebf = R2;
  u16* W1  = R2 + (size_t)MROWS*DMODEL;
  u16* xdtT  = R2;
  u16* ynorm = R2;
  float* dtraw = (float*)alloc((size_t)MROWS*NHEADS*4);
  float* dt_t  = (float*)alloc((size_t)NBATCH*NHEADS*SEQL*4);
  float* acs   = (float*)alloc((size_t)NBATCH*NHEADS*SEQL*4);
  u16* BTt   = (u16*)alloc((size_t)NBATCH*DSTATE*SEQL*2);
  u16* CTt   = (u16*)alloc((size_t)NBATCH*DSTATE*SEQL*2);
  u16* Cn    = (u16*)alloc((size_t)NBATCH*SEQL*DSTATE*2);
  u16* CBm   = (u16*)alloc((size_t)NBATCH*NCHUNK*CHUNKL*CHUNKL*2);
  u16* W2    = (u16*)alloc((size_t)DMODEL*DINNER*2);

  size_t off_base = off;
  u16* S = (u16*)alloc((size_t)NBATCH*NHEADS*NCHUNK*HEADD*DSTATE*2);
  bool use_par = (off <= ws_size);

  if (off_base > ws_size){
    k_sentinel<<<1,1,0,stream>>>((float*)d_out);
    return;
  }

  float* pred   = (float*)d_out;
  float* hidden = (float*)d_out + (size_t)MROWS*3;
  u16* zb = (u16*)hidden;

  hipFuncSetAttribute((const void*)k_gemm8<1>, hipFuncAttributeMaxDynamicSharedMemorySize, 131072);
  hipFuncSetAttribute((const void*)k_gemm8<0>, hipFuncAttributeMaxDynamicSharedMemorySize, 131072);

  k_cvt<<<16384,256,0,stream>>>(embed, Ebf, (long)MROWS*DMODEL, (long)MROWS*DMODEL);
  k_cvt<<<4608,256,0,stream>>>(in_proj_w, W1, (long)NPROJ*DMODEL, (long)NPROJP*DMODEL);
  k_cvt<<<2048,256,0,stream>>>(out_proj_w, W2, (long)DMODEL*DINNER, (long)DMODEL*DINNER);
  {
    dim3 g1(64, NPROJP/256);
    k_gemm8<1><<<g1,512,131072,stream>>>(Ebf, W1, DMODEL, 0, nullptr, zb, xbc, dtraw);
  }
  k_dtprep<<<4096,128,0,stream>>>(dtraw, dt_bias, A_log, dt_t, acs);
  k_conv<<<4608,256,0,stream>>>(xbc, conv_w, conv_b, dt_t, xdtT, BTt, CTt);
  k_cb<<<128,256,0,stream>>>(BTt, CTt, CBm, Cn);
  if (use_par){
    k_par<<<4096,256,0,stream>>>(BTt, xdtT, acs, S);
    k_scan<<<2048,256,0,stream>>>(S, acs);
    k_yoff<<<4096,256,0,stream>>>(Cn, xdtT, CBm, S, acs, dt_t, Dp, yb);
  } else {
    k_ssd<<<256,256,0,stream>>>(Cn, BTt, xdtT, CBm, acs, dt_t, Dp, yb);
  }
  k_gate<<<16384,256,0,stream>>>(yb, zb, norm_w, ynorm);
  {
    dim3 g2(64, DMODEL/256);
    k_gemm8<0><<<g2,512,131072,stream>>>(ynorm, W2, DINNER, DMODEL, hidden, nullptr, nullptr, nullptr);
  }
  k_pred<<<2048,256,0,stream>>>(hidden, dec_w, dec_b, pred);
}

// Round 7
// 532.060 us; speedup vs baseline: 1.4377x; 1.0034x over previous
//
#include <hip/hip_runtime.h>
#include <cstdint>

#define DEVI __device__ __forceinline__

typedef unsigned short u16;
typedef unsigned int u32;
typedef __attribute__((ext_vector_type(4))) float f32x4;
typedef __attribute__((ext_vector_type(8))) u16 u16x8;
typedef __attribute__((ext_vector_type(4))) u16 u16x4;
typedef __attribute__((ext_vector_type(8))) __bf16 bf16x8;

#define SEQL 2048
#define NBATCH 8
#define MROWS (NBATCH*SEQL)
#define DMODEL 1024
#define DINNER 2048
#define NHEADS 32
#define HEADD 64
#define DSTATE 128
#define CONVD 2304
#define NPROJ 4384
#define NPROJP 4608
#define CHUNKL 128
#define NCHUNK 16
#define PADC 136

DEVI float bf2f(u16 v){ u32 u = ((u32)v)<<16; return __builtin_bit_cast(float,u); }
DEVI u16 f2bf(float f){ u32 u = __builtin_bit_cast(u32,f); u32 r = (u + 0x7fffu + ((u>>16)&1u))>>16; return (u16)r; }

DEVI void gld_lds16(const void* g, void* lds){
  __builtin_amdgcn_global_load_lds(
    (const __attribute__((address_space(1))) void*)(uintptr_t)g,
    (__attribute__((address_space(3))) void*)(u32)(uintptr_t)lds, 16, 0, 0);
}

DEVI f32x4 MFMA(u16x8 a, u16x8 b, f32x4 c){
  return __builtin_amdgcn_mfma_f32_16x16x32_bf16(
      __builtin_bit_cast(bf16x8,a), __builtin_bit_cast(bf16x8,b), c, 0,0,0);
}

__global__ void k_sentinel(float* o){ o[0] = 12345.0f; }

// ---------------- merged f32 -> bf16 conversions (3 segments) -------------
// blocks [0,16384): embed ; [16384,20992): in_proj (zero-padded to NPROJP) ;
// [20992,23040): out_proj. 1024 elems per block.
__global__ __launch_bounds__(256) void k_cvt3(const float* __restrict__ e, u16* __restrict__ eb,
    const float* __restrict__ w1, u16* __restrict__ w1b,
    const float* __restrict__ w2, u16* __restrict__ w2b)
{
  int bid = blockIdx.x;
  const float* src; u16* dst; long n; long base;
  if (bid < 16384){ src = e;  dst = eb;  n = (long)MROWS*DMODEL;  base = (long)bid*1024; }
  else if (bid < 20992){ src = w1; dst = w1b; n = (long)NPROJ*DMODEL; base = (long)(bid-16384)*1024; }
  else { src = w2; dst = w2b; n = (long)DMODEL*DINNER; base = (long)(bid-20992)*1024; }
  long idx = base + (long)threadIdx.x*4;
  u16x4 o;
  if (idx < n){
    f32x4 v = *(const f32x4*)(src+idx);
    o[0]=f2bf(v[0]); o[1]=f2bf(v[1]); o[2]=f2bf(v[2]); o[3]=f2bf(v[3]);
  } else { o[0]=0; o[1]=0; o[2]=0; o[3]=0; }
  *(u16x4*)(dst+idx) = o;
}

// ================= 256^2 8-phase GEMM (T1+T2+T3+T4+T5) ====================
#define STG(mat, h, ts) do { \
    const int d_ = (ts) & 1; \
    const size_t ko_ = (size_t)(((ts) < NT) ? (ts) : (NT-1)) * 64; \
    gld_lds16(sbase[mat][h][0] + ko_, (char*)lds + (mat)*65536 + (d_*2+(h))*16384 + tid*16); \
    gld_lds16(sbase[mat][h][1] + ko_, (char*)lds + (mat)*65536 + (d_*2+(h))*16384 + 8192 + tid*16); \
  } while(0)

#define LDA8(AF, d_, qm) { \
    _Pragma("unroll") for (int mf=0; mf<4; mf++) \
    _Pragma("unroll") for (int ks=0; ks<2; ks++) \
      AF[mf][ks] = *(const u16x8*)(lds + (size_t)((d_)*2+wm)*8192 + ((qm)*64+mf*16+lidx)*64 + ((ks*4+krow)^(lidx&7))*8); }

#define LDB4(BF, d_, qn) { \
    _Pragma("unroll") for (int nf=0; nf<2; nf++) \
    _Pragma("unroll") for (int ks=0; ks<2; ks++) \
      BF[nf][ks] = *(const u16x8*)(lds + 32768 + (size_t)((d_)*2+(wn>>1))*8192 + ((wn&1)*64+(qn)*32+nf*16+lidx)*64 + ((ks*4+krow)^(lidx&7))*8); }

#define MMAQ(QM, QN, AF, BF) { \
    _Pragma("unroll") for (int mf=0; mf<4; mf++) \
    _Pragma("unroll") for (int nf=0; nf<2; nf++) \
    _Pragma("unroll") for (int ks=0; ks<2; ks++) \
      acc[(QM)*4+mf][(QN)*2+nf] = MFMA(AF[mf][ks], BF[nf][ks], acc[(QM)*4+mf][(QN)*2+nf]); }

#define LHINT asm volatile("s_waitcnt lgkmcnt(8)" ::: "memory");

#define BAR1 __builtin_amdgcn_sched_barrier(0); __builtin_amdgcn_s_barrier(); \
    asm volatile("s_waitcnt lgkmcnt(0)" ::: "memory"); __builtin_amdgcn_sched_barrier(0); \
    __builtin_amdgcn_s_setprio(1);
#define BAR2 __builtin_amdgcn_s_setprio(0); __builtin_amdgcn_sched_barrier(0); \
    __builtin_amdgcn_s_barrier(); __builtin_amdgcn_sched_barrier(0);

template<int MODE>
__global__ __launch_bounds__(512, 2) void k_gemm8(const u16* __restrict__ A, const u16* __restrict__ Bt,
    const int K, const int Ndim, float* __restrict__ outF,
    u16* __restrict__ z_out, u16* __restrict__ xbc_out, float* __restrict__ dtraw_out)
{
  extern __shared__ u16 lds[];
  const int NT = K >> 6;
  const int tid = threadIdx.x;
  const int lane = tid & 63, wid = tid >> 6;
  const int wm = wid >> 2, wn = wid & 3;
  const int lidx = lane & 15, krow = lane >> 4;
  // bijective chunked XCD transform + GROUP_M=8 grouping (L2-resident A-band)
  const int nmt = gridDim.x, nnt = gridDim.y;
  const int nwg = nmt * nnt;
  const int orig = blockIdx.y * nmt + blockIdx.x;
  const int qq = nwg >> 3, rr = nwg & 7;
  const int xcd = orig & 7, li = orig >> 3;
  const int pid = (xcd < rr ? xcd*(qq+1) : rr*(qq+1) + (xcd-rr)*qq) + li;
  const int GM = 8;
  const int npg = GM * nnt;
  const int gid = pid / npg;
  const int rem = pid % npg;
  const int m0 = (gid*GM + (rem & (GM-1))) * 256;
  const int n0 = (rem / GM) * 256;

  f32x4 acc[8][4];
  const f32x4 zf = {0.f,0.f,0.f,0.f};
  #pragma unroll
  for (int i=0;i<8;i++)
    #pragma unroll
    for (int j=0;j<4;j++) acc[i][j] = zf;

  const int r0 = tid >> 3;
  const int gsw = ((tid & 7) ^ (r0 & 7)) * 8;
  const u16* sbase[2][2][2];
  #pragma unroll
  for (int h=0; h<2; h++)
    #pragma unroll
    for (int L=0; L<2; L++){
      sbase[0][h][L] = A  + (size_t)(m0 + h*128 + L*64 + r0)*K + gsw;
      sbase[1][h][L] = Bt + (size_t)(n0 + h*128 + L*64 + r0)*K + gsw;
    }

  STG(0,0,0); STG(0,1,0); STG(1,0,0); STG(1,1,0);
  asm volatile("s_waitcnt vmcnt(4)" ::: "memory");
  STG(0,0,1); STG(0,1,1); STG(1,0,1);
  asm volatile("s_waitcnt vmcnt(6)" ::: "memory");
  __builtin_amdgcn_sched_barrier(0);
  __builtin_amdgcn_s_barrier();
  __builtin_amdgcn_sched_barrier(0);

  u16x8 af[4][2], bf0[2][2], bf1[2][2];
  for (int t = 0; t < NT; t += 2){
    LDA8(af, 0, 0); LDB4(bf0, 0, 0); STG(1,1,t+1); LHINT;
    BAR1; MMAQ(0,0,af,bf0); BAR2;
    LDB4(bf1, 0, 1);
    BAR1; MMAQ(0,1,af,bf1); BAR2;
    LDA8(af, 0, 1); STG(1,0,t+2);
    BAR1; MMAQ(1,1,af,bf1); BAR2;
    STG(0,0,t+2); STG(0,1,t+2);
    asm volatile("s_waitcnt vmcnt(6)" ::: "memory");
    BAR1; MMAQ(1,0,af,bf0); BAR2;
    LDA8(af, 1, 0); LDB4(bf0, 1, 0); STG(1,1,t+2); LHINT;
    BAR1; MMAQ(0,0,af,bf0); BAR2;
    LDB4(bf1, 1, 1);
    BAR1; MMAQ(0,1,af,bf1); BAR2;
    LDA8(af, 1, 1); STG(1,0,t+3);
    BAR1; MMAQ(1,1,af,bf1); BAR2;
    STG(0,0,t+3); STG(0,1,t+3);
    asm volatile("s_waitcnt vmcnt(6)" ::: "memory");
    BAR1; MMAQ(1,0,af,bf0); BAR2;
  }
  asm volatile("s_waitcnt vmcnt(0)" ::: "memory");

  #pragma unroll
  for (int im=0; im<8; im++)
    #pragma unroll
    for (int in=0; in<4; in++)
      #pragma unroll
      for (int r=0; r<4; r++){
        int gm = m0 + wm*128 + im*16 + krow*4 + r;
        int gn = n0 + wn*64 + in*16 + lidx;
        float v = acc[im][in][r];
        if (MODE==0){
          outF[(long)gm*Ndim + gn] = v;
        } else {
          if (gn < DINNER) z_out[(long)gm*DINNER + gn] = f2bf(v);
          else if (gn < DINNER+CONVD) xbc_out[(long)gm*CONVD + (gn-DINNER)] = f2bf(v);
          else if (gn < NPROJ) dtraw_out[(long)gm*NHEADS + (gn-DINNER-CONVD)] = v;
        }
      }
}

// ---------------- dt prep: softplus + per-chunk inclusive cumsum ----------
__global__ __launch_bounds__(128) void k_dtprep(const float* __restrict__ dtraw, const float* __restrict__ dt_bias,
    const float* __restrict__ A_log, float* __restrict__ dt_t, float* __restrict__ acs_t)
{
  int b = blockIdx.x >> 9;
  int h = (blockIdx.x >> 4) & 31;
  int c = blockIdx.x & 15;
  int l = threadIdx.x;
  int gl = c*128 + l;
  float raw = dtraw[((long)(b*SEQL + gl))*NHEADS + h] + dt_bias[h];
  float dt = (raw > 20.f) ? raw : log1pf(expf(raw));
  float A = -expf(A_log[h]);
  float ac = dt*A;
  __shared__ float ss[128];
  ss[l] = ac; __syncthreads();
  for (int o=1;o<128;o<<=1){
    float v = (l>=o)? ss[l-o] : 0.f;
    __syncthreads();
    ss[l] += v;
    __syncthreads();
  }
  float acs = ss[l];
  dt_t[((long)(b*NHEADS+h))*SEQL + gl] = dt;
  acs_t[((long)(b*NHEADS+h))*SEQL + gl] = acs;
}

// ---------------- causal depthwise conv + silu; split outputs -------------
__global__ __launch_bounds__(256) void k_conv(const u16* __restrict__ xbc, const float* __restrict__ conv_w,
    const float* __restrict__ conv_b, const float* __restrict__ dt_t,
    u16* __restrict__ xdtT, u16* __restrict__ BTt, u16* __restrict__ CTt)
{
  __shared__ u16 sm[131*64];
  int idx = blockIdx.x;
  int b = idx / 576; int rem = idx % 576; int cbk = rem >> 4; int lb = rem & 15;
  int ch0 = cbk*64, l0 = lb*128;
  for (int g = threadIdx.x; g < 131*8; g += 256){
    int r = g >> 3, cg = g & 7;
    int gl = l0 - 3 + r;
    u16x8 v;
    if (gl >= 0) v = *(const u16x8*)(xbc + ((long)(b*SEQL+gl))*CONVD + ch0 + cg*8);
    else { v[0]=0;v[1]=0;v[2]=0;v[3]=0;v[4]=0;v[5]=0;v[6]=0;v[7]=0; }
    *(u16x8*)(&sm[r*64 + cg*8]) = v;
  }
  __syncthreads();
  int ci = threadIdx.x & 63, g4 = threadIdx.x >> 6;
  int chg = ch0 + ci;
  f32x4 wv = *(const f32x4*)(conv_w + chg*4);
  float bia = conv_b[chg];
  bool isX = chg < DINNER;
  int h = chg >> 6; if (h > 31) h = 31;
  int p = chg & 63;
  const float* dtrow = dt_t + ((long)(b*NHEADS+h))*SEQL + l0 + g4*32;
  u16x8 ov[4];
  #pragma unroll
  for (int i=0;i<32;i++){
    int lr = g4*32 + i;
    float a = bia + wv[0]*bf2f(sm[(lr+0)*64+ci]) + wv[1]*bf2f(sm[(lr+1)*64+ci])
                  + wv[2]*bf2f(sm[(lr+2)*64+ci]) + wv[3]*bf2f(sm[(lr+3)*64+ci]);
    float s = a / (1.f + __expf(-a));
    if (isX) s *= dtrow[i];
    ov[i>>3][i&7] = f2bf(s);
  }
  u16* dst;
  if (isX)                      dst = xdtT + (((long)(b*NHEADS+h))*HEADD + p)*SEQL + l0 + g4*32;
  else if (chg < DINNER+DSTATE) dst = BTt + ((long)(b*DSTATE + (chg-DINNER)))*SEQL + l0 + g4*32;
  else                          dst = CTt + ((long)(b*DSTATE + (chg-DINNER-DSTATE)))*SEQL + l0 + g4*32;
  #pragma unroll
  for (int q=0;q<4;q++) *(u16x8*)(dst + q*8) = ov[q];
}

// ============ merged k_cb + k_par ============
// blocks [0,128): CB = C*B^T per (b,c) + Cn transpose-out
// blocks [128, 128+4096): per-(b,c,h) chunk states via MFMA
__global__ __launch_bounds__(256) void k_cbpar(const u16* __restrict__ BTt, const u16* __restrict__ CTt,
    const u16* __restrict__ xdtT, const float* __restrict__ acs_t,
    u16* __restrict__ CBm, u16* __restrict__ Cn, u16* __restrict__ states)
{
  __shared__ __align__(16) char smem[69632];  // cb: Cl(34816)+Bl(34816); par: Bs+Xs+floats
  const int tid = threadIdx.x;
  const int lane = tid & 63, wid = tid >> 6;
  const int lidx = lane & 15, krow = lane >> 4;
  const f32x4 zf = {0.f,0.f,0.f,0.f};
  if (blockIdx.x < 128){
    u16* Cl = (u16*)smem;
    u16* Bl = (u16*)(smem + 34816);
    int b = blockIdx.x >> 4, c = blockIdx.x & 15;
    for (int g = tid; g < 2048; g += 256){
      int n = g >> 4, lg = g & 15;
      u16x8 vc = *(const u16x8*)(CTt + ((long)(b*DSTATE+n))*SEQL + c*CHUNKL + lg*8);
      u16x8 vb = *(const u16x8*)(BTt + ((long)(b*DSTATE+n))*SEQL + c*CHUNKL + lg*8);
      #pragma unroll
      for (int j=0;j<8;j++){
        Cl[(lg*8+j)*136 + n] = vc[j];
        Bl[(lg*8+j)*136 + n] = vb[j];
      }
    }
    __syncthreads();
    const int wr = wid & 1, wc2 = wid >> 1;
    f32x4 acc[4][4];
    #pragma unroll
    for (int i=0;i<4;i++)
      #pragma unroll
      for (int j=0;j<4;j++) acc[i][j] = zf;
    #pragma unroll
    for (int k0=0;k0<128;k0+=32){
      u16x8 af[4], bfv[4];
      #pragma unroll
      for (int i=0;i<4;i++){
        af[i]  = *(const u16x8*)(&Cl[(wr*64+i*16+lidx)*136 + k0 + krow*8]);
        bfv[i] = *(const u16x8*)(&Bl[(wc2*64+i*16+lidx)*136 + k0 + krow*8]);
      }
      #pragma unroll
      for (int i=0;i<4;i++)
        #pragma unroll
        for (int j=0;j<4;j++)
          acc[i][j] = MFMA(af[i], bfv[j], acc[i][j]);
    }
    long base = ((long)(b*16+c))*128*128;
    #pragma unroll
    for (int i=0;i<4;i++)
      #pragma unroll
      for (int j=0;j<4;j++)
        #pragma unroll
        for (int r=0;r<4;r++){
          int l = wr*64+i*16+krow*4+r;
          int s = wc2*64+j*16+lidx;
          CBm[base + (long)l*128 + s] = f2bf(acc[i][j][r]);
        }
    for (int g = tid; g < 2048; g += 256){
      int l = g >> 4, ng = g & 15;
      u16x8 o;
      #pragma unroll
      for (int j=0;j<8;j++) o[j] = Cl[l*136 + ng*8 + j];
      *(u16x8*)(Cn + ((long)(b*SEQL + c*CHUNKL + l))*DSTATE + ng*8) = o;
    }
  } else {
    u16* Bs = (u16*)smem;                       // 128*PADC
    u16* Xs = (u16*)(smem + 34816);             // 64*PADC
    float* acs_s = (float*)(smem + 52224);      // 128
    float* dec_s = (float*)(smem + 52736);      // 128
    const int idx = blockIdx.x - 128;
    const int c = idx & 15, bh = idx >> 4, b = bh >> 5;
    const int wps = wid & 1, wns = wid >> 1;
    const float* acs_g = acs_t + (long)bh*SEQL + c*128;
    const u16* X_g = xdtT + (long)bh*HEADD*SEQL + c*128;
    const u16* B_g = BTt + (long)b*DSTATE*SEQL + c*128;
    if (tid < 128) acs_s[tid] = acs_g[tid];
    __syncthreads();
    if (tid < 128) dec_s[tid] = __expf(acs_s[127] - acs_s[tid]);
    __syncthreads();
    for (int g = tid; g < 2048; g += 256){
      int n = g >> 4, lg = g & 15;
      u16x8 v = *(const u16x8*)(B_g + (long)n*SEQL + lg*8);
      u16x8 o;
      #pragma unroll
      for (int j=0;j<8;j++) o[j] = f2bf(bf2f(v[j])*dec_s[lg*8+j]);
      *(u16x8*)(&Bs[n*PADC + lg*8]) = o;
    }
    for (int g = tid; g < 1024; g += 256){
      int p = g >> 4, lg = g & 15;
      *(u16x8*)(&Xs[p*PADC + lg*8]) = *(const u16x8*)(X_g + (long)p*SEQL + lg*8);
    }
    __syncthreads();
    f32x4 accS[2][4];
    #pragma unroll
    for (int i=0;i<2;i++){ accS[i][0]=zf; accS[i][1]=zf; accS[i][2]=zf; accS[i][3]=zf; }
    #pragma unroll
    for (int k0=0;k0<128;k0+=32){
      u16x8 as2[2], bs2[4];
      #pragma unroll
      for (int i=0;i<2;i++) as2[i] = *(const u16x8*)(&Xs[(wps*32+i*16+lidx)*PADC + k0 + krow*8]);
      #pragma unroll
      for (int j=0;j<4;j++) bs2[j] = *(const u16x8*)(&Bs[(wns*64+j*16+lidx)*PADC + k0 + krow*8]);
      #pragma unroll
      for (int i=0;i<2;i++)
        #pragma unroll
        for (int j=0;j<4;j++)
          accS[i][j] = MFMA(as2[i], bs2[j], accS[i][j]);
    }
    u16* Sg = states + (long)idx*8192;
    #pragma unroll
    for (int i=0;i<2;i++)
      #pragma unroll
      for (int j=0;j<4;j++)
        #pragma unroll
        for (int r=0;r<4;r++){
          int p = wps*32 + i*16 + krow*4 + r;
          int n = wns*64 + j*16 + lidx;
          Sg[p*128 + n] = f2bf(accS[i][j][r]);
        }
  }
}

__global__ __launch_bounds__(256) void k_scan(u16* __restrict__ states, const float* __restrict__ acs_t)
{
  long gid = (long)blockIdx.x*256 + threadIdx.x;
  int bh = (int)(gid >> 11);
  int q = (int)(gid & 2047);
  __shared__ float cds[16];
  if (threadIdx.x < 16) cds[threadIdx.x] = __expf(acs_t[(long)bh*SEQL + threadIdx.x*128 + 127]);
  __syncthreads();
  u16* p = states + (long)bh*NCHUNK*8192 + q*4;
  u16x4 sv[16];
  #pragma unroll
  for (int c=0;c<16;c++) sv[c] = *(const u16x4*)(p + c*8192);
  float c0=0.f,c1=0.f,c2=0.f,c3=0.f;
  #pragma unroll
  for (int c=0;c<16;c++){
    u16x4 o; o[0]=f2bf(c0); o[1]=f2bf(c1); o[2]=f2bf(c2); o[3]=f2bf(c3);
    *(u16x4*)(p + c*8192) = o;
    float cd = cds[c];
    c0 = c0*cd + bf2f(sv[c][0]);
    c1 = c1*cd + bf2f(sv[c][1]);
    c2 = c2*cd + bf2f(sv[c][2]);
    c3 = c3*cd + bf2f(sv[c][3]);
  }
}

__global__ __launch_bounds__(256) void k_yoff(
    const u16* __restrict__ Cng, const u16* __restrict__ xdtT, const u16* __restrict__ CBm,
    const u16* __restrict__ SI, const float* __restrict__ acs_t, const float* __restrict__ dt_t,
    const float* __restrict__ Dparam, u16* __restrict__ y)
{
  __shared__ u16 Ts[128*PADC];
  __shared__ u16 Us[64*PADC];
  __shared__ float acs_s[128], dtr_s[128], eacs_s[128];
  const int idx = blockIdx.x;
  const int c = idx & 15, bh = idx >> 4, b = bh >> 5, h = bh & 31;
  const int tid = threadIdx.x, lane = tid & 63, wid = tid >> 6;
  const int lidx = lane & 15, krow = lane >> 4;
  const int wl = wid & 1, wp = wid >> 1;
  const float Dh = Dparam[h];
  const float* acs_g = acs_t + (long)bh*SEQL + c*128;
  const float* dt_g  = dt_t  + (long)bh*SEQL + c*128;
  const u16* X_g = xdtT + (long)bh*HEADD*SEQL + c*128;
  const u16* C_g = Cng + ((long)(b*SEQL + c*128))*DSTATE;
  const u16* CB_g = CBm + ((long)(b*NCHUNK + c))*CHUNKL*CHUNKL;
  const u16* SI_g = SI + (long)idx*8192;
  if (tid < 128){ acs_s[tid] = acs_g[tid]; dtr_s[tid] = dt_g[tid]; }
  __syncthreads();
  if (tid < 128) eacs_s[tid] = __expf(acs_s[tid]);
  __syncthreads();
  {
    int l = tid >> 1, s0 = (tid & 1)*64;
    float al = acs_s[l];
    #pragma unroll
    for (int qq=0;qq<8;qq++){
      u16x8 v = *(const u16x8*)(CB_g + (long)l*CHUNKL + s0 + qq*8);
      u16x8 o;
      #pragma unroll
      for (int j=0;j<8;j++){
        int s = s0 + qq*8 + j;
        float pv = (s <= l) ? bf2f(v[j]) * __expf(al - acs_s[s]) : 0.f;
        o[j] = f2bf(pv);
      }
      *(u16x8*)(&Ts[l*PADC + s0 + qq*8]) = o;
    }
  }
  for (int g = tid; g < 1024; g += 256){
    int p = g >> 4, lg = g & 15;
    *(u16x8*)(&Us[p*PADC + lg*8]) = *(const u16x8*)(X_g + (long)p*SEQL + lg*8);
  }
  __syncthreads();
  const f32x4 zf = {0.f,0.f,0.f,0.f};
  f32x4 accY[4][2];
  #pragma unroll
  for (int i=0;i<4;i++){ accY[i][0]=zf; accY[i][1]=zf; }
  #pragma unroll
  for (int k0=0;k0<128;k0+=32){
    u16x8 af[4], bfv[2];
    #pragma unroll
    for (int i=0;i<4;i++) af[i] = *(const u16x8*)(&Ts[(wl*64+i*16+lidx)*PADC + k0 + krow*8]);
    #pragma unroll
    for (int j=0;j<2;j++) bfv[j] = *(const u16x8*)(&Us[(wp*32+j*16+lidx)*PADC + k0 + krow*8]);
    #pragma unroll
    for (int i=0;i<4;i++)
      #pragma unroll
      for (int j=0;j<2;j++)
        accY[i][j] = MFMA(af[i], bfv[j], accY[i][j]);
  }
  #pragma unroll
  for (int i=0;i<4;i++)
    #pragma unroll
    for (int j=0;j<2;j++)
      #pragma unroll
      for (int r=0;r<4;r++){
        int l = wl*64 + i*16 + krow*4 + r;
        int p = wp*32 + j*16 + lidx;
        accY[i][j][r] += Dh * bf2f(Us[p*PADC + l]) / dtr_s[l];
      }
  __syncthreads();
  for (int g = tid; g < 2048; g += 256){
    int l = g >> 4, cb = g & 15;
    u16x8 v = *(const u16x8*)(C_g + (long)l*DSTATE + cb*8);
    float e = eacs_s[l];
    u16x8 o;
    #pragma unroll
    for (int j=0;j<8;j++) o[j] = f2bf(bf2f(v[j])*e);
    *(u16x8*)(&Ts[l*PADC + cb*8]) = o;
  }
  for (int g = tid; g < 1024; g += 256){
    int p = g >> 4, lg = g & 15;
    *(u16x8*)(&Us[p*PADC + lg*8]) = *(const u16x8*)(SI_g + p*128 + lg*8);
  }
  __syncthreads();
  #pragma unroll
  for (int k0=0;k0<128;k0+=32){
    u16x8 af[4], bfv[2];
    #pragma unroll
    for (int i=0;i<4;i++) af[i] = *(const u16x8*)(&Ts[(wl*64+i*16+lidx)*PADC + k0 + krow*8]);
    #pragma unroll
    for (int j=0;j<2;j++) bfv[j] = *(const u16x8*)(&Us[(wp*32+j*16+lidx)*PADC + k0 + krow*8]);
    #pragma unroll
    for (int i=0;i<4;i++)
      #pragma unroll
      for (int j=0;j<2;j++)
        accY[i][j] = MFMA(af[i], bfv[j], accY[i][j]);
  }
  #pragma unroll
  for (int i=0;i<4;i++)
    #pragma unroll
    for (int j=0;j<2;j++)
      #pragma unroll
      for (int r=0;r<4;r++){
        int l = wl*64 + i*16 + krow*4 + r;
        int p = wp*32 + j*16 + lidx;
        y[((long)(b*SEQL + c*128 + l))*DINNER + h*HEADD + p] = f2bf(accY[i][j][r]);
      }
}

// ---------------- fused SSD (fallback if workspace too small) -------------
__global__ __launch_bounds__(256) void k_ssd(
    const u16* __restrict__ Cng, const u16* __restrict__ BTt, const u16* __restrict__ xdtT,
    const u16* __restrict__ CBm, const float* __restrict__ acs_t, const float* __restrict__ dt_t,
    const float* __restrict__ Dparam, u16* __restrict__ y)
{
  __shared__ u16 Cs[128*PADC];
  __shared__ u16 Bs[128*PADC];
  __shared__ u16 Ps[128*PADC];
  __shared__ u16 Xs[64*PADC];
  __shared__ float carry[64*132];
  __shared__ float acs_s[128], eacs_s[128], dec_s[128], dtr_s[128];
  const int bh = blockIdx.x;
  const int b = bh >> 5, h = bh & 31;
  const int tid = threadIdx.x, lane = tid & 63, wid = tid >> 6;
  const int lidx = lane & 15, krow = lane >> 4;
  const int wl = wid & 1, wp = wid >> 1;
  const int wps = wid & 1, wns = wid >> 1;
  for (int i = tid; i < 64*132; i += 256) carry[i] = 0.f;
  const float Dh = Dparam[h];
  const float* acs_g = acs_t + (long)bh*SEQL;
  const float* dt_g = dt_t + (long)bh*SEQL;
  const u16* X_g = xdtT + (long)bh*HEADD*SEQL;
  const u16* B_g = BTt + (long)b*DSTATE*SEQL;
  const u16* C_g = Cng + (long)b*SEQL*DSTATE;
  const u16* CB_g = CBm + (long)b*NCHUNK*CHUNKL*CHUNKL;
  const f32x4 zf = {0.f,0.f,0.f,0.f};
  for (int c=0;c<NCHUNK;c++){
    __syncthreads();
    if (tid < 128){ acs_s[tid] = acs_g[c*128+tid]; dtr_s[tid] = dt_g[c*128+tid]; }
    __syncthreads();
    if (tid < 128){ float a = acs_s[tid]; eacs_s[tid] = __expf(a); dec_s[tid] = __expf(acs_s[127]-a); }
    __syncthreads();
    for (int g = tid; g < 2048; g += 256){
      int l = g >> 4, cb = g & 15;
      u16x8 v = *(const u16x8*)(C_g + ((long)(c*128+l))*DSTATE + cb*8);
      float e = eacs_s[l];
      u16x8 o;
      #pragma unroll
      for (int j=0;j<8;j++) o[j] = f2bf(bf2f(v[j])*e);
      *(u16x8*)(&Cs[l*PADC + cb*8]) = o;
    }
    for (int g = tid; g < 2048; g += 256){
      int n = g >> 4, lg = g & 15;
      u16x8 v = *(const u16x8*)(B_g + (long)n*SEQL + c*128 + lg*8);
      u16x8 o;
      #pragma unroll
      for (int j=0;j<8;j++) o[j] = f2bf(bf2f(v[j])*dec_s[lg*8+j]);
      *(u16x8*)(&Bs[n*PADC + lg*8]) = o;
    }
    for (int g = tid; g < 1024; g += 256){
      int p = g >> 4, lg = g & 15;
      *(u16x8*)(&Xs[p*PADC + lg*8]) = *(const u16x8*)(X_g + (long)p*SEQL + c*128 + lg*8);
    }
    {
      int l = tid >> 1, s0 = (tid & 1)*64;
      float al = acs_s[l];
      #pragma unroll
      for (int q=0;q<8;q++){
        u16x8 v = *(const u16x8*)(CB_g + ((long)(c*128+l))*CHUNKL + s0 + q*8);
        u16x8 o;
        #pragma unroll
        for (int j=0;j<8;j++){
          int s = s0 + q*8 + j;
          float pv = (s <= l) ? bf2f(v[j]) * __expf(al - acs_s[s]) : 0.f;
          o[j] = f2bf(pv);
        }
        *(u16x8*)(&Ps[l*PADC + s0 + q*8]) = o;
      }
    }
    __syncthreads();
    f32x4 accY[4][2];
    f32x4 accS[2][4];
    #pragma unroll
    for (int i=0;i<4;i++){ accY[i][0]=zf; accY[i][1]=zf; }
    #pragma unroll
    for (int i=0;i<2;i++){ accS[i][0]=zf; accS[i][1]=zf; accS[i][2]=zf; accS[i][3]=zf; }
    #pragma unroll
    for (int k0=0;k0<128;k0+=32){
      u16x8 af[4], bfv[2];
      #pragma unroll
      for (int i=0;i<4;i++) af[i] = *(const u16x8*)(&Cs[(wl*64+i*16+lidx)*PADC + k0 + krow*8]);
      #pragma unroll
      for (int j=0;j<2;j++){
        const float* cp = &carry[(wp*32+j*16+lidx)*132 + k0 + krow*8];
        f32x4 c0 = *(const f32x4*)cp;
        f32x4 c1 = *(const f32x4*)(cp+4);
        u16x8 o;
        o[0]=f2bf(c0[0]); o[1]=f2bf(c0[1]); o[2]=f2bf(c0[2]); o[3]=f2bf(c0[3]);
        o[4]=f2bf(c1[0]); o[5]=f2bf(c1[1]); o[6]=f2bf(c1[2]); o[7]=f2bf(c1[3]);
        bfv[j] = o;
      }
      #pragma unroll
      for (int i=0;i<4;i++)
        #pragma unroll
        for (int j=0;j<2;j++)
          accY[i][j] = MFMA(af[i], bfv[j], accY[i][j]);
    }
    #pragma unroll
    for (int k0=0;k0<128;k0+=32){
      u16x8 af[4], bfv[2];
      #pragma unroll
      for (int i=0;i<4;i++) af[i] = *(const u16x8*)(&Ps[(wl*64+i*16+lidx)*PADC + k0 + krow*8]);
      #pragma unroll
      for (int j=0;j<2;j++) bfv[j] = *(const u16x8*)(&Xs[(wp*32+j*16+lidx)*PADC + k0 + krow*8]);
      #pragma unroll
      for (int i=0;i<4;i++)
        #pragma unroll
        for (int j=0;j<2;j++)
          accY[i][j] = MFMA(af[i], bfv[j], accY[i][j]);
    }
    #pragma unroll
    for (int k0=0;k0<128;k0+=32){
      u16x8 as2[2], bs2[4];
      #pragma unroll
      for (int i=0;i<2;i++) as2[i] = *(const u16x8*)(&Xs[(wps*32+i*16+lidx)*PADC + k0 + krow*8]);
      #pragma unroll
      for (int j=0;j<4;j++) bs2[j] = *(const u16x8*)(&Bs[(wns*64+j*16+lidx)*PADC + k0 + krow*8]);
      #pragma unroll
      for (int i=0;i<2;i++)
        #pragma unroll
        for (int j=0;j<4;j++)
          accS[i][j] = MFMA(as2[i], bs2[j], accS[i][j]);
    }
    __syncthreads();
    float cd = __expf(acs_s[127]);
    #pragma unroll
    for (int i=0;i<2;i++)
      #pragma unroll
      for (int j=0;j<4;j++)
        #pragma unroll
        for (int r=0;r<4;r++){
          int p = wps*32 + i*16 + krow*4 + r;
          int n = wns*64 + j*16 + lidx;
          carry[p*132+n] = carry[p*132+n]*cd + accS[i][j][r];
        }
    #pragma unroll
    for (int i=0;i<4;i++)
      #pragma unroll
      for (int j=0;j<2;j++)
        #pragma unroll
        for (int r=0;r<4;r++){
          int l = wl*64 + i*16 + krow*4 + r;
          int p = wp*32 + j*16 + lidx;
          float xv = bf2f(Xs[p*PADC + l]) / dtr_s[l];
          float val = accY[i][j][r] + Dh*xv;
          y[((long)(b*SEQL + c*128 + l))*DINNER + h*HEADD + p] = f2bf(val);
        }
  }
}

// ---------------- gating (silu(z)) + RMSNorm -> bf16 ----------------------
__global__ __launch_bounds__(256) void k_gate(const u16* __restrict__ y, const u16* __restrict__ z,
    const float* __restrict__ norm_w, u16* __restrict__ out)
{
  long row = blockIdx.x;
  const u16* yr = y + row*DINNER;
  const u16* zr = z + row*DINNER;
  int t = threadIdx.x;
  u16x8 yy = *(const u16x8*)(yr + t*8);
  u16x8 zz = *(const u16x8*)(zr + t*8);
  float g[8]; float ss = 0.f;
  #pragma unroll
  for (int j=0;j<8;j++){
    float zfv = bf2f(zz[j]);
    float sg = zfv / (1.f + __expf(-zfv));
    float gv = bf2f(yy[j]) * sg;
    g[j] = gv; ss += gv*gv;
  }
  #pragma unroll
  for (int o=32;o>0;o>>=1) ss += __shfl_down(ss, o);
  __shared__ float part[4];
  int lane = t & 63, wid = t>>6;
  if (lane==0) part[wid] = ss;
  __syncthreads();
  float tot = part[0]+part[1]+part[2]+part[3];
  float inv = rsqrtf(tot*(1.f/DINNER) + 1e-5f);
  u16x8 o;
  #pragma unroll
  for (int j=0;j<8;j++) o[j] = f2bf(g[j]*inv*norm_w[t*8+j]);
  *(u16x8*)(out + row*DINNER + t*8) = o;
}

// ---------------- pred = hidden @ dec_w^T + dec_b -------------------------
__global__ __launch_bounds__(256) void k_pred(const float* __restrict__ hid, const float* __restrict__ dec_w,
    const float* __restrict__ dec_b, float* __restrict__ pred)
{
  int t = threadIdx.x;
  long row = (long)blockIdx.x*8 + (t>>5);
  int lk = t & 31;
  const float* hr = hid + row*DMODEL;
  float a0=0.f,a1=0.f,a2=0.f;
  #pragma unroll
  for (int i=0;i<8;i++){
    f32x4 hv = *(const f32x4*)(hr + lk*4 + i*128);
    f32x4 w0 = *(const f32x4*)(dec_w + 0*DMODEL + lk*4 + i*128);
    f32x4 w1 = *(const f32x4*)(dec_w + 1*DMODEL + lk*4 + i*128);
    f32x4 w2 = *(const f32x4*)(dec_w + 2*DMODEL + lk*4 + i*128);
    a0 += hv[0]*w0[0]+hv[1]*w0[1]+hv[2]*w0[2]+hv[3]*w0[3];
    a1 += hv[0]*w1[0]+hv[1]*w1[1]+hv[2]*w1[2]+hv[3]*w1[3];
    a2 += hv[0]*w2[0]+hv[1]*w2[1]+hv[2]*w2[2]+hv[3]*w2[3];
  }
  #pragma unroll
  for (int o=16;o>0;o>>=1){
    a0 += __shfl_down(a0,o,32); a1 += __shfl_down(a1,o,32); a2 += __shfl_down(a2,o,32);
  }
  if (lk==0){
    pred[row*3+0] = a0 + dec_b[0];
    pred[row*3+1] = a1 + dec_b[1];
    pred[row*3+2] = a2 + dec_b[2];
  }
}

extern "C" void kernel_launch(void* const* d_in, const int* in_sizes, int n_in,
                              void* d_out, int out_size, void* d_ws, size_t ws_size,
                              hipStream_t stream)
{
  const float* embed      = (const float*)d_in[0];
  const float* in_proj_w  = (const float*)d_in[1];
  const float* conv_w     = (const float*)d_in[2];
  const float* conv_b     = (const float*)d_in[3];
  const float* dt_bias    = (const float*)d_in[4];
  const float* A_log      = (const float*)d_in[5];
  const float* Dp         = (const float*)d_in[6];
  const float* norm_w     = (const float*)d_in[7];
  const float* out_proj_w = (const float*)d_in[8];
  const float* dec_w      = (const float*)d_in[9];
  const float* dec_b      = (const float*)d_in[10];

  char* ws = (char*)d_ws;
  size_t off = 0;
  auto alloc = [&](size_t bytes)->void*{ void* p = ws + off; off += (bytes + 255) & ~(size_t)255; return p; };

  u16* xbc = (u16*)alloc((size_t)MROWS*CONVD*2);
  u16* yb  = xbc;
  u16* R2  = (u16*)alloc((size_t)MROWS*DINNER*2);
  u16* Ebf = R2;
  u16* W1  = R2 + (size_t)MROWS*DMODEL;
  u16* xdtT  = R2;
  u16* ynorm = R2;
  float* dtraw = (float*)alloc((size_t)MROWS*NHEADS*4);
  float* dt_t  = (float*)alloc((size_t)NBATCH*NHEADS*SEQL*4);
  float* acs   = (float*)alloc((size_t)NBATCH*NHEADS*SEQL*4);
  u16* BTt   = (u16*)alloc((size_t)NBATCH*DSTATE*SEQL*2);
  u16* CTt   = (u16*)alloc((size_t)NBATCH*DSTATE*SEQL*2);
  u16* Cn    = (u16*)alloc((size_t)NBATCH*SEQL*DSTATE*2);
  u16* CBm   = (u16*)alloc((size_t)NBATCH*NCHUNK*CHUNKL*CHUNKL*2);
  u16* W2    = (u16*)alloc((size_t)DMODEL*DINNER*2);

  size_t off_base = off;
  u16* S = (u16*)alloc((size_t)NBATCH*NHEADS*NCHUNK*HEADD*DSTATE*2);
  bool use_par = (off <= ws_size);

  if (off_base > ws_size){
    k_sentinel<<<1,1,0,stream>>>((float*)d_out);
    return;
  }

  float* pred   = (float*)d_out;
  float* hidden = (float*)d_out + (size_t)MROWS*3;
  u16* zb = (u16*)hidden;

  hipFuncSetAttribute((const void*)k_gemm8<1>, hipFuncAttributeMaxDynamicSharedMemorySize, 131072);
  hipFuncSetAttribute((const void*)k_gemm8<0>, hipFuncAttributeMaxDynamicSharedMemorySize, 131072);

  k_cvt3<<<23040,256,0,stream>>>(embed, Ebf, in_proj_w, W1, out_proj_w, W2);
  {
    dim3 g1(64, NPROJP/256);
    k_gemm8<1><<<g1,512,131072,stream>>>(Ebf, W1, DMODEL, 0, nullptr, zb, xbc, dtraw);
  }
  k_dtprep<<<4096,128,0,stream>>>(dtraw, dt_bias, A_log, dt_t, acs);
  k_conv<<<4608,256,0,stream>>>(xbc, conv_w, conv_b, dt_t, xdtT, BTt, CTt);
  k_cbpar<<<(use_par ? 4224 : 128),256,0,stream>>>(BTt, CTt, xdtT, acs, CBm, Cn, S);
  if (use_par){
    k_scan<<<2048,256,0,stream>>>(S, acs);
    k_yoff<<<4096,256,0,stream>>>(Cn, xdtT, CBm, S, acs, dt_t, Dp, yb);
  } else {
    k_ssd<<<256,256,0,stream>>>(Cn, BTt, xdtT, CBm, acs, dt_t, Dp, yb);
  }
  k_gate<<<16384,256,0,stream>>>(yb, zb, norm_w, ynorm);
  {
    dim3 g2(64, DMODEL/256);
    k_gemm8<0><<<g2,512,131072,stream>>>(ynorm, W2, DINNER, DMODEL, hidden, nullptr, nullptr, nullptr);
  }
  k_pred<<<2048,256,0,stream>>>(hidden, dec_w, dec_b, pred);
}